// Round 1
// baseline (678.021 us; speedup 1.0000x reference)
//
#include <hip/hip_runtime.h>
#include <math.h>

#define HD   1024
#define LSEQ 512
#define NB   16
#define KTOP 5
#define NEGV 1e30f

// ---------------- Kernel A: start logits + mask -> masked_start_logits ----------------
__global__ void k_start_logits(const float* __restrict__ seq,
                               const float* __restrict__ Wst,
                               const float* __restrict__ bst,
                               const float* __restrict__ mask,
                               float* __restrict__ msl) {
  int wave = threadIdx.x >> 6, lane = threadIdx.x & 63;
  int row = blockIdx.x * 4 + wave;  // 0..8191 = b*512 + l
  const float4* s4 = (const float4*)(seq + (size_t)row * HD);
  const float4* w4 = (const float4*)Wst;
  float acc = 0.f;
#pragma unroll
  for (int m = 0; m < 4; ++m) {
    int i = lane + 64 * m;
    float4 a = s4[i], w = w4[i];
    acc += a.x * w.x + a.y * w.y + a.z * w.z + a.w * w.w;
  }
#pragma unroll
  for (int off = 32; off; off >>= 1) acc += __shfl_xor(acc, off);
  if (lane == 0) {
    float logit = acc + bst[0];
    float mv = mask[row];
    msl[row] = logit * mv - NEGV * (1.f - mv);
  }
}

// ---------------- Kernel B/E: row log_softmax + top5 (row length 512) ----------------
// xin: rows of 512 (masked logits). lsm_out: log_softmax. top_out[row*5+it].
// p_out (optional): softmax probs. idx_out (optional): argmax indices.
__global__ void k_softmax_topk(const float* __restrict__ xin,
                               float* __restrict__ lsm_out,
                               float* __restrict__ top_out,
                               float* __restrict__ p_out,
                               int* __restrict__ idx_out) {
  int row = blockIdx.x, t = threadIdx.x;
  int lane = t & 63, wid = t >> 6;
  __shared__ float redf[4];
  __shared__ int redi[4];
  __shared__ float bc_m, bc_s;
  __shared__ int bc_i;
  const float* x = xin + (size_t)row * LSEQ;
  float x0 = x[t], x1 = x[t + 256];

  // max
  float m = fmaxf(x0, x1);
#pragma unroll
  for (int off = 32; off; off >>= 1) m = fmaxf(m, __shfl_xor(m, off));
  if (lane == 0) redf[wid] = m;
  __syncthreads();
  if (t == 0) bc_m = fmaxf(fmaxf(redf[0], redf[1]), fmaxf(redf[2], redf[3]));
  __syncthreads();
  m = bc_m;

  // sum exp
  float e0 = expf(x0 - m), e1 = expf(x1 - m);
  float s = e0 + e1;
#pragma unroll
  for (int off = 32; off; off >>= 1) s += __shfl_xor(s, off);
  if (lane == 0) redf[wid] = s;
  __syncthreads();
  if (t == 0) bc_s = redf[0] + redf[1] + redf[2] + redf[3];
  __syncthreads();
  s = bc_s;
  float ls = logf(s);

  lsm_out[(size_t)row * LSEQ + t] = x0 - m - ls;
  lsm_out[(size_t)row * LSEQ + t + 256] = x1 - m - ls;
  if (p_out) {
    float inv = 1.f / s;
    p_out[(size_t)row * LSEQ + t] = e0 * inv;
    p_out[(size_t)row * LSEQ + t + 256] = e1 * inv;
  }

  // top-5 (sorted desc, lowest-index tie-break) on raw masked logits (same order as lsm)
  bool a0 = true, a1 = true;
  for (int it = 0; it < KTOP; ++it) {
    float v0 = a0 ? x0 : -INFINITY;
    float v1 = a1 ? x1 : -INFINITY;
    float bv = v0; int bi = t;
    if (v1 > bv) { bv = v1; bi = t + 256; }
#pragma unroll
    for (int off = 32; off; off >>= 1) {
      float ov = __shfl_xor(bv, off);
      int oi = __shfl_xor(bi, off);
      if (ov > bv || (ov == bv && oi < bi)) { bv = ov; bi = oi; }
    }
    __syncthreads();  // previous iteration's reads complete
    if (lane == 0) { redf[wid] = bv; redi[wid] = bi; }
    __syncthreads();
    if (t == 0) {
      float wv = redf[0]; int wi = redi[0];
      for (int w = 1; w < 4; ++w)
        if (redf[w] > wv || (redf[w] == wv && redi[w] < wi)) { wv = redf[w]; wi = redi[w]; }
      top_out[row * KTOP + it] = wv - m - ls;
      if (idx_out) idx_out[row * KTOP + it] = wi;
      bc_i = wi;
    }
    __syncthreads();
    int wi = bc_i;
    if (wi == t) a0 = false;
    if (wi == t + 256) a1 = false;
  }
}

// ---------------- Kernel C1: X2'[b,k,:] = start_feature @ W2 + b_end_in ----------------
__global__ void k_x2(const float* __restrict__ seq,
                     const int* __restrict__ idx_ws,
                     const float* __restrict__ Wei,   // W_end_in (2H,H)
                     const float* __restrict__ bei,
                     float* __restrict__ x2p) {
  int bk = blockIdx.x;  // 0..79
  int b = bk / KTOP;
  int t = threadIdx.x;
  __shared__ float srow[HD];
  int l = idx_ws[bk];
  const float* sr = seq + ((size_t)(b * LSEQ + l)) * HD;
  for (int i = t; i < HD; i += 256) srow[i] = sr[i];
  __syncthreads();
  const float* W2 = Wei + (size_t)HD * HD;  // second half rows
  float4 acc = *(const float4*)(bei + 4 * t);
#pragma unroll 4
  for (int h = 0; h < HD; ++h) {
    float4 w = *(const float4*)(W2 + (size_t)h * HD + 4 * t);
    float sv = srow[h];
    acc.x = fmaf(sv, w.x, acc.x);
    acc.y = fmaf(sv, w.y, acc.y);
    acc.z = fmaf(sv, w.z, acc.z);
    acc.w = fmaf(sv, w.w, acc.w);
  }
  *(float4*)(x2p + (size_t)bk * HD + 4 * t) = acc;
}

// ---------------- Kernel C2: answer_feature input = concat(sum_l p*seq, class_feature) ----------------
__global__ void k_answer_in(const float* __restrict__ seq,
                            const float* __restrict__ p_ws,
                            const int* __restrict__ cls,
                            float* __restrict__ af) {
  int b = blockIdx.x, t = threadIdx.x;
  __shared__ float ps[LSEQ];
  ps[t] = p_ws[b * LSEQ + t];
  ps[t + 256] = p_ws[b * LSEQ + t + 256];
  __syncthreads();
  const float* sb = seq + (size_t)b * LSEQ * HD;
  float4 acc = make_float4(0.f, 0.f, 0.f, 0.f);
#pragma unroll 4
  for (int l = 0; l < LSEQ; ++l) {
    float4 v = *(const float4*)(sb + (size_t)l * HD + 4 * t);
    float p = ps[l];
    acc.x = fmaf(p, v.x, acc.x);
    acc.y = fmaf(p, v.y, acc.y);
    acc.z = fmaf(p, v.z, acc.z);
    acc.w = fmaf(p, v.w, acc.w);
  }
  *(float4*)(af + (size_t)b * 2 * HD + 4 * t) = acc;
  int ci = cls[b];
  float4 cf = *(const float4*)(sb + (size_t)ci * HD + 4 * t);
  *(float4*)(af + (size_t)b * 2 * HD + HD + 4 * t) = cf;
}

// ---------------- Kernel C3: class_logits = tanh(af @ W_ans_in + b) @ W_ans_out ----------------
__global__ void k_answer_out(const float* __restrict__ af,
                             const float* __restrict__ Wai,
                             const float* __restrict__ bai,
                             const float* __restrict__ Wao,
                             float* __restrict__ out6) {
  int b = blockIdx.x, t = threadIdx.x;
  int lane = t & 63, wid = t >> 6;
  __shared__ float a_s[2 * HD];
  __shared__ float red[4];
  for (int i = t; i < 2 * HD; i += 256) a_s[i] = af[(size_t)b * 2 * HD + i];
  __syncthreads();
  float4 acc = *(const float4*)(bai + 4 * t);
#pragma unroll 4
  for (int h = 0; h < 2 * HD; ++h) {
    float4 w = *(const float4*)(Wai + (size_t)h * HD + 4 * t);
    float a = a_s[h];
    acc.x = fmaf(a, w.x, acc.x);
    acc.y = fmaf(a, w.y, acc.y);
    acc.z = fmaf(a, w.z, acc.z);
    acc.w = fmaf(a, w.w, acc.w);
  }
  float4 wo = *(const float4*)(Wao + 4 * t);
  float part = tanhf(acc.x) * wo.x + tanhf(acc.y) * wo.y +
               tanhf(acc.z) * wo.z + tanhf(acc.w) * wo.w;
#pragma unroll
  for (int off = 32; off; off >>= 1) part += __shfl_xor(part, off);
  if (lane == 0) red[wid] = part;
  __syncthreads();
  if (t == 0) out6[b] = red[0] + red[1] + red[2] + red[3];
}

// ---------------- Kernel D: fused X1-GEMM + tanh + LN + end-logit + mask ----------------
// Block: 32 rows (of b*512+l) x 1024 cols; 512 threads; thread = 16 rows x 4 cols.
__launch_bounds__(512, 1)
__global__ void k_end_logits(const float* __restrict__ seq,
                             const float* __restrict__ Wei,   // W1 = first H rows
                             const float* __restrict__ x2p,   // X2' (B,K,H)
                             const float* __restrict__ gamma,
                             const float* __restrict__ beta,
                             const float* __restrict__ Wout,  // W_end_out (H,1)
                             const float* __restrict__ beo,   // b_end_out
                             const float* __restrict__ mask,
                             float* __restrict__ mel) {       // masked_end_logits (B,K,L)
  __shared__ float As[32][64];
  __shared__ float Xs[KTOP][HD];
  __shared__ float gs[HD];
  __shared__ float part[160][4][3];
  __shared__ float sred[8][2];
  __shared__ float sGB[2];

  int t = threadIdx.x;
  int bid = blockIdx.x;        // 0..255
  int b = bid >> 4;
  int l0 = (bid & 15) * 32;
  const float* W1 = Wei;

  // stage g = gamma*Wout; partials for S_g, S_bw
  float pg = 0.f, pbw = 0.f;
  for (int i = t; i < HD; i += 512) {
    float g = gamma[i] * Wout[i];
    gs[i] = g;
    pg += g;
    pbw += beta[i] * Wout[i];
  }
#pragma unroll
  for (int off = 32; off; off >>= 1) {
    pg += __shfl_xor(pg, off);
    pbw += __shfl_xor(pbw, off);
  }
  if ((t & 63) == 0) { sred[t >> 6][0] = pg; sred[t >> 6][1] = pbw; }
  // stage X2' for this b
  for (int i = t; i < KTOP * HD; i += 512) ((float*)Xs)[i] = x2p[(size_t)b * KTOP * HD + i];
  __syncthreads();
  if (t == 0) {
    float a = 0.f, c = 0.f;
    for (int w = 0; w < 8; ++w) { a += sred[w][0]; c += sred[w][1]; }
    sGB[0] = a; sGB[1] = c;
  }

  int colb = (t & 255) * 4;
  int rhalf = t >> 8;
  int r0 = rhalf * 16;
  float4 acc[16];
#pragma unroll
  for (int r = 0; r < 16; ++r) acc[r] = make_float4(0.f, 0.f, 0.f, 0.f);

  const float* arow = seq + ((size_t)(b * LSEQ + l0)) * HD;
  int st_row = t >> 4;         // 0..31
  int st_k = (t & 15) * 4;     // 0..60

  for (int kc = 0; kc < HD; kc += 64) {
    __syncthreads();
    *(float4*)&As[st_row][st_k] = *(const float4*)(arow + (size_t)st_row * HD + kc + st_k);
    __syncthreads();
#pragma unroll 4
    for (int kk4 = 0; kk4 < 16; ++kk4) {
      int kk = kk4 * 4;
      float4 b0 = *(const float4*)(W1 + (size_t)(kc + kk) * HD + colb);
      float4 b1 = *(const float4*)(W1 + (size_t)(kc + kk + 1) * HD + colb);
      float4 b2 = *(const float4*)(W1 + (size_t)(kc + kk + 2) * HD + colb);
      float4 b3 = *(const float4*)(W1 + (size_t)(kc + kk + 3) * HD + colb);
#pragma unroll
      for (int r = 0; r < 16; ++r) {
        float4 a4 = *(const float4*)&As[r0 + r][kk];
        acc[r].x = fmaf(a4.x, b0.x, fmaf(a4.y, b1.x, fmaf(a4.z, b2.x, fmaf(a4.w, b3.x, acc[r].x))));
        acc[r].y = fmaf(a4.x, b0.y, fmaf(a4.y, b1.y, fmaf(a4.z, b2.y, fmaf(a4.w, b3.y, acc[r].y))));
        acc[r].z = fmaf(a4.x, b0.z, fmaf(a4.y, b1.z, fmaf(a4.z, b2.z, fmaf(a4.w, b3.z, acc[r].z))));
        acc[r].w = fmaf(a4.x, b0.w, fmaf(a4.y, b1.w, fmaf(a4.z, b2.w, fmaf(a4.w, b3.w, acc[r].w))));
      }
    }
  }
  __syncthreads();

  float sG = sGB[0], sBW = sGB[1];
  float bEndOut = beo[0];
  int lane = t & 63;
  int widh = (t >> 6) & 3;

#pragma unroll
  for (int r = 0; r < 16; ++r) {
#pragma unroll
    for (int k = 0; k < KTOP; ++k) {
      float4 xv = *(const float4*)&Xs[k][colb];
      float4 gv = *(const float4*)&gs[colb];
      float v0 = tanhf(acc[r].x + xv.x);
      float v1 = tanhf(acc[r].y + xv.y);
      float v2 = tanhf(acc[r].z + xv.z);
      float v3 = tanhf(acc[r].w + xv.w);
      float sv = v0 + v1 + v2 + v3;
      float sv2 = v0 * v0 + v1 * v1 + v2 * v2 + v3 * v3;
      float svg = v0 * gv.x + v1 * gv.y + v2 * gv.z + v3 * gv.w;
#pragma unroll
      for (int off = 32; off; off >>= 1) {
        sv += __shfl_xor(sv, off);
        sv2 += __shfl_xor(sv2, off);
        svg += __shfl_xor(svg, off);
      }
      if (lane == 0) {
        int rk = (r0 + r) * KTOP + k;
        part[rk][widh][0] = sv;
        part[rk][widh][1] = sv2;
        part[rk][widh][2] = svg;
      }
    }
  }
  __syncthreads();

  if (t < 160) {
    int rloc = t / KTOP, k = t % KTOP;
    float sv = 0.f, sv2 = 0.f, svg = 0.f;
#pragma unroll
    for (int w = 0; w < 4; ++w) {
      sv += part[t][w][0];
      sv2 += part[t][w][1];
      svg += part[t][w][2];
    }
    float mu = sv * (1.f / (float)HD);
    float var = sv2 * (1.f / (float)HD) - mu * mu;
    float rr = rsqrtf(var + 1e-12f);
    float logit = rr * (svg - mu * sG) + sBW + bEndOut;
    int l = l0 + rloc;
    float mv = mask[b * LSEQ + l];
    mel[((size_t)b * KTOP + k) * LSEQ + l] = logit * mv - NEGV * (1.f - mv);
  }
}

// ---------------- host ----------------
extern "C" void kernel_launch(void* const* d_in, const int* in_sizes, int n_in,
                              void* d_out, int out_size, void* d_ws, size_t ws_size,
                              hipStream_t stream) {
  (void)in_sizes; (void)n_in; (void)out_size; (void)ws_size;
  const float* seq = (const float*)d_in[0];
  const int*   cls = (const int*)d_in[1];
  const float* mask = (const float*)d_in[2];
  const float* Wst = (const float*)d_in[3];
  const float* bst = (const float*)d_in[4];
  const float* Wei = (const float*)d_in[5];
  const float* bei = (const float*)d_in[6];
  const float* gam = (const float*)d_in[7];
  const float* bet = (const float*)d_in[8];
  const float* Weo = (const float*)d_in[9];
  const float* beo = (const float*)d_in[10];
  const float* Wai = (const float*)d_in[11];
  const float* bai = (const float*)d_in[12];
  const float* Wao = (const float*)d_in[13];

  float* out = (float*)d_out;
  float* out0 = out;             // start_predictions  (16,512)
  float* out1 = out0 + 8192;     // end_predictions    (16,5,512)
  float* out2 = out1 + 40960;    // masked_start_logits(16,512)
  float* out3 = out2 + 8192;     // masked_end_logits  (16,5,512)
  float* out4 = out3 + 40960;    // start_top_predictions (16,5)
  float* out5 = out4 + 80;       // end_top_predictions (16,25)
  float* out6 = out5 + 400;      // class_logits (16)

  float* wsf = (float*)d_ws;
  float* p_ws = wsf;                       // 8192
  float* x2p  = wsf + 8192;                // 80*1024
  float* af   = x2p + 80 * 1024;           // 16*2048
  int*   idx_ws = (int*)(af + 16 * 2048);  // 80 ints

  k_start_logits<<<2048, 256, 0, stream>>>(seq, Wst, bst, mask, out2);
  k_softmax_topk<<<NB, 256, 0, stream>>>(out2, out0, out4, p_ws, idx_ws);
  k_x2<<<NB * KTOP, 256, 0, stream>>>(seq, idx_ws, Wei, bei, x2p);
  k_answer_in<<<NB, 256, 0, stream>>>(seq, p_ws, cls, af);
  k_answer_out<<<NB, 256, 0, stream>>>(af, Wai, bai, Wao, out6);
  k_end_logits<<<256, 512, 0, stream>>>(seq, Wei, x2p, gam, bet, Weo, beo, mask, out3);
  k_softmax_topk<<<NB * KTOP, 256, 0, stream>>>(out3, out1, out5, nullptr, nullptr);
}

// Round 2
// 248.848 us; speedup vs baseline: 2.7246x; 2.7246x over previous
//
#include <hip/hip_runtime.h>
#include <math.h>

#define HD   1024
#define LSEQ 512
#define NB   16
#define KTOP 5
#define NEGV 1e30f

typedef __bf16 bf16x8 __attribute__((ext_vector_type(8)));
typedef float  f32x4  __attribute__((ext_vector_type(4)));

__device__ inline unsigned short f2bf(float f) {
  unsigned u = __float_as_uint(f);
  unsigned r = (u + 0x7FFFu + ((u >> 16) & 1u)) >> 16;
  return (unsigned short)r;
}

__device__ inline float fast_tanh(float x) {
  float e = __expf(-2.f * fabsf(x));
  float v = (1.f - e) / (1.f + e);
  return copysignf(v, x);
}

#define GLDS(g, l) __builtin_amdgcn_global_load_lds(                      \
    (const __attribute__((address_space(1))) unsigned int*)(g),          \
    (__attribute__((address_space(3))) unsigned int*)(l), 16, 0, 0)

// ---------------- conversions ----------------
__global__ void k_conv_f2b(const float* __restrict__ x, unsigned short* __restrict__ y, int n4) {
  int i = blockIdx.x * blockDim.x + threadIdx.x;
  int stride = gridDim.x * blockDim.x;
  for (; i < n4; i += stride) {
    float4 v = ((const float4*)x)[i];
    ushort4 o;
    o.x = f2bf(v.x); o.y = f2bf(v.y); o.z = f2bf(v.z); o.w = f2bf(v.w);
    ((ushort4*)y)[i] = o;
  }
}

// W1 (first H rows of Wei, [h][d]) -> bf16 transposed Wt[d][h]
__global__ void k_convT(const float* __restrict__ W, unsigned short* __restrict__ Wt) {
  __shared__ unsigned short tile[32][33];
  int tx = threadIdx.x, ty = threadIdx.y;
  int h0 = blockIdx.x * 32, d0 = blockIdx.y * 32;
#pragma unroll
  for (int i = 0; i < 4; ++i)
    tile[ty + 8 * i][tx] = f2bf(W[(size_t)(h0 + ty + 8 * i) * HD + d0 + tx]);
  __syncthreads();
#pragma unroll
  for (int i = 0; i < 4; ++i)
    Wt[(size_t)(d0 + ty + 8 * i) * HD + h0 + tx] = tile[tx][ty + 8 * i];
}

// ---------------- Kernel A: start logits + mask ----------------
__global__ void k_start_logits(const float* __restrict__ seq,
                               const float* __restrict__ Wst,
                               const float* __restrict__ bst,
                               const float* __restrict__ mask,
                               float* __restrict__ msl) {
  int wave = threadIdx.x >> 6, lane = threadIdx.x & 63;
  int row = blockIdx.x * 4 + wave;
  const float4* s4 = (const float4*)(seq + (size_t)row * HD);
  const float4* w4 = (const float4*)Wst;
  float acc = 0.f;
#pragma unroll
  for (int m = 0; m < 4; ++m) {
    int i = lane + 64 * m;
    float4 a = s4[i], w = w4[i];
    acc += a.x * w.x + a.y * w.y + a.z * w.z + a.w * w.w;
  }
#pragma unroll
  for (int off = 32; off; off >>= 1) acc += __shfl_xor(acc, off);
  if (lane == 0) {
    float logit = acc + bst[0];
    float mv = mask[row];
    msl[row] = logit * mv - NEGV * (1.f - mv);
  }
}

// ---------------- row log_softmax + top5 (rows of 512) ----------------
__global__ void k_softmax_topk(const float* __restrict__ xin,
                               float* __restrict__ lsm_out,
                               float* __restrict__ top_out,
                               float* __restrict__ p_out,
                               int* __restrict__ idx_out) {
  int row = blockIdx.x, t = threadIdx.x;
  int lane = t & 63, wid = t >> 6;
  __shared__ float redf[4];
  __shared__ int redi[4];
  __shared__ float bc_m, bc_s;
  __shared__ int bc_i;
  const float* x = xin + (size_t)row * LSEQ;
  float x0 = x[t], x1 = x[t + 256];

  float m = fmaxf(x0, x1);
#pragma unroll
  for (int off = 32; off; off >>= 1) m = fmaxf(m, __shfl_xor(m, off));
  if (lane == 0) redf[wid] = m;
  __syncthreads();
  if (t == 0) bc_m = fmaxf(fmaxf(redf[0], redf[1]), fmaxf(redf[2], redf[3]));
  __syncthreads();
  m = bc_m;

  float e0 = expf(x0 - m), e1 = expf(x1 - m);
  float s = e0 + e1;
#pragma unroll
  for (int off = 32; off; off >>= 1) s += __shfl_xor(s, off);
  if (lane == 0) redf[wid] = s;
  __syncthreads();
  if (t == 0) bc_s = redf[0] + redf[1] + redf[2] + redf[3];
  __syncthreads();
  s = bc_s;
  float ls = logf(s);

  lsm_out[(size_t)row * LSEQ + t] = x0 - m - ls;
  lsm_out[(size_t)row * LSEQ + t + 256] = x1 - m - ls;
  if (p_out) {
    float inv = 1.f / s;
    p_out[(size_t)row * LSEQ + t] = e0 * inv;
    p_out[(size_t)row * LSEQ + t + 256] = e1 * inv;
  }

  bool a0 = true, a1 = true;
  for (int it = 0; it < KTOP; ++it) {
    float v0 = a0 ? x0 : -INFINITY;
    float v1 = a1 ? x1 : -INFINITY;
    float bv = v0; int bi = t;
    if (v1 > bv) { bv = v1; bi = t + 256; }
#pragma unroll
    for (int off = 32; off; off >>= 1) {
      float ov = __shfl_xor(bv, off);
      int oi = __shfl_xor(bi, off);
      if (ov > bv || (ov == bv && oi < bi)) { bv = ov; bi = oi; }
    }
    __syncthreads();
    if (lane == 0) { redf[wid] = bv; redi[wid] = bi; }
    __syncthreads();
    if (t == 0) {
      float wv = redf[0]; int wi = redi[0];
      for (int w = 1; w < 4; ++w)
        if (redf[w] > wv || (redf[w] == wv && redi[w] < wi)) { wv = redf[w]; wi = redi[w]; }
      top_out[row * KTOP + it] = wv - m - ls;
      if (idx_out) idx_out[row * KTOP + it] = wi;
      bc_i = wi;
    }
    __syncthreads();
    int wi = bc_i;
    if (wi == t) a0 = false;
    if (wi == t + 256) a1 = false;
  }
}

// ---------------- X2 partials: x2part[bk][slice][:] = srow_slice @ W2_slice ----------------
__global__ void k_x2p(const float* __restrict__ seq,
                      const int* __restrict__ idx,
                      const float* __restrict__ Wei,
                      float* __restrict__ x2part) {
  int bk = blockIdx.x, b = bk / KTOP, s = blockIdx.y, t = threadIdx.x;
  __shared__ float srow[128];
  int l = idx[bk];
  if (t < 128) srow[t] = seq[((size_t)(b * LSEQ + l)) * HD + s * 128 + t];
  __syncthreads();
  const float* W2 = Wei + (size_t)HD * HD + (size_t)s * 128 * HD;
  float4 acc = make_float4(0.f, 0.f, 0.f, 0.f);
#pragma unroll 8
  for (int h = 0; h < 128; ++h) {
    float4 wv = *(const float4*)(W2 + (size_t)h * HD + 4 * t);
    float sv = srow[h];
    acc.x = fmaf(sv, wv.x, acc.x);
    acc.y = fmaf(sv, wv.y, acc.y);
    acc.z = fmaf(sv, wv.z, acc.z);
    acc.w = fmaf(sv, wv.w, acc.w);
  }
  *(float4*)(x2part + ((size_t)bk * 8 + s) * HD + 4 * t) = acc;
}

__global__ void k_x2r(const float* __restrict__ x2part,
                      const float* __restrict__ bei,
                      float* __restrict__ x2p) {
  int bk = blockIdx.x, t = threadIdx.x;
  float4 a = *(const float4*)(bei + 4 * t);
#pragma unroll
  for (int s = 0; s < 8; ++s) {
    float4 p = *(const float4*)(x2part + ((size_t)bk * 8 + s) * HD + 4 * t);
    a.x += p.x; a.y += p.y; a.z += p.z; a.w += p.w;
  }
  *(float4*)(x2p + (size_t)bk * HD + 4 * t) = a;
}

// ---------------- MFMA GEMM (seq_bf16 @ W1t_bf16) fused tanh/LN partial sums ----------------
__global__ void k_gemm_end(const unsigned short* __restrict__ Abf,  // [8192][1024] bf16
                           const unsigned short* __restrict__ Bt,   // [1024 d][1024 h] bf16
                           const float* __restrict__ x2p,
                           const float* __restrict__ gamma,
                           const float* __restrict__ Wout,
                           float* __restrict__ sums) {
  __shared__ unsigned short As[128 * 32];
  __shared__ unsigned short Bs[128 * 32];
  int t = threadIdx.x;
  int w = t >> 6, lane = t & 63, ln = lane & 15, hi = lane >> 4;
  int wr = w >> 1, wc = w & 1;
  int R0 = blockIdx.x * 128, C0 = blockIdx.y * 128;
  int b = R0 >> 9;

  f32x4 acc[4][4] = {};

  const unsigned short* aBase = Abf + (size_t)(R0 + (t >> 2)) * HD + (t & 3) * 8;
  const unsigned short* bBase = Bt + (size_t)(C0 + (t >> 2)) * HD + (t & 3) * 8;
  unsigned short* aw = As + (t & 192) * 8;  // wave-uniform LDS base (shorts)
  unsigned short* bw = Bs + (t & 192) * 8;

  for (int kc = 0; kc < HD; kc += 32) {
    __syncthreads();
    GLDS(aBase + kc, aw);
    GLDS(aBase + kc + 64 * HD, aw + 2048);
    GLDS(bBase + kc, bw);
    GLDS(bBase + kc + 64 * HD, bw + 2048);
    __syncthreads();
    bf16x8 av[4], bv[4];
#pragma unroll
    for (int m = 0; m < 4; ++m)
      av[m] = *(const bf16x8*)(const void*)&As[(wr * 64 + m * 16 + ln) * 32 + hi * 8];
#pragma unroll
    for (int n = 0; n < 4; ++n)
      bv[n] = *(const bf16x8*)(const void*)&Bs[(wc * 64 + n * 16 + ln) * 32 + hi * 8];
#pragma unroll
    for (int m = 0; m < 4; ++m)
#pragma unroll
      for (int n = 0; n < 4; ++n)
        acc[m][n] = __builtin_amdgcn_mfma_f32_16x16x32_bf16(av[m], bv[n], acc[m][n], 0, 0, 0);
  }

  // epilogue: per (row,k) partial sums over this block's 128 cols
  float gsv[4];
  float x2v[4][KTOP];
#pragma unroll
  for (int n = 0; n < 4; ++n) {
    int c = C0 + wc * 64 + n * 16 + ln;
    gsv[n] = gamma[c] * Wout[c];
#pragma unroll
    for (int k = 0; k < KTOP; ++k) x2v[n][k] = x2p[((size_t)b * KTOP + k) * HD + c];
  }
#pragma unroll
  for (int m = 0; m < 4; ++m)
#pragma unroll
    for (int j = 0; j < 4; ++j) {
      int row = R0 + wr * 64 + m * 16 + hi * 4 + j;
#pragma unroll
      for (int k = 0; k < KTOP; ++k) {
        float sv = 0.f, s2 = 0.f, sg = 0.f;
#pragma unroll
        for (int n = 0; n < 4; ++n) {
          float v = fast_tanh(acc[m][n][j] + x2v[n][k]);
          sv += v; s2 += v * v; sg += v * gsv[n];
        }
#pragma unroll
        for (int off = 8; off; off >>= 1) {
          sv += __shfl_xor(sv, off);
          s2 += __shfl_xor(s2, off);
          sg += __shfl_xor(sg, off);
        }
        if (ln == 0) {
          float* p = sums + ((size_t)row * KTOP + k) * 3;
          atomicAdd(p, sv);
          atomicAdd(p + 1, s2);
          atomicAdd(p + 2, sg);
        }
      }
    }
}

// ---------------- finalize end logits: LN algebra + mask ----------------
__global__ void k_end_final(const float* __restrict__ sums,
                            const float* __restrict__ gamma,
                            const float* __restrict__ beta,
                            const float* __restrict__ Wout,
                            const float* __restrict__ beo,
                            const float* __restrict__ mask,
                            float* __restrict__ mel) {
  int bk = blockIdx.x, b = bk / KTOP, k = bk % KTOP;
  int t = threadIdx.x, lane = t & 63, wid = t >> 6;
  __shared__ float red[4][2];
  float pg = 0.f, pb = 0.f;
  for (int i = t; i < HD; i += 256) {
    float wv = Wout[i];
    pg += gamma[i] * wv;
    pb += beta[i] * wv;
  }
#pragma unroll
  for (int off = 32; off; off >>= 1) {
    pg += __shfl_xor(pg, off);
    pb += __shfl_xor(pb, off);
  }
  if (lane == 0) { red[wid][0] = pg; red[wid][1] = pb; }
  __syncthreads();
  float sG = red[0][0] + red[1][0] + red[2][0] + red[3][0];
  float sBW = red[0][1] + red[1][1] + red[2][1] + red[3][1] + beo[0];
  for (int l = t; l < LSEQ; l += 256) {
    int row = b * LSEQ + l;
    const float* s = sums + ((size_t)row * KTOP + k) * 3;
    float sv = s[0], s2 = s[1], sg = s[2];
    float mu = sv * (1.f / (float)HD);
    float var = s2 * (1.f / (float)HD) - mu * mu;
    float rr = rsqrtf(var + 1e-12f);
    float logit = rr * (sg - mu * sG) + sBW;
    float mv = mask[row];
    mel[((size_t)b * KTOP + k) * LSEQ + l] = logit * mv - NEGV * (1.f - mv);
  }
}

// ---------------- answer path (split 8-way) ----------------
__global__ void k_ans_in(const float* __restrict__ seq,
                         const float* __restrict__ p_ws,
                         const int* __restrict__ cls,
                         float* __restrict__ pa,
                         float* __restrict__ cf) {
  int b = blockIdx.x, s = blockIdx.y, t = threadIdx.x;
  __shared__ float ps[64];
  if (t < 64) ps[t] = p_ws[b * LSEQ + s * 64 + t];
  __syncthreads();
  const float* sb = seq + (size_t)(b * LSEQ + s * 64) * HD;
  float4 acc = make_float4(0.f, 0.f, 0.f, 0.f);
#pragma unroll 4
  for (int l = 0; l < 64; ++l) {
    float4 v = *(const float4*)(sb + (size_t)l * HD + 4 * t);
    float p = ps[l];
    acc.x = fmaf(p, v.x, acc.x);
    acc.y = fmaf(p, v.y, acc.y);
    acc.z = fmaf(p, v.z, acc.z);
    acc.w = fmaf(p, v.w, acc.w);
  }
  *(float4*)(pa + ((size_t)b * 8 + s) * HD + 4 * t) = acc;
  if (s == 0) {
    int ci = cls[b];
    *(float4*)(cf + (size_t)b * HD + 4 * t) =
        *(const float4*)(seq + (size_t)(b * LSEQ + ci) * HD + 4 * t);
  }
}

__global__ void k_ans_out_p(const float* __restrict__ pa,
                            const float* __restrict__ cf,
                            const float* __restrict__ Wai,
                            float* __restrict__ part_ans) {
  int b = blockIdx.x, s = blockIdx.y, t = threadIdx.x;
  __shared__ float a_s[256];
  int i0 = s * 256;
  int ig = i0 + t;
  float av;
  if (ig < HD) {
    av = 0.f;
#pragma unroll
    for (int q = 0; q < 8; ++q) av += pa[((size_t)b * 8 + q) * HD + ig];
  } else {
    av = cf[(size_t)b * HD + (ig - HD)];
  }
  a_s[t] = av;
  __syncthreads();
  float4 acc = make_float4(0.f, 0.f, 0.f, 0.f);
#pragma unroll 8
  for (int r = 0; r < 256; ++r) {
    float4 wv = *(const float4*)(Wai + (size_t)(i0 + r) * HD + 4 * t);
    float a = a_s[r];
    acc.x = fmaf(a, wv.x, acc.x);
    acc.y = fmaf(a, wv.y, acc.y);
    acc.z = fmaf(a, wv.z, acc.z);
    acc.w = fmaf(a, wv.w, acc.w);
  }
  *(float4*)(part_ans + ((size_t)b * 8 + s) * HD + 4 * t) = acc;
}

__global__ void k_ans_final(const float* __restrict__ part_ans,
                            const float* __restrict__ bai,
                            const float* __restrict__ Wao,
                            float* __restrict__ out6) {
  int b = blockIdx.x, t = threadIdx.x, lane = t & 63, wid = t >> 6;
  __shared__ float red[4];
  float4 a = *(const float4*)(bai + 4 * t);
#pragma unroll
  for (int s = 0; s < 8; ++s) {
    float4 p = *(const float4*)(part_ans + ((size_t)b * 8 + s) * HD + 4 * t);
    a.x += p.x; a.y += p.y; a.z += p.z; a.w += p.w;
  }
  float4 wo = *(const float4*)(Wao + 4 * t);
  float part = fast_tanh(a.x) * wo.x + fast_tanh(a.y) * wo.y +
               fast_tanh(a.z) * wo.z + fast_tanh(a.w) * wo.w;
#pragma unroll
  for (int off = 32; off; off >>= 1) part += __shfl_xor(part, off);
  if (lane == 0) red[wid] = part;
  __syncthreads();
  if (t == 0) out6[b] = red[0] + red[1] + red[2] + red[3];
}

// ================= fallback (round-1) kernels =================
__global__ void k_x2_old(const float* __restrict__ seq, const int* __restrict__ idx_ws,
                         const float* __restrict__ Wei, const float* __restrict__ bei,
                         float* __restrict__ x2p) {
  int bk = blockIdx.x;
  int b = bk / KTOP;
  int t = threadIdx.x;
  __shared__ float srow[HD];
  int l = idx_ws[bk];
  const float* sr = seq + ((size_t)(b * LSEQ + l)) * HD;
  for (int i = t; i < HD; i += 256) srow[i] = sr[i];
  __syncthreads();
  const float* W2 = Wei + (size_t)HD * HD;
  float4 acc = *(const float4*)(bei + 4 * t);
#pragma unroll 4
  for (int h = 0; h < HD; ++h) {
    float4 w = *(const float4*)(W2 + (size_t)h * HD + 4 * t);
    float sv = srow[h];
    acc.x = fmaf(sv, w.x, acc.x);
    acc.y = fmaf(sv, w.y, acc.y);
    acc.z = fmaf(sv, w.z, acc.z);
    acc.w = fmaf(sv, w.w, acc.w);
  }
  *(float4*)(x2p + (size_t)bk * HD + 4 * t) = acc;
}

__global__ void k_answer_in_old(const float* __restrict__ seq, const float* __restrict__ p_ws,
                                const int* __restrict__ cls, float* __restrict__ af) {
  int b = blockIdx.x, t = threadIdx.x;
  __shared__ float ps[LSEQ];
  ps[t] = p_ws[b * LSEQ + t];
  ps[t + 256] = p_ws[b * LSEQ + t + 256];
  __syncthreads();
  const float* sb = seq + (size_t)b * LSEQ * HD;
  float4 acc = make_float4(0.f, 0.f, 0.f, 0.f);
#pragma unroll 4
  for (int l = 0; l < LSEQ; ++l) {
    float4 v = *(const float4*)(sb + (size_t)l * HD + 4 * t);
    float p = ps[l];
    acc.x = fmaf(p, v.x, acc.x);
    acc.y = fmaf(p, v.y, acc.y);
    acc.z = fmaf(p, v.z, acc.z);
    acc.w = fmaf(p, v.w, acc.w);
  }
  *(float4*)(af + (size_t)b * 2 * HD + 4 * t) = acc;
  int ci = cls[b];
  float4 cfv = *(const float4*)(sb + (size_t)ci * HD + 4 * t);
  *(float4*)(af + (size_t)b * 2 * HD + HD + 4 * t) = cfv;
}

__global__ void k_answer_out_old(const float* __restrict__ af, const float* __restrict__ Wai,
                                 const float* __restrict__ bai, const float* __restrict__ Wao,
                                 float* __restrict__ out6) {
  int b = blockIdx.x, t = threadIdx.x;
  int lane = t & 63, wid = t >> 6;
  __shared__ float a_s[2 * HD];
  __shared__ float red[4];
  for (int i = t; i < 2 * HD; i += 256) a_s[i] = af[(size_t)b * 2 * HD + i];
  __syncthreads();
  float4 acc = *(const float4*)(bai + 4 * t);
#pragma unroll 4
  for (int h = 0; h < 2 * HD; ++h) {
    float4 w = *(const float4*)(Wai + (size_t)h * HD + 4 * t);
    float a = a_s[h];
    acc.x = fmaf(a, w.x, acc.x);
    acc.y = fmaf(a, w.y, acc.y);
    acc.z = fmaf(a, w.z, acc.z);
    acc.w = fmaf(a, w.w, acc.w);
  }
  float4 wo = *(const float4*)(Wao + 4 * t);
  float part = tanhf(acc.x) * wo.x + tanhf(acc.y) * wo.y +
               tanhf(acc.z) * wo.z + tanhf(acc.w) * wo.w;
#pragma unroll
  for (int off = 32; off; off >>= 1) part += __shfl_xor(part, off);
  if (lane == 0) red[wid] = part;
  __syncthreads();
  if (t == 0) out6[b] = red[0] + red[1] + red[2] + red[3];
}

__launch_bounds__(512, 1)
__global__ void k_end_logits_old(const float* __restrict__ seq,
                                 const float* __restrict__ Wei,
                                 const float* __restrict__ x2p,
                                 const float* __restrict__ gamma,
                                 const float* __restrict__ beta,
                                 const float* __restrict__ Wout,
                                 const float* __restrict__ beo,
                                 const float* __restrict__ mask,
                                 float* __restrict__ mel) {
  __shared__ float As[32][64];
  __shared__ float Xs[KTOP][HD];
  __shared__ float gs[HD];
  __shared__ float part[160][4][3];
  __shared__ float sred[8][2];
  __shared__ float sGB[2];

  int t = threadIdx.x;
  int bid = blockIdx.x;
  int b = bid >> 4;
  int l0 = (bid & 15) * 32;
  const float* W1 = Wei;

  float pg = 0.f, pbw = 0.f;
  for (int i = t; i < HD; i += 512) {
    float g = gamma[i] * Wout[i];
    gs[i] = g;
    pg += g;
    pbw += beta[i] * Wout[i];
  }
#pragma unroll
  for (int off = 32; off; off >>= 1) {
    pg += __shfl_xor(pg, off);
    pbw += __shfl_xor(pbw, off);
  }
  if ((t & 63) == 0) { sred[t >> 6][0] = pg; sred[t >> 6][1] = pbw; }
  for (int i = t; i < KTOP * HD; i += 512) ((float*)Xs)[i] = x2p[(size_t)b * KTOP * HD + i];
  __syncthreads();
  if (t == 0) {
    float a = 0.f, c = 0.f;
    for (int w = 0; w < 8; ++w) { a += sred[w][0]; c += sred[w][1]; }
    sGB[0] = a; sGB[1] = c;
  }

  int colb = (t & 255) * 4;
  int rhalf = t >> 8;
  int r0 = rhalf * 16;
  float4 acc[16];
#pragma unroll
  for (int r = 0; r < 16; ++r) acc[r] = make_float4(0.f, 0.f, 0.f, 0.f);

  const float* arow = seq + ((size_t)(b * LSEQ + l0)) * HD;
  int st_row = t >> 4;
  int st_k = (t & 15) * 4;

  for (int kc = 0; kc < HD; kc += 64) {
    __syncthreads();
    *(float4*)&As[st_row][st_k] = *(const float4*)(arow + (size_t)st_row * HD + kc + st_k);
    __syncthreads();
#pragma unroll 4
    for (int kk4 = 0; kk4 < 16; ++kk4) {
      int kk = kk4 * 4;
      float4 b0 = *(const float4*)(W1 + (size_t)(kc + kk) * HD + colb);
      float4 b1 = *(const float4*)(W1 + (size_t)(kc + kk + 1) * HD + colb);
      float4 b2 = *(const float4*)(W1 + (size_t)(kc + kk + 2) * HD + colb);
      float4 b3 = *(const float4*)(W1 + (size_t)(kc + kk + 3) * HD + colb);
#pragma unroll
      for (int r = 0; r < 16; ++r) {
        float4 a4 = *(const float4*)&As[r0 + r][kk];
        acc[r].x = fmaf(a4.x, b0.x, fmaf(a4.y, b1.x, fmaf(a4.z, b2.x, fmaf(a4.w, b3.x, acc[r].x))));
        acc[r].y = fmaf(a4.x, b0.y, fmaf(a4.y, b1.y, fmaf(a4.z, b2.y, fmaf(a4.w, b3.y, acc[r].y))));
        acc[r].z = fmaf(a4.x, b0.z, fmaf(a4.y, b1.z, fmaf(a4.z, b2.z, fmaf(a4.w, b3.z, acc[r].z))));
        acc[r].w = fmaf(a4.x, b0.w, fmaf(a4.y, b1.w, fmaf(a4.z, b2.w, fmaf(a4.w, b3.w, acc[r].w))));
      }
    }
  }
  __syncthreads();

  float sG = sGB[0], sBW = sGB[1];
  float bEndOut = beo[0];
  int lane = t & 63;
  int widh = (t >> 6) & 3;

#pragma unroll
  for (int r = 0; r < 16; ++r) {
#pragma unroll
    for (int k = 0; k < KTOP; ++k) {
      float4 xv = *(const float4*)&Xs[k][colb];
      float4 gv = *(const float4*)&gs[colb];
      float v0 = tanhf(acc[r].x + xv.x);
      float v1 = tanhf(acc[r].y + xv.y);
      float v2 = tanhf(acc[r].z + xv.z);
      float v3 = tanhf(acc[r].w + xv.w);
      float sv = v0 + v1 + v2 + v3;
      float sv2 = v0 * v0 + v1 * v1 + v2 * v2 + v3 * v3;
      float svg = v0 * gv.x + v1 * gv.y + v2 * gv.z + v3 * gv.w;
#pragma unroll
      for (int off = 32; off; off >>= 1) {
        sv += __shfl_xor(sv, off);
        sv2 += __shfl_xor(sv2, off);
        svg += __shfl_xor(svg, off);
      }
      if (lane == 0) {
        int rk = (r0 + r) * KTOP + k;
        part[rk][widh][0] = sv;
        part[rk][widh][1] = sv2;
        part[rk][widh][2] = svg;
      }
    }
  }
  __syncthreads();

  if (t < 160) {
    int rloc = t / KTOP, k = t % KTOP;
    float sv = 0.f, sv2 = 0.f, svg = 0.f;
#pragma unroll
    for (int w = 0; w < 4; ++w) {
      sv += part[t][w][0];
      sv2 += part[t][w][1];
      svg += part[t][w][2];
    }
    float mu = sv * (1.f / (float)HD);
    float var = sv2 * (1.f / (float)HD) - mu * mu;
    float rr = rsqrtf(var + 1e-12f);
    float logit = rr * (svg - mu * sG) + sBW + bEndOut;
    int l = l0 + rloc;
    float mv = mask[b * LSEQ + l];
    mel[((size_t)b * KTOP + k) * LSEQ + l] = logit * mv - NEGV * (1.f - mv);
  }
}

// ---------------- host ----------------
extern "C" void kernel_launch(void* const* d_in, const int* in_sizes, int n_in,
                              void* d_out, int out_size, void* d_ws, size_t ws_size,
                              hipStream_t stream) {
  (void)in_sizes; (void)n_in; (void)out_size;
  const float* seq = (const float*)d_in[0];
  const int*   cls = (const int*)d_in[1];
  const float* mask = (const float*)d_in[2];
  const float* Wst = (const float*)d_in[3];
  const float* bst = (const float*)d_in[4];
  const float* Wei = (const float*)d_in[5];
  const float* bei = (const float*)d_in[6];
  const float* gam = (const float*)d_in[7];
  const float* bet = (const float*)d_in[8];
  const float* Weo = (const float*)d_in[9];
  const float* beo = (const float*)d_in[10];
  const float* Wai = (const float*)d_in[11];
  const float* bai = (const float*)d_in[12];
  const float* Wao = (const float*)d_in[13];

  float* out = (float*)d_out;
  float* out0 = out;             // start_predictions  (16,512)
  float* out1 = out0 + 8192;     // end_predictions    (16,5,512)
  float* out2 = out1 + 40960;    // masked_start_logits(16,512)
  float* out3 = out2 + 8192;     // masked_end_logits  (16,5,512)
  float* out4 = out3 + 40960;    // start_top_predictions (16,5)
  float* out5 = out4 + 80;       // end_top_predictions (16,25)
  float* out6 = out5 + 400;      // class_logits (16)

  // ws layout (fast path)
  unsigned short* seqb = (unsigned short*)d_ws;            // 8192*1024 bf16
  unsigned short* w1t  = seqb + (size_t)8192 * 1024;       // 1024*1024 bf16
  float* p_ws   = (float*)(w1t + (size_t)1024 * 1024);     // 8192
  int*   idx_ws = (int*)(p_ws + 8192);                     // 128 (80 used)
  float* x2part = (float*)(idx_ws + 128);                  // 640*1024
  float* x2p    = x2part + (size_t)640 * 1024;             // 80*1024
  float* sums   = x2p + (size_t)80 * 1024;                 // 8192*5*3
  float* pa     = sums + (size_t)8192 * 15;                // 128*1024
  float* cf     = pa + (size_t)128 * 1024;                 // 16*1024
  float* pans   = cf + (size_t)16 * 1024;                  // 128*1024
  size_t need = (size_t)((char*)(pans + (size_t)128 * 1024) - (char*)d_ws);

  if (ws_size >= need) {
    hipMemsetAsync(sums, 0, (size_t)8192 * 15 * sizeof(float), stream);
    k_conv_f2b<<<2048, 256, 0, stream>>>(seq, seqb, 8192 * 1024 / 4);
    k_convT<<<dim3(32, 32), dim3(32, 8), 0, stream>>>(Wei, w1t);
    k_start_logits<<<2048, 256, 0, stream>>>(seq, Wst, bst, mask, out2);
    k_softmax_topk<<<NB, 256, 0, stream>>>(out2, out0, out4, p_ws, idx_ws);
    k_x2p<<<dim3(NB * KTOP, 8), 256, 0, stream>>>(seq, idx_ws, Wei, x2part);
    k_x2r<<<NB * KTOP, 256, 0, stream>>>(x2part, bei, x2p);
    k_gemm_end<<<dim3(64, 8), 256, 0, stream>>>(seqb, w1t, x2p, gam, Weo, sums);
    k_end_final<<<NB * KTOP, 256, 0, stream>>>(sums, gam, bet, Weo, beo, mask, out3);
    k_softmax_topk<<<NB * KTOP, 256, 0, stream>>>(out3, out1, out5, nullptr, nullptr);
    k_ans_in<<<dim3(NB, 8), 256, 0, stream>>>(seq, p_ws, cls, pa, cf);
    k_ans_out_p<<<dim3(NB, 8), 256, 0, stream>>>(pa, cf, Wai, pans);
    k_ans_final<<<NB, 256, 0, stream>>>(pans, bai, Wao, out6);
  } else {
    // fallback: round-1 path (small ws)
    float* f_p   = (float*)d_ws;                 // 8192
    float* f_x2p = f_p + 8192;                   // 80*1024
    float* f_af  = f_x2p + 80 * 1024;            // 16*2048
    int*   f_idx = (int*)(f_af + 16 * 2048);     // 80
    k_start_logits<<<2048, 256, 0, stream>>>(seq, Wst, bst, mask, out2);
    k_softmax_topk<<<NB, 256, 0, stream>>>(out2, out0, out4, f_p, f_idx);
    k_x2_old<<<NB * KTOP, 256, 0, stream>>>(seq, f_idx, Wei, bei, f_x2p);
    k_answer_in_old<<<NB, 256, 0, stream>>>(seq, f_p, cls, f_af);
    k_answer_out_old<<<NB, 256, 0, stream>>>(f_af, Wai, bai, Wao, out6);
    k_end_logits_old<<<256, 512, 0, stream>>>(seq, Wei, f_x2p, gam, bet, Weo, beo, mask, out3);
    k_softmax_topk<<<NB * KTOP, 256, 0, stream>>>(out3, out1, out5, nullptr, nullptr);
  }
}

// Round 3
// 143.941 us; speedup vs baseline: 4.7104x; 1.7288x over previous
//
#include <hip/hip_runtime.h>
#include <math.h>

#define HD   1024
#define LSEQ 512
#define NB   16
#define KTOP 5
#define NEGV 1e30f

typedef __bf16 bf16x8 __attribute__((ext_vector_type(8)));
typedef float  f32x4  __attribute__((ext_vector_type(4)));

__device__ inline unsigned short f2bf(float f) {
  unsigned u = __float_as_uint(f);
  unsigned r = (u + 0x7FFFu + ((u >> 16) & 1u)) >> 16;
  return (unsigned short)r;
}

__device__ inline float fast_tanh(float x) {
  float e = __expf(-2.f * fabsf(x));
  float v = (1.f - e) / (1.f + e);
  return copysignf(v, x);
}

#define GLDS(g, l) __builtin_amdgcn_global_load_lds(                      \
    (const __attribute__((address_space(1))) unsigned int*)(g),          \
    (__attribute__((address_space(3))) unsigned int*)(l), 16, 0, 0)

// ---------------- fused f32->bf16 conversion + start logits ----------------
// one wave per row (8192 rows); converts seq row to bf16 and dots with Wst.
__global__ void k_conv_start(const float* __restrict__ seq,
                             unsigned short* __restrict__ seqb,
                             const float* __restrict__ Wst,
                             const float* __restrict__ bst,
                             const float* __restrict__ mask,
                             float* __restrict__ msl) {
  int wave = threadIdx.x >> 6, lane = threadIdx.x & 63;
  int row = blockIdx.x * 4 + wave;
  const float4* s4 = (const float4*)(seq + (size_t)row * HD);
  const float4* w4 = (const float4*)Wst;
  ushort4* o4 = (ushort4*)(seqb + (size_t)row * HD);
  float acc = 0.f;
#pragma unroll
  for (int m = 0; m < 4; ++m) {
    int i = lane + 64 * m;
    float4 a = s4[i], w = w4[i];
    acc += a.x * w.x + a.y * w.y + a.z * w.z + a.w * w.w;
    ushort4 o;
    o.x = f2bf(a.x); o.y = f2bf(a.y); o.z = f2bf(a.z); o.w = f2bf(a.w);
    o4[i] = o;
  }
#pragma unroll
  for (int off = 32; off; off >>= 1) acc += __shfl_xor(acc, off);
  if (lane == 0) {
    float logit = acc + bst[0];
    float mv = mask[row];
    msl[row] = logit * mv - NEGV * (1.f - mv);
  }
}

// W1 (first H rows of Wei, [h][d]) -> bf16 transposed Wt[d][h]
__global__ void k_convT(const float* __restrict__ W, unsigned short* __restrict__ Wt) {
  __shared__ unsigned short tile[32][33];
  int tx = threadIdx.x, ty = threadIdx.y;
  int h0 = blockIdx.x * 32, d0 = blockIdx.y * 32;
#pragma unroll
  for (int i = 0; i < 4; ++i)
    tile[ty + 8 * i][tx] = f2bf(W[(size_t)(h0 + ty + 8 * i) * HD + d0 + tx]);
  __syncthreads();
#pragma unroll
  for (int i = 0; i < 4; ++i)
    Wt[(size_t)(d0 + ty + 8 * i) * HD + h0 + tx] = tile[tx][ty + 8 * i];
}

// ---------------- row log_softmax + top5 (rows of 512) ----------------
__global__ void k_softmax_topk(const float* __restrict__ xin,
                               float* __restrict__ lsm_out,
                               float* __restrict__ top_out,
                               float* __restrict__ p_out,
                               int* __restrict__ idx_out) {
  int row = blockIdx.x, t = threadIdx.x;
  int lane = t & 63, wid = t >> 6;
  __shared__ float redf[4];
  __shared__ int redi[4];
  __shared__ float bc_m, bc_s;
  __shared__ int bc_i;
  const float* x = xin + (size_t)row * LSEQ;
  float x0 = x[t], x1 = x[t + 256];

  float m = fmaxf(x0, x1);
#pragma unroll
  for (int off = 32; off; off >>= 1) m = fmaxf(m, __shfl_xor(m, off));
  if (lane == 0) redf[wid] = m;
  __syncthreads();
  if (t == 0) bc_m = fmaxf(fmaxf(redf[0], redf[1]), fmaxf(redf[2], redf[3]));
  __syncthreads();
  m = bc_m;

  float e0 = expf(x0 - m), e1 = expf(x1 - m);
  float s = e0 + e1;
#pragma unroll
  for (int off = 32; off; off >>= 1) s += __shfl_xor(s, off);
  if (lane == 0) redf[wid] = s;
  __syncthreads();
  if (t == 0) bc_s = redf[0] + redf[1] + redf[2] + redf[3];
  __syncthreads();
  s = bc_s;
  float ls = logf(s);

  lsm_out[(size_t)row * LSEQ + t] = x0 - m - ls;
  lsm_out[(size_t)row * LSEQ + t + 256] = x1 - m - ls;
  if (p_out) {
    float inv = 1.f / s;
    p_out[(size_t)row * LSEQ + t] = e0 * inv;
    p_out[(size_t)row * LSEQ + t + 256] = e1 * inv;
  }

  bool a0 = true, a1 = true;
  for (int it = 0; it < KTOP; ++it) {
    float v0 = a0 ? x0 : -INFINITY;
    float v1 = a1 ? x1 : -INFINITY;
    float bv = v0; int bi = t;
    if (v1 > bv) { bv = v1; bi = t + 256; }
#pragma unroll
    for (int off = 32; off; off >>= 1) {
      float ov = __shfl_xor(bv, off);
      int oi = __shfl_xor(bi, off);
      if (ov > bv || (ov == bv && oi < bi)) { bv = ov; bi = oi; }
    }
    __syncthreads();
    if (lane == 0) { redf[wid] = bv; redi[wid] = bi; }
    __syncthreads();
    if (t == 0) {
      float wv = redf[0]; int wi = redi[0];
      for (int w = 1; w < 4; ++w)
        if (redf[w] > wv || (redf[w] == wv && redi[w] < wi)) { wv = redf[w]; wi = redi[w]; }
      top_out[row * KTOP + it] = wv - m - ls;
      if (idx_out) idx_out[row * KTOP + it] = wi;
      bc_i = wi;
    }
    __syncthreads();
    int wi = bc_i;
    if (wi == t) a0 = false;
    if (wi == t + 256) a1 = false;
  }
}

// ---------------- X2 partials ----------------
__global__ void k_x2p(const float* __restrict__ seq,
                      const int* __restrict__ idx,
                      const float* __restrict__ Wei,
                      float* __restrict__ x2part) {
  int bk = blockIdx.x, b = bk / KTOP, s = blockIdx.y, t = threadIdx.x;
  __shared__ float srow[128];
  int l = idx[bk];
  if (t < 128) srow[t] = seq[((size_t)(b * LSEQ + l)) * HD + s * 128 + t];
  __syncthreads();
  const float* W2 = Wei + (size_t)HD * HD + (size_t)s * 128 * HD;
  float4 acc = make_float4(0.f, 0.f, 0.f, 0.f);
#pragma unroll 8
  for (int h = 0; h < 128; ++h) {
    float4 wv = *(const float4*)(W2 + (size_t)h * HD + 4 * t);
    float sv = srow[h];
    acc.x = fmaf(sv, wv.x, acc.x);
    acc.y = fmaf(sv, wv.y, acc.y);
    acc.z = fmaf(sv, wv.z, acc.z);
    acc.w = fmaf(sv, wv.w, acc.w);
  }
  *(float4*)(x2part + ((size_t)bk * 8 + s) * HD + 4 * t) = acc;
}

__global__ void k_x2r(const float* __restrict__ x2part,
                      const float* __restrict__ bei,
                      float* __restrict__ x2p) {
  int bk = blockIdx.x, t = threadIdx.x;
  float4 a = *(const float4*)(bei + 4 * t);
#pragma unroll
  for (int s = 0; s < 8; ++s) {
    float4 p = *(const float4*)(x2part + ((size_t)bk * 8 + s) * HD + 4 * t);
    a.x += p.x; a.y += p.y; a.z += p.z; a.w += p.w;
  }
  *(float4*)(x2p + (size_t)bk * HD + 4 * t) = a;
}

// ---------------- MFMA GEMM, 2-phase pipeline, swizzled LDS, fused LN sums ----------------
// tile 128x128, BK=64, 4 waves, double-buffered LDS.
// MODE 0: write per-colblock partials; MODE 1: atomicAdd into sums.
template <int MODE>
__launch_bounds__(256, 2)
__global__ void k_gemm_end(const unsigned short* __restrict__ Abf,  // [8192][1024] bf16
                           const unsigned short* __restrict__ Bt,   // [1024 d][1024 h] bf16
                           const float* __restrict__ x2p,
                           const float* __restrict__ gamma,
                           const float* __restrict__ Wout,
                           float* __restrict__ outp) {
  __shared__ unsigned short As[2][128 * 64];
  __shared__ unsigned short Bs[2][128 * 64];
  int t = threadIdx.x;
  int w = t >> 6, lane = t & 63, ln = lane & 15, hi = lane >> 4;
  int wr = w >> 1, wc = w & 1;
  int R0 = blockIdx.x * 128, C0 = blockIdx.y * 128;
  int b = R0 >> 9;

  f32x4 acc[4][4] = {};

  // STAGE: linear LDS dest, inverse-swizzled global source (chunk ^= row&7).
#define STAGE(buf, kc)                                                        \
  do {                                                                        \
    _Pragma("unroll")                                                         \
    for (int p_ = 0; p_ < 4; ++p_) {                                          \
      int rr_ = p_ * 32 + (t >> 3);                                           \
      int cc_ = (t & 7) ^ (rr_ & 7);                                          \
      GLDS(Abf + (size_t)(R0 + rr_) * HD + (kc) + cc_ * 8,                    \
           &As[buf][p_ * 2048 + w * 512]);                                    \
      GLDS(Bt + (size_t)(C0 + rr_) * HD + (kc) + cc_ * 8,                     \
           &Bs[buf][p_ * 2048 + w * 512]);                                    \
    }                                                                         \
  } while (0)

  STAGE(0, 0);
  for (int it = 0; it < 16; ++it) {
    int cur = it & 1;
    if (it < 15) {
      STAGE(cur ^ 1, (it + 1) * 64);
      asm volatile("s_waitcnt vmcnt(8)" ::: "memory");  // cur's 8 loads done, next 8 in flight
    } else {
      asm volatile("s_waitcnt vmcnt(0)" ::: "memory");
    }
    __builtin_amdgcn_s_barrier();
    __builtin_amdgcn_sched_barrier(0);
#pragma unroll
    for (int ks = 0; ks < 2; ++ks) {
      bf16x8 av[4], bv[4];
#pragma unroll
      for (int m = 0; m < 4; ++m) {
        int r = wr * 64 + m * 16 + ln;
        av[m] = *(const bf16x8*)(const void*)&As[cur][r * 64 + (((ks * 4 + hi) ^ (r & 7)) * 8)];
      }
#pragma unroll
      for (int n = 0; n < 4; ++n) {
        int r = wc * 64 + n * 16 + ln;
        bv[n] = *(const bf16x8*)(const void*)&Bs[cur][r * 64 + (((ks * 4 + hi) ^ (r & 7)) * 8)];
      }
#pragma unroll
      for (int m = 0; m < 4; ++m)
#pragma unroll
        for (int n = 0; n < 4; ++n)
          acc[m][n] = __builtin_amdgcn_mfma_f32_16x16x32_bf16(av[m], bv[n], acc[m][n], 0, 0, 0);
    }
    __builtin_amdgcn_sched_barrier(0);
    __builtin_amdgcn_s_barrier();
  }
#undef STAGE

  // epilogue: per (row,k) partial LN sums over this block's 128 cols
  float gsv[4];
  float x2v[4][KTOP];
#pragma unroll
  for (int n = 0; n < 4; ++n) {
    int c = C0 + wc * 64 + n * 16 + ln;
    gsv[n] = gamma[c] * Wout[c];
#pragma unroll
    for (int k = 0; k < KTOP; ++k) x2v[n][k] = x2p[((size_t)b * KTOP + k) * HD + c];
  }
#pragma unroll
  for (int m = 0; m < 4; ++m)
#pragma unroll
    for (int j = 0; j < 4; ++j) {
      int row = R0 + wr * 64 + m * 16 + hi * 4 + j;
#pragma unroll
      for (int k = 0; k < KTOP; ++k) {
        float sv = 0.f, s2 = 0.f, sg = 0.f;
#pragma unroll
        for (int n = 0; n < 4; ++n) {
          float v = fast_tanh(acc[m][n][j] + x2v[n][k]);
          sv += v; s2 += v * v; sg += v * gsv[n];
        }
#pragma unroll
        for (int off = 8; off; off >>= 1) {
          sv += __shfl_xor(sv, off);
          s2 += __shfl_xor(s2, off);
          sg += __shfl_xor(sg, off);
        }
        if (ln == 0) {
          if (MODE == 0) {
            float* p = outp + (((size_t)blockIdx.y * 8192 + row) * KTOP + k) * 3;
            p[0] = sv; p[1] = s2; p[2] = sg;
          } else {
            float* p = outp + ((size_t)row * KTOP + k) * 3;
            atomicAdd(p, sv);
            atomicAdd(p + 1, s2);
            atomicAdd(p + 2, sg);
          }
        }
      }
    }
}

// ---------------- finalize end logits: sum partials + LN algebra + mask ----------------
__global__ void k_end_final(const float* __restrict__ sums, int ncb,
                            const float* __restrict__ gamma,
                            const float* __restrict__ beta,
                            const float* __restrict__ Wout,
                            const float* __restrict__ beo,
                            const float* __restrict__ mask,
                            float* __restrict__ mel) {
  int bk = blockIdx.x, b = bk / KTOP, k = bk % KTOP;
  int t = threadIdx.x, lane = t & 63, wid = t >> 6;
  __shared__ float red[4][2];
  float pg = 0.f, pb = 0.f;
  for (int i = t; i < HD; i += 256) {
    float wv = Wout[i];
    pg += gamma[i] * wv;
    pb += beta[i] * wv;
  }
#pragma unroll
  for (int off = 32; off; off >>= 1) {
    pg += __shfl_xor(pg, off);
    pb += __shfl_xor(pb, off);
  }
  if (lane == 0) { red[wid][0] = pg; red[wid][1] = pb; }
  __syncthreads();
  float sG = red[0][0] + red[1][0] + red[2][0] + red[3][0];
  float sBW = red[0][1] + red[1][1] + red[2][1] + red[3][1] + beo[0];
  for (int l = t; l < LSEQ; l += 256) {
    int row = b * LSEQ + l;
    float sv = 0.f, s2 = 0.f, sg = 0.f;
    for (int s = 0; s < ncb; ++s) {
      const float* p = sums + (((size_t)s * 8192 + row) * KTOP + k) * 3;
      sv += p[0]; s2 += p[1]; sg += p[2];
    }
    float mu = sv * (1.f / (float)HD);
    float var = s2 * (1.f / (float)HD) - mu * mu;
    float rr = rsqrtf(var + 1e-12f);
    float logit = rr * (sg - mu * sG) + sBW;
    float mv = mask[row];
    mel[((size_t)b * KTOP + k) * LSEQ + l] = logit * mv - NEGV * (1.f - mv);
  }
}

// ---------------- answer path (split 8-way) ----------------
__global__ void k_ans_in(const float* __restrict__ seq,
                         const float* __restrict__ p_ws,
                         const int* __restrict__ cls,
                         float* __restrict__ pa,
                         float* __restrict__ cf) {
  int b = blockIdx.x, s = blockIdx.y, t = threadIdx.x;
  __shared__ float ps[64];
  if (t < 64) ps[t] = p_ws[b * LSEQ + s * 64 + t];
  __syncthreads();
  const float* sb = seq + (size_t)(b * LSEQ + s * 64) * HD;
  float4 acc = make_float4(0.f, 0.f, 0.f, 0.f);
#pragma unroll 4
  for (int l = 0; l < 64; ++l) {
    float4 v = *(const float4*)(sb + (size_t)l * HD + 4 * t);
    float p = ps[l];
    acc.x = fmaf(p, v.x, acc.x);
    acc.y = fmaf(p, v.y, acc.y);
    acc.z = fmaf(p, v.z, acc.z);
    acc.w = fmaf(p, v.w, acc.w);
  }
  *(float4*)(pa + ((size_t)b * 8 + s) * HD + 4 * t) = acc;
  if (s == 0) {
    int ci = cls[b];
    *(float4*)(cf + (size_t)b * HD + 4 * t) =
        *(const float4*)(seq + (size_t)(b * LSEQ + ci) * HD + 4 * t);
  }
}

__global__ void k_ans_out_p(const float* __restrict__ pa,
                            const float* __restrict__ cf,
                            const float* __restrict__ Wai,
                            float* __restrict__ part_ans) {
  int b = blockIdx.x, s = blockIdx.y, t = threadIdx.x;
  __shared__ float a_s[256];
  int i0 = s * 256;
  int ig = i0 + t;
  float av;
  if (ig < HD) {
    av = 0.f;
#pragma unroll
    for (int q = 0; q < 8; ++q) av += pa[((size_t)b * 8 + q) * HD + ig];
  } else {
    av = cf[(size_t)b * HD + (ig - HD)];
  }
  a_s[t] = av;
  __syncthreads();
  float4 acc = make_float4(0.f, 0.f, 0.f, 0.f);
#pragma unroll 8
  for (int r = 0; r < 256; ++r) {
    float4 wv = *(const float4*)(Wai + (size_t)(i0 + r) * HD + 4 * t);
    float a = a_s[r];
    acc.x = fmaf(a, wv.x, acc.x);
    acc.y = fmaf(a, wv.y, acc.y);
    acc.z = fmaf(a, wv.z, acc.z);
    acc.w = fmaf(a, wv.w, acc.w);
  }
  *(float4*)(part_ans + ((size_t)b * 8 + s) * HD + 4 * t) = acc;
}

__global__ void k_ans_final(const float* __restrict__ part_ans,
                            const float* __restrict__ bai,
                            const float* __restrict__ Wao,
                            float* __restrict__ out6) {
  int b = blockIdx.x, t = threadIdx.x, lane = t & 63, wid = t >> 6;
  __shared__ float red[4];
  float4 a = *(const float4*)(bai + 4 * t);
#pragma unroll
  for (int s = 0; s < 8; ++s) {
    float4 p = *(const float4*)(part_ans + ((size_t)b * 8 + s) * HD + 4 * t);
    a.x += p.x; a.y += p.y; a.z += p.z; a.w += p.w;
  }
  float4 wo = *(const float4*)(Wao + 4 * t);
  float part = fast_tanh(a.x) * wo.x + fast_tanh(a.y) * wo.y +
               fast_tanh(a.z) * wo.z + fast_tanh(a.w) * wo.w;
#pragma unroll
  for (int off = 32; off; off >>= 1) part += __shfl_xor(part, off);
  if (lane == 0) red[wid] = part;
  __syncthreads();
  if (t == 0) out6[b] = red[0] + red[1] + red[2] + red[3];
}

// ---------------- host ----------------
extern "C" void kernel_launch(void* const* d_in, const int* in_sizes, int n_in,
                              void* d_out, int out_size, void* d_ws, size_t ws_size,
                              hipStream_t stream) {
  (void)in_sizes; (void)n_in; (void)out_size;
  const float* seq = (const float*)d_in[0];
  const int*   cls = (const int*)d_in[1];
  const float* mask = (const float*)d_in[2];
  const float* Wst = (const float*)d_in[3];
  const float* bst = (const float*)d_in[4];
  const float* Wei = (const float*)d_in[5];
  const float* bei = (const float*)d_in[6];
  const float* gam = (const float*)d_in[7];
  const float* bet = (const float*)d_in[8];
  const float* Weo = (const float*)d_in[9];
  const float* beo = (const float*)d_in[10];
  const float* Wai = (const float*)d_in[11];
  const float* bai = (const float*)d_in[12];
  const float* Wao = (const float*)d_in[13];

  float* out = (float*)d_out;
  float* out0 = out;             // start_predictions  (16,512)
  float* out1 = out0 + 8192;     // end_predictions    (16,5,512)
  float* out2 = out1 + 40960;    // masked_start_logits(16,512)
  float* out3 = out2 + 8192;     // masked_end_logits  (16,5,512)
  float* out4 = out3 + 40960;    // start_top_predictions (16,5)
  float* out5 = out4 + 80;       // end_top_predictions (16,25)
  float* out6 = out5 + 400;      // class_logits (16)

  // common ws layout
  unsigned short* seqb = (unsigned short*)d_ws;            // 8192*1024 bf16
  unsigned short* w1t  = seqb + (size_t)8192 * 1024;       // 1024*1024 bf16
  float* p_ws   = (float*)(w1t + (size_t)1024 * 1024);     // 8192
  int*   idx_ws = (int*)(p_ws + 8192);                     // 128 (80 used)
  float* x2p    = (float*)(idx_ws + 128);                  // 80*1024
  float* pa     = x2p + (size_t)80 * 1024;                 // 128*1024
  float* cf     = pa + (size_t)128 * 1024;                 // 16*1024
  float* pans   = cf + (size_t)16 * 1024;                  // 128*1024
  float* unionb = pans + (size_t)128 * 1024;               // union region
  // big tier: unionb holds x2part (640*1024 f) then gemm partials (8*8192*15 f)
  size_t union_big = (size_t)8 * 8192 * KTOP * 3;          // 3.93 MB
  size_t union_small = (size_t)640 * 1024 + (size_t)8192 * KTOP * 3;  // x2part + sums
  size_t base_f = (size_t)((float*)unionb - (float*)d_ws);
  size_t need_big = (base_f + union_big) * sizeof(float);
  size_t need_small = (base_f + union_small) * sizeof(float);

  k_conv_start<<<2048, 256, 0, stream>>>(seq, seqb, Wst, bst, mask, out2);
  k_convT<<<dim3(32, 32), dim3(32, 8), 0, stream>>>(Wei, w1t);
  k_softmax_topk<<<NB, 256, 0, stream>>>(out2, out0, out4, p_ws, idx_ws);

  if (ws_size >= need_big) {
    float* x2part = unionb;
    float* part = unionb;  // reuses space after x2r consumed x2part
    k_x2p<<<dim3(NB * KTOP, 8), 256, 0, stream>>>(seq, idx_ws, Wei, x2part);
    k_x2r<<<NB * KTOP, 256, 0, stream>>>(x2part, bei, x2p);
    k_gemm_end<0><<<dim3(64, 8), 256, 0, stream>>>(seqb, w1t, x2p, gam, Weo, part);
    k_end_final<<<NB * KTOP, 256, 0, stream>>>(part, 8, gam, bet, Weo, beo, mask, out3);
  } else {
    // atomic tier (fits in round-2-proven footprint)
    float* x2part = unionb;
    float* sums = unionb + (size_t)640 * 1024;
    k_x2p<<<dim3(NB * KTOP, 8), 256, 0, stream>>>(seq, idx_ws, Wei, x2part);
    k_x2r<<<NB * KTOP, 256, 0, stream>>>(x2part, bei, x2p);
    hipMemsetAsync(sums, 0, (size_t)8192 * KTOP * 3 * sizeof(float), stream);
    k_gemm_end<1><<<dim3(64, 8), 256, 0, stream>>>(seqb, w1t, x2p, gam, Weo, sums);
    k_end_final<<<NB * KTOP, 256, 0, stream>>>(sums, 1, gam, bet, Weo, beo, mask, out3);
  }
  (void)need_small;

  k_softmax_topk<<<NB * KTOP, 256, 0, stream>>>(out3, out1, out5, nullptr, nullptr);
  k_ans_in<<<dim3(NB, 8), 256, 0, stream>>>(seq, p_ws, cls, pa, cf);
  k_ans_out_p<<<dim3(NB, 8), 256, 0, stream>>>(pa, cf, Wai, pans);
  k_ans_final<<<NB, 256, 0, stream>>>(pans, bai, Wao, out6);
}

// Round 4
// 120.344 us; speedup vs baseline: 5.6340x; 1.1961x over previous
//
#include <hip/hip_runtime.h>
#include <math.h>

#define HD   1024
#define LSEQ 512
#define NB   16
#define KTOP 5
#define NEGV 1e30f

typedef __bf16 bf16x8 __attribute__((ext_vector_type(8)));
typedef float  f32x4  __attribute__((ext_vector_type(4)));
typedef unsigned short u16x8 __attribute__((ext_vector_type(8)));

__device__ inline unsigned short f2bf(float f) {
  unsigned u = __float_as_uint(f);
  unsigned r = (u + 0x7FFFu + ((u >> 16) & 1u)) >> 16;
  return (unsigned short)r;
}
__device__ inline float bf2f(unsigned short u) {
  return __uint_as_float(((unsigned)u) << 16);
}

__device__ inline float fast_tanh(float x) {
  float e = __expf(-2.f * fabsf(x));
  float v = (1.f - e) / (1.f + e);
  return copysignf(v, x);
}

#define GLDS(g, l) __builtin_amdgcn_global_load_lds(                      \
    (const __attribute__((address_space(1))) unsigned int*)(g),          \
    (__attribute__((address_space(3))) unsigned int*)(l), 16, 0, 0)

// ---------------- K1: fused f32->bf16 conversion + start logits + W1 transpose ----------------
__global__ void k_prep(const float* __restrict__ seq,
                       unsigned short* __restrict__ seqb,
                       const float* __restrict__ Wst,
                       const float* __restrict__ bst,
                       const float* __restrict__ mask,
                       float* __restrict__ msl,
                       const float* __restrict__ Wei,
                       unsigned short* __restrict__ w1t) {
  __shared__ unsigned short tile[32][33];
  int bx = blockIdx.x;
  if (bx < 2048) {
    int wave = threadIdx.x >> 6, lane = threadIdx.x & 63;
    int row = bx * 4 + wave;
    const float4* s4 = (const float4*)(seq + (size_t)row * HD);
    const float4* w4 = (const float4*)Wst;
    ushort4* o4 = (ushort4*)(seqb + (size_t)row * HD);
    float acc = 0.f;
#pragma unroll
    for (int m = 0; m < 4; ++m) {
      int i = lane + 64 * m;
      float4 a = s4[i], w = w4[i];
      acc += a.x * w.x + a.y * w.y + a.z * w.z + a.w * w.w;
      ushort4 o;
      o.x = f2bf(a.x); o.y = f2bf(a.y); o.z = f2bf(a.z); o.w = f2bf(a.w);
      o4[i] = o;
    }
#pragma unroll
    for (int off = 32; off; off >>= 1) acc += __shfl_xor(acc, off);
    if (lane == 0) {
      float logit = acc + bst[0];
      float mv = mask[row];
      msl[row] = logit * mv - NEGV * (1.f - mv);
    }
  } else {
    int tb = bx - 2048;  // 0..1023
    int h0 = (tb & 31) * 32, d0 = (tb >> 5) * 32;
    int tx = threadIdx.x & 31, ty = threadIdx.x >> 5;  // 32 x 8
#pragma unroll
    for (int i = 0; i < 4; ++i)
      tile[ty + 8 * i][tx] = f2bf(Wei[(size_t)(h0 + ty + 8 * i) * HD + d0 + tx]);
    __syncthreads();
#pragma unroll
    for (int i = 0; i < 4; ++i)
      w1t[(size_t)(d0 + ty + 8 * i) * HD + h0 + tx] = tile[tx][ty + 8 * i];
  }
}

// ---------------- K2/K7: row log_softmax + top5 (rows of 512) ----------------
__global__ void k_softmax_topk(const float* __restrict__ xin,
                               float* __restrict__ lsm_out,
                               float* __restrict__ top_out,
                               float* __restrict__ p_out,
                               int* __restrict__ idx_out) {
  int row = blockIdx.x, t = threadIdx.x;
  int lane = t & 63, wid = t >> 6;
  __shared__ float redf[4];
  __shared__ int redi[4];
  __shared__ float bc_m, bc_s;
  __shared__ int bc_i;
  const float* x = xin + (size_t)row * LSEQ;
  float x0 = x[t], x1 = x[t + 256];

  float m = fmaxf(x0, x1);
#pragma unroll
  for (int off = 32; off; off >>= 1) m = fmaxf(m, __shfl_xor(m, off));
  if (lane == 0) redf[wid] = m;
  __syncthreads();
  if (t == 0) bc_m = fmaxf(fmaxf(redf[0], redf[1]), fmaxf(redf[2], redf[3]));
  __syncthreads();
  m = bc_m;

  float e0 = expf(x0 - m), e1 = expf(x1 - m);
  float s = e0 + e1;
#pragma unroll
  for (int off = 32; off; off >>= 1) s += __shfl_xor(s, off);
  if (lane == 0) redf[wid] = s;
  __syncthreads();
  if (t == 0) bc_s = redf[0] + redf[1] + redf[2] + redf[3];
  __syncthreads();
  s = bc_s;
  float ls = logf(s);

  lsm_out[(size_t)row * LSEQ + t] = x0 - m - ls;
  lsm_out[(size_t)row * LSEQ + t + 256] = x1 - m - ls;
  if (p_out) {
    float inv = 1.f / s;
    p_out[(size_t)row * LSEQ + t] = e0 * inv;
    p_out[(size_t)row * LSEQ + t + 256] = e1 * inv;
  }

  bool a0 = true, a1 = true;
  for (int it = 0; it < KTOP; ++it) {
    float v0 = a0 ? x0 : -INFINITY;
    float v1 = a1 ? x1 : -INFINITY;
    float bv = v0; int bi = t;
    if (v1 > bv) { bv = v1; bi = t + 256; }
#pragma unroll
    for (int off = 32; off; off >>= 1) {
      float ov = __shfl_xor(bv, off);
      int oi = __shfl_xor(bi, off);
      if (ov > bv || (ov == bv && oi < bi)) { bv = ov; bi = oi; }
    }
    __syncthreads();
    if (lane == 0) { redf[wid] = bv; redi[wid] = bi; }
    __syncthreads();
    if (t == 0) {
      float wv = redf[0]; int wi = redi[0];
      for (int w = 1; w < 4; ++w)
        if (redf[w] > wv || (redf[w] == wv && redi[w] < wi)) { wv = redf[w]; wi = redi[w]; }
      top_out[row * KTOP + it] = wv - m - ls;
      if (idx_out) idx_out[row * KTOP + it] = wi;
      bc_i = wi;
    }
    __syncthreads();
    int wi = bc_i;
    if (wi == t) a0 = false;
    if (wi == t + 256) a1 = false;
  }
}

// ---------------- K3/K4: X2' = start_feature @ W2 + b_end_in ----------------
__global__ void k_x2p(const float* __restrict__ seq,
                      const int* __restrict__ idx,
                      const float* __restrict__ Wei,
                      float* __restrict__ x2part) {
  int bk = blockIdx.x, b = bk / KTOP, s = blockIdx.y, t = threadIdx.x;
  __shared__ float srow[128];
  int l = idx[bk];
  if (t < 128) srow[t] = seq[((size_t)(b * LSEQ + l)) * HD + s * 128 + t];
  __syncthreads();
  const float* W2 = Wei + (size_t)HD * HD + (size_t)s * 128 * HD;
  float4 acc = make_float4(0.f, 0.f, 0.f, 0.f);
#pragma unroll 8
  for (int h = 0; h < 128; ++h) {
    float4 wv = *(const float4*)(W2 + (size_t)h * HD + 4 * t);
    float sv = srow[h];
    acc.x = fmaf(sv, wv.x, acc.x);
    acc.y = fmaf(sv, wv.y, acc.y);
    acc.z = fmaf(sv, wv.z, acc.z);
    acc.w = fmaf(sv, wv.w, acc.w);
  }
  *(float4*)(x2part + ((size_t)bk * 8 + s) * HD + 4 * t) = acc;
}

__global__ void k_x2r(const float* __restrict__ x2part,
                      const float* __restrict__ bei,
                      float* __restrict__ x2p) {
  int bk = blockIdx.x, t = threadIdx.x;
  float4 a = *(const float4*)(bei + 4 * t);
#pragma unroll
  for (int s = 0; s < 8; ++s) {
    float4 p = *(const float4*)(x2part + ((size_t)bk * 8 + s) * HD + 4 * t);
    a.x += p.x; a.y += p.y; a.z += p.z; a.w += p.w;
  }
  *(float4*)(x2p + (size_t)bk * HD + 4 * t) = a;
}

// ---------------- K5: pure MFMA GEMM -> X1 bf16 ----------------
// 128x128 tile, BK=64, 4 waves, double-buffered swizzled LDS, counted vmcnt.
__launch_bounds__(256, 2)
__global__ void k_gemm(const unsigned short* __restrict__ Abf,  // [8192][1024] bf16
                       const unsigned short* __restrict__ Bt,   // [1024 d][1024 h] bf16
                       unsigned short* __restrict__ X1) {       // [8192][1024] bf16
  __shared__ unsigned short As[2][128 * 64];
  __shared__ unsigned short Bs[2][128 * 64];
  int t = threadIdx.x;
  int w = t >> 6, lane = t & 63, ln = lane & 15, hi = lane >> 4;
  int wr = w >> 1, wc = w & 1;
  int R0 = blockIdx.x * 128, C0 = blockIdx.y * 128;

  f32x4 acc[4][4] = {};

#define STAGE(buf, kc)                                                        \
  do {                                                                        \
    _Pragma("unroll")                                                         \
    for (int p_ = 0; p_ < 4; ++p_) {                                          \
      int rr_ = p_ * 32 + (t >> 3);                                           \
      int cc_ = (t & 7) ^ (rr_ & 7);                                          \
      GLDS(Abf + (size_t)(R0 + rr_) * HD + (kc) + cc_ * 8,                    \
           &As[buf][p_ * 2048 + w * 512]);                                    \
      GLDS(Bt + (size_t)(C0 + rr_) * HD + (kc) + cc_ * 8,                     \
           &Bs[buf][p_ * 2048 + w * 512]);                                    \
    }                                                                         \
  } while (0)

  STAGE(0, 0);
  for (int it = 0; it < 16; ++it) {
    int cur = it & 1;
    if (it < 15) {
      STAGE(cur ^ 1, (it + 1) * 64);
      asm volatile("s_waitcnt vmcnt(8)" ::: "memory");
    } else {
      asm volatile("s_waitcnt vmcnt(0)" ::: "memory");
    }
    __builtin_amdgcn_s_barrier();
    __builtin_amdgcn_sched_barrier(0);
#pragma unroll
    for (int ks = 0; ks < 2; ++ks) {
      bf16x8 av[4], bv[4];
#pragma unroll
      for (int m = 0; m < 4; ++m) {
        int r = wr * 64 + m * 16 + ln;
        av[m] = *(const bf16x8*)(const void*)&As[cur][r * 64 + (((ks * 4 + hi) ^ (r & 7)) * 8)];
      }
#pragma unroll
      for (int n = 0; n < 4; ++n) {
        int r = wc * 64 + n * 16 + ln;
        bv[n] = *(const bf16x8*)(const void*)&Bs[cur][r * 64 + (((ks * 4 + hi) ^ (r & 7)) * 8)];
      }
#pragma unroll
      for (int m = 0; m < 4; ++m)
#pragma unroll
        for (int n = 0; n < 4; ++n)
          acc[m][n] = __builtin_amdgcn_mfma_f32_16x16x32_bf16(av[m], bv[n], acc[m][n], 0, 0, 0);
    }
    __builtin_amdgcn_sched_barrier(0);
    __builtin_amdgcn_s_barrier();
  }
#undef STAGE

  // store X1 as bf16
#pragma unroll
  for (int m = 0; m < 4; ++m)
#pragma unroll
    for (int j = 0; j < 4; ++j) {
      int row = R0 + wr * 64 + m * 16 + hi * 4 + j;
#pragma unroll
      for (int n = 0; n < 4; ++n) {
        int col = C0 + wc * 64 + n * 16 + ln;
        X1[(size_t)row * HD + col] = f2bf(acc[m][n][j]);
      }
    }
}

// ---------------- K6: per-row tanh + LN sums + end logit + mask ----------------
// one wave per row; 4 rows per block; 2048 blocks.
__global__ void k_endrow(const unsigned short* __restrict__ X1,
                         const float* __restrict__ x2p,
                         const float* __restrict__ gamma,
                         const float* __restrict__ beta,
                         const float* __restrict__ Wout,
                         const float* __restrict__ beo,
                         const float* __restrict__ mask,
                         float* __restrict__ mel) {
  int t = threadIdx.x, wave = t >> 6, lane = t & 63;
  int row = blockIdx.x * 4 + wave;
  int b = row >> 9, l = row & 511;
  __shared__ float red[4][2];
  __shared__ float sgb[2];

  float pg = 0.f, pb = 0.f;
  for (int i = t; i < HD; i += 256) {
    float wv = Wout[i];
    pg += gamma[i] * wv;
    pb += beta[i] * wv;
  }
#pragma unroll
  for (int off = 32; off; off >>= 1) {
    pg += __shfl_xor(pg, off);
    pb += __shfl_xor(pb, off);
  }
  if (lane == 0) { red[wave][0] = pg; red[wave][1] = pb; }
  __syncthreads();
  if (t == 0) {
    sgb[0] = red[0][0] + red[1][0] + red[2][0] + red[3][0];
    sgb[1] = red[0][1] + red[1][1] + red[2][1] + red[3][1] + beo[0];
  }
  __syncthreads();
  float sG = sgb[0], sBW = sgb[1];

  int c0 = lane * 16;
  const u16x8* xp = (const u16x8*)(X1 + (size_t)row * HD + c0);
  u16x8 pk0 = xp[0], pk1 = xp[1];
  float xv[16], gw[16];
#pragma unroll
  for (int i = 0; i < 8; ++i) { xv[i] = bf2f(pk0[i]); xv[8 + i] = bf2f(pk1[i]); }
#pragma unroll
  for (int q = 0; q < 4; ++q) {
    float4 g4 = *(const float4*)(gamma + c0 + 4 * q);
    float4 w4 = *(const float4*)(Wout + c0 + 4 * q);
    gw[4 * q + 0] = g4.x * w4.x; gw[4 * q + 1] = g4.y * w4.y;
    gw[4 * q + 2] = g4.z * w4.z; gw[4 * q + 3] = g4.w * w4.w;
  }
  float mv = mask[row];

#pragma unroll
  for (int k = 0; k < KTOP; ++k) {
    const float4* x2 = (const float4*)(x2p + ((size_t)b * KTOP + k) * HD + c0);
    float sv = 0.f, s2 = 0.f, sg = 0.f;
#pragma unroll
    for (int q = 0; q < 4; ++q) {
      float4 xq = x2[q];
      float vz[4];
      vz[0] = fast_tanh(xv[4 * q + 0] + xq.x);
      vz[1] = fast_tanh(xv[4 * q + 1] + xq.y);
      vz[2] = fast_tanh(xv[4 * q + 2] + xq.z);
      vz[3] = fast_tanh(xv[4 * q + 3] + xq.w);
#pragma unroll
      for (int e = 0; e < 4; ++e) {
        sv += vz[e];
        s2 = fmaf(vz[e], vz[e], s2);
        sg = fmaf(vz[e], gw[4 * q + e], sg);
      }
    }
#pragma unroll
    for (int off = 32; off; off >>= 1) {
      sv += __shfl_xor(sv, off);
      s2 += __shfl_xor(s2, off);
      sg += __shfl_xor(sg, off);
    }
    if (lane == 0) {
      float mu = sv * (1.f / (float)HD);
      float var = s2 * (1.f / (float)HD) - mu * mu;
      float rr = rsqrtf(var + 1e-12f);
      float logit = rr * (sg - mu * sG) + sBW;
      mel[((size_t)b * KTOP + k) * LSEQ + l] = logit * mv - NEGV * (1.f - mv);
    }
  }
}

// ---------------- K8/K9/K10: answer path ----------------
__global__ void k_ans_in(const float* __restrict__ seq,
                         const float* __restrict__ p_ws,
                         const int* __restrict__ cls,
                         float* __restrict__ pa,   // (16,32,1024)
                         float* __restrict__ cf) {
  int b = blockIdx.x, s = blockIdx.y, t = threadIdx.x;
  __shared__ float ps[16];
  if (t < 16) ps[t] = p_ws[b * LSEQ + s * 16 + t];
  __syncthreads();
  const float* sb = seq + (size_t)(b * LSEQ + s * 16) * HD;
  float4 acc = make_float4(0.f, 0.f, 0.f, 0.f);
#pragma unroll
  for (int r = 0; r < 16; ++r) {
    float4 v = *(const float4*)(sb + (size_t)r * HD + 4 * t);
    float p = ps[r];
    acc.x = fmaf(p, v.x, acc.x);
    acc.y = fmaf(p, v.y, acc.y);
    acc.z = fmaf(p, v.z, acc.z);
    acc.w = fmaf(p, v.w, acc.w);
  }
  *(float4*)(pa + ((size_t)b * 32 + s) * HD + 4 * t) = acc;
  if (s == 0) {
    int ci = cls[b];
    *(float4*)(cf + (size_t)b * HD + 4 * t) =
        *(const float4*)(seq + (size_t)(b * LSEQ + ci) * HD + 4 * t);
  }
}

__global__ void k_ans_mid(const float* __restrict__ pa,
                          const float* __restrict__ cf,
                          const float* __restrict__ Wai,
                          float* __restrict__ pans) {  // (16,16,1024)
  int b = blockIdx.x, c = blockIdx.y, t = threadIdx.x;
  __shared__ float a_s[128];
  if (t < 128) {
    int i = c * 128 + t;
    float av;
    if (i < HD) {
      av = 0.f;
#pragma unroll
      for (int s = 0; s < 32; ++s) av += pa[((size_t)b * 32 + s) * HD + i];
    } else {
      av = cf[(size_t)b * HD + (i - HD)];
    }
    a_s[t] = av;
  }
  __syncthreads();
  float4 acc = make_float4(0.f, 0.f, 0.f, 0.f);
#pragma unroll 8
  for (int r = 0; r < 128; ++r) {
    float4 wv = *(const float4*)(Wai + (size_t)(c * 128 + r) * HD + 4 * t);
    float a = a_s[r];
    acc.x = fmaf(a, wv.x, acc.x);
    acc.y = fmaf(a, wv.y, acc.y);
    acc.z = fmaf(a, wv.z, acc.z);
    acc.w = fmaf(a, wv.w, acc.w);
  }
  *(float4*)(pans + ((size_t)b * 16 + c) * HD + 4 * t) = acc;
}

__global__ void k_ans_final(const float* __restrict__ pans,
                            const float* __restrict__ bai,
                            const float* __restrict__ Wao,
                            float* __restrict__ out6) {
  int b = blockIdx.x, t = threadIdx.x, lane = t & 63, wid = t >> 6;
  __shared__ float red[4];
  float4 a = *(const float4*)(bai + 4 * t);
#pragma unroll
  for (int c = 0; c < 16; ++c) {
    float4 p = *(const float4*)(pans + ((size_t)b * 16 + c) * HD + 4 * t);
    a.x += p.x; a.y += p.y; a.z += p.z; a.w += p.w;
  }
  float4 wo = *(const float4*)(Wao + 4 * t);
  float part = fast_tanh(a.x) * wo.x + fast_tanh(a.y) * wo.y +
               fast_tanh(a.z) * wo.z + fast_tanh(a.w) * wo.w;
#pragma unroll
  for (int off = 32; off; off >>= 1) part += __shfl_xor(part, off);
  if (lane == 0) red[wid] = part;
  __syncthreads();
  if (t == 0) out6[b] = red[0] + red[1] + red[2] + red[3];
}

// ================= fallback tier: round-3 fused gemm (atomic) =================
__launch_bounds__(256, 2)
__global__ void k_gemm_end_at(const unsigned short* __restrict__ Abf,
                              const unsigned short* __restrict__ Bt,
                              const float* __restrict__ x2p,
                              const float* __restrict__ gamma,
                              const float* __restrict__ Wout,
                              float* __restrict__ outp) {
  __shared__ unsigned short As[2][128 * 64];
  __shared__ unsigned short Bs[2][128 * 64];
  int t = threadIdx.x;
  int w = t >> 6, lane = t & 63, ln = lane & 15, hi = lane >> 4;
  int wr = w >> 1, wc = w & 1;
  int R0 = blockIdx.x * 128, C0 = blockIdx.y * 128;
  int b = R0 >> 9;
  f32x4 acc[4][4] = {};
#define STAGE(buf, kc)                                                        \
  do {                                                                        \
    _Pragma("unroll")                                                         \
    for (int p_ = 0; p_ < 4; ++p_) {                                          \
      int rr_ = p_ * 32 + (t >> 3);                                           \
      int cc_ = (t & 7) ^ (rr_ & 7);                                          \
      GLDS(Abf + (size_t)(R0 + rr_) * HD + (kc) + cc_ * 8,                    \
           &As[buf][p_ * 2048 + w * 512]);                                    \
      GLDS(Bt + (size_t)(C0 + rr_) * HD + (kc) + cc_ * 8,                     \
           &Bs[buf][p_ * 2048 + w * 512]);                                    \
    }                                                                         \
  } while (0)
  STAGE(0, 0);
  for (int it = 0; it < 16; ++it) {
    int cur = it & 1;
    if (it < 15) {
      STAGE(cur ^ 1, (it + 1) * 64);
      asm volatile("s_waitcnt vmcnt(8)" ::: "memory");
    } else {
      asm volatile("s_waitcnt vmcnt(0)" ::: "memory");
    }
    __builtin_amdgcn_s_barrier();
    __builtin_amdgcn_sched_barrier(0);
#pragma unroll
    for (int ks = 0; ks < 2; ++ks) {
      bf16x8 av[4], bv[4];
#pragma unroll
      for (int m = 0; m < 4; ++m) {
        int r = wr * 64 + m * 16 + ln;
        av[m] = *(const bf16x8*)(const void*)&As[cur][r * 64 + (((ks * 4 + hi) ^ (r & 7)) * 8)];
      }
#pragma unroll
      for (int n = 0; n < 4; ++n) {
        int r = wc * 64 + n * 16 + ln;
        bv[n] = *(const bf16x8*)(const void*)&Bs[cur][r * 64 + (((ks * 4 + hi) ^ (r & 7)) * 8)];
      }
#pragma unroll
      for (int m = 0; m < 4; ++m)
#pragma unroll
        for (int n = 0; n < 4; ++n)
          acc[m][n] = __builtin_amdgcn_mfma_f32_16x16x32_bf16(av[m], bv[n], acc[m][n], 0, 0, 0);
    }
    __builtin_amdgcn_sched_barrier(0);
    __builtin_amdgcn_s_barrier();
  }
#undef STAGE
  float gsv[4];
  float x2v[4][KTOP];
#pragma unroll
  for (int n = 0; n < 4; ++n) {
    int c = C0 + wc * 64 + n * 16 + ln;
    gsv[n] = gamma[c] * Wout[c];
#pragma unroll
    for (int k = 0; k < KTOP; ++k) x2v[n][k] = x2p[((size_t)b * KTOP + k) * HD + c];
  }
#pragma unroll
  for (int m = 0; m < 4; ++m)
#pragma unroll
    for (int j = 0; j < 4; ++j) {
      int row = R0 + wr * 64 + m * 16 + hi * 4 + j;
#pragma unroll
      for (int k = 0; k < KTOP; ++k) {
        float sv = 0.f, s2 = 0.f, sg = 0.f;
#pragma unroll
        for (int n = 0; n < 4; ++n) {
          float v = fast_tanh(acc[m][n][j] + x2v[n][k]);
          sv += v; s2 += v * v; sg += v * gsv[n];
        }
#pragma unroll
        for (int off = 8; off; off >>= 1) {
          sv += __shfl_xor(sv, off);
          s2 += __shfl_xor(s2, off);
          sg += __shfl_xor(sg, off);
        }
        if (ln == 0) {
          float* p = outp + ((size_t)row * KTOP + k) * 3;
          atomicAdd(p, sv);
          atomicAdd(p + 1, s2);
          atomicAdd(p + 2, sg);
        }
      }
    }
}

__global__ void k_end_final(const float* __restrict__ sums,
                            const float* __restrict__ gamma,
                            const float* __restrict__ beta,
                            const float* __restrict__ Wout,
                            const float* __restrict__ beo,
                            const float* __restrict__ mask,
                            float* __restrict__ mel) {
  int bk = blockIdx.x, b = bk / KTOP, k = bk % KTOP;
  int t = threadIdx.x, lane = t & 63, wid = t >> 6;
  __shared__ float red[4][2];
  float pg = 0.f, pb = 0.f;
  for (int i = t; i < HD; i += 256) {
    float wv = Wout[i];
    pg += gamma[i] * wv;
    pb += beta[i] * wv;
  }
#pragma unroll
  for (int off = 32; off; off >>= 1) {
    pg += __shfl_xor(pg, off);
    pb += __shfl_xor(pb, off);
  }
  if (lane == 0) { red[wid][0] = pg; red[wid][1] = pb; }
  __syncthreads();
  float sG = red[0][0] + red[1][0] + red[2][0] + red[3][0];
  float sBW = red[0][1] + red[1][1] + red[2][1] + red[3][1] + beo[0];
  for (int l = t; l < LSEQ; l += 256) {
    int row = b * LSEQ + l;
    const float* s = sums + ((size_t)row * KTOP + k) * 3;
    float sv = s[0], s2 = s[1], sg = s[2];
    float mu = sv * (1.f / (float)HD);
    float var = s2 * (1.f / (float)HD) - mu * mu;
    float rr = rsqrtf(var + 1e-12f);
    float logit = rr * (sg - mu * sG) + sBW;
    float mv = mask[row];
    mel[((size_t)b * KTOP + k) * LSEQ + l] = logit * mv - NEGV * (1.f - mv);
  }
}

// ---------------- host ----------------
extern "C" void kernel_launch(void* const* d_in, const int* in_sizes, int n_in,
                              void* d_out, int out_size, void* d_ws, size_t ws_size,
                              hipStream_t stream) {
  (void)in_sizes; (void)n_in; (void)out_size;
  const float* seq = (const float*)d_in[0];
  const int*   cls = (const int*)d_in[1];
  const float* mask = (const float*)d_in[2];
  const float* Wst = (const float*)d_in[3];
  const float* bst = (const float*)d_in[4];
  const float* Wei = (const float*)d_in[5];
  const float* bei = (const float*)d_in[6];
  const float* gam = (const float*)d_in[7];
  const float* bet = (const float*)d_in[8];
  const float* Weo = (const float*)d_in[9];
  const float* beo = (const float*)d_in[10];
  const float* Wai = (const float*)d_in[11];
  const float* bai = (const float*)d_in[12];
  const float* Wao = (const float*)d_in[13];

  float* out = (float*)d_out;
  float* out0 = out;             // start_predictions  (16,512)
  float* out1 = out0 + 8192;     // end_predictions    (16,5,512)
  float* out2 = out1 + 40960;    // masked_start_logits(16,512)
  float* out3 = out2 + 8192;     // masked_end_logits  (16,5,512)
  float* out4 = out3 + 40960;    // start_top_predictions (16,5)
  float* out5 = out4 + 80;       // end_top_predictions (16,25)
  float* out6 = out5 + 400;      // class_logits (16)

  // ws layout
  char* p = (char*)d_ws;
  unsigned short* seqb = (unsigned short*)p;  p += (size_t)8192 * 1024 * 2;  // 16MB
  unsigned short* w1t  = (unsigned short*)p;  p += (size_t)1024 * 1024 * 2;  // 2MB
  float* p_ws   = (float*)p;                  p += 8192 * 4;
  int*   idx_ws = (int*)p;                    p += 128 * 4;
  float* x2p    = (float*)p;                  p += (size_t)80 * 1024 * 4;
  float* pa     = (float*)p;                  p += (size_t)16 * 32 * 1024 * 4;  // 2MB
  float* cf     = (float*)p;                  p += (size_t)16 * 1024 * 4;
  float* pans   = (float*)p;                  p += (size_t)16 * 16 * 1024 * 4;  // 1MB
  // tail union: x2part (2.62MB) consumed before X1 (16MB) is written
  float* x2part = (float*)p;
  unsigned short* x1 = (unsigned short*)p;
  float* sums = (float*)(p + (size_t)640 * 1024 * 4);  // small tier only
  size_t base = (size_t)(p - (char*)d_ws);
  size_t need_big = base + (size_t)8192 * 1024 * 2;
  size_t need_small = base + (size_t)640 * 1024 * 4 + (size_t)8192 * KTOP * 3 * 4;

  k_prep<<<3072, 256, 0, stream>>>(seq, seqb, Wst, bst, mask, out2, Wei, w1t);
  k_softmax_topk<<<NB, 256, 0, stream>>>(out2, out0, out4, p_ws, idx_ws);
  k_x2p<<<dim3(NB * KTOP, 8), 256, 0, stream>>>(seq, idx_ws, Wei, x2part);
  k_x2r<<<NB * KTOP, 256, 0, stream>>>(x2part, bei, x2p);

  if (ws_size >= need_big) {
    k_gemm<<<dim3(64, 8), 256, 0, stream>>>(seqb, w1t, x1);
    k_endrow<<<2048, 256, 0, stream>>>(x1, x2p, gam, bet, Weo, beo, mask, out3);
  } else if (ws_size >= need_small) {
    hipMemsetAsync(sums, 0, (size_t)8192 * KTOP * 3 * sizeof(float), stream);
    k_gemm_end_at<<<dim3(64, 8), 256, 0, stream>>>(seqb, w1t, x2p, gam, Weo, sums);
    k_end_final<<<NB * KTOP, 256, 0, stream>>>(sums, gam, bet, Weo, beo, mask, out3);
  }

  k_softmax_topk<<<NB * KTOP, 256, 0, stream>>>(out3, out1, out5, nullptr, nullptr);
  k_ans_in<<<dim3(NB, 32), 256, 0, stream>>>(seq, p_ws, cls, pa, cf);
  k_ans_mid<<<dim3(NB, 16), 256, 0, stream>>>(pa, cf, Wai, pans);
  k_ans_final<<<NB, 256, 0, stream>>>(pans, bai, Wao, out6);
}

// Round 5
// 105.380 us; speedup vs baseline: 6.4341x; 1.1420x over previous
//
#include <hip/hip_runtime.h>
#include <math.h>

#define HD   1024
#define LSEQ 512
#define NB   16
#define KTOP 5
#define NEGV 1e30f

typedef __bf16 bf16x8 __attribute__((ext_vector_type(8)));
typedef float  f32x4  __attribute__((ext_vector_type(4)));

__device__ inline unsigned short f2bf(float f) {
  unsigned u = __float_as_uint(f);
  unsigned r = (u + 0x7FFFu + ((u >> 16) & 1u)) >> 16;
  return (unsigned short)r;
}
__device__ inline float bf2f(unsigned short u) {
  return __uint_as_float(((unsigned)u) << 16);
}

__device__ inline float fast_tanh(float x) {
  float e = __expf(-2.f * fabsf(x));
  float v = (1.f - e) / (1.f + e);
  return copysignf(v, x);
}

// tanh(arg) where pre-scaled xs = A*arg, A = 2*log2(e):
// tanh = 1 - 2*rcp(1 + exp2(xs)). Handles +-inf saturation correctly.
__device__ inline float tanh_scaled(float xs) {
  float e = __builtin_amdgcn_exp2f(xs);
  float r = __builtin_amdgcn_rcpf(1.f + e);
  return fmaf(-2.f, r, 1.f);
}

#define GLDS(g, l) __builtin_amdgcn_global_load_lds(                      \
    (const __attribute__((address_space(1))) unsigned int*)(g),          \
    (__attribute__((address_space(3))) unsigned int*)(l), 16, 0, 0)

// ---------------- K1: f32->bf16 conv + start logits + W1 transpose + LN consts ----------------
__global__ void k_prep(const float* __restrict__ seq,
                       unsigned short* __restrict__ seqb,
                       const float* __restrict__ Wst,
                       const float* __restrict__ bst,
                       const float* __restrict__ mask,
                       float* __restrict__ msl,
                       const float* __restrict__ Wei,
                       unsigned short* __restrict__ w1t,
                       const float* __restrict__ gam,
                       const float* __restrict__ bet,
                       const float* __restrict__ Weo,
                       const float* __restrict__ beo,
                       float* __restrict__ gw_ws,
                       float* __restrict__ sgb_ws) {
  __shared__ unsigned short tile[32][33];
  __shared__ float redp[4][2];
  int bx = blockIdx.x;
  if (bx < 2048) {
    int wave = threadIdx.x >> 6, lane = threadIdx.x & 63;
    int row = bx * 4 + wave;
    const float4* s4 = (const float4*)(seq + (size_t)row * HD);
    const float4* w4 = (const float4*)Wst;
    ushort4* o4 = (ushort4*)(seqb + (size_t)row * HD);
    float acc = 0.f;
#pragma unroll
    for (int m = 0; m < 4; ++m) {
      int i = lane + 64 * m;
      float4 a = s4[i], w = w4[i];
      acc += a.x * w.x + a.y * w.y + a.z * w.z + a.w * w.w;
      ushort4 o;
      o.x = f2bf(a.x); o.y = f2bf(a.y); o.z = f2bf(a.z); o.w = f2bf(a.w);
      o4[i] = o;
    }
#pragma unroll
    for (int off = 32; off; off >>= 1) acc += __shfl_xor(acc, off);
    if (lane == 0) {
      float logit = acc + bst[0];
      float mv = mask[row];
      msl[row] = logit * mv - NEGV * (1.f - mv);
    }
  } else if (bx < 3072) {
    int tb = bx - 2048;  // 0..1023
    int h0 = (tb & 31) * 32, d0 = (tb >> 5) * 32;
    int tx = threadIdx.x & 31, ty = threadIdx.x >> 5;  // 32 x 8
#pragma unroll
    for (int i = 0; i < 4; ++i)
      tile[ty + 8 * i][tx] = f2bf(Wei[(size_t)(h0 + ty + 8 * i) * HD + d0 + tx]);
    __syncthreads();
#pragma unroll
    for (int i = 0; i < 4; ++i)
      w1t[(size_t)(d0 + ty + 8 * i) * HD + h0 + tx] = tile[tx][ty + 8 * i];
  } else {
    // gw = gamma*Wout; sG = sum gw; sBW = sum beta*Wout + beo
    int t = threadIdx.x, wave = t >> 6, lane = t & 63;
    float4 g = ((const float4*)gam)[t];
    float4 w = ((const float4*)Weo)[t];
    float4 bv = ((const float4*)bet)[t];
    float4 gwv = make_float4(g.x * w.x, g.y * w.y, g.z * w.z, g.w * w.w);
    ((float4*)gw_ws)[t] = gwv;
    float pg = gwv.x + gwv.y + gwv.z + gwv.w;
    float pb = bv.x * w.x + bv.y * w.y + bv.z * w.z + bv.w * w.w;
#pragma unroll
    for (int off = 32; off; off >>= 1) {
      pg += __shfl_xor(pg, off);
      pb += __shfl_xor(pb, off);
    }
    if (lane == 0) { redp[wave][0] = pg; redp[wave][1] = pb; }
    __syncthreads();
    if (t == 0) {
      sgb_ws[0] = redp[0][0] + redp[1][0] + redp[2][0] + redp[3][0];
      sgb_ws[1] = redp[0][1] + redp[1][1] + redp[2][1] + redp[3][1] + beo[0];
    }
  }
}

// ---------------- K2/K7: row log_softmax + top5 (rows of 512) ----------------
__global__ void k_softmax_topk(const float* __restrict__ xin,
                               float* __restrict__ lsm_out,
                               float* __restrict__ top_out,
                               float* __restrict__ p_out,
                               int* __restrict__ idx_out) {
  int row = blockIdx.x, t = threadIdx.x;
  int lane = t & 63, wid = t >> 6;
  __shared__ float redf[4];
  __shared__ int redi[4];
  __shared__ float bc_m, bc_s;
  __shared__ int bc_i;
  const float* x = xin + (size_t)row * LSEQ;
  float x0 = x[t], x1 = x[t + 256];

  float m = fmaxf(x0, x1);
#pragma unroll
  for (int off = 32; off; off >>= 1) m = fmaxf(m, __shfl_xor(m, off));
  if (lane == 0) redf[wid] = m;
  __syncthreads();
  if (t == 0) bc_m = fmaxf(fmaxf(redf[0], redf[1]), fmaxf(redf[2], redf[3]));
  __syncthreads();
  m = bc_m;

  float e0 = expf(x0 - m), e1 = expf(x1 - m);
  float s = e0 + e1;
#pragma unroll
  for (int off = 32; off; off >>= 1) s += __shfl_xor(s, off);
  if (lane == 0) redf[wid] = s;
  __syncthreads();
  if (t == 0) bc_s = redf[0] + redf[1] + redf[2] + redf[3];
  __syncthreads();
  s = bc_s;
  float ls = logf(s);

  lsm_out[(size_t)row * LSEQ + t] = x0 - m - ls;
  lsm_out[(size_t)row * LSEQ + t + 256] = x1 - m - ls;
  if (p_out) {
    float inv = 1.f / s;
    p_out[(size_t)row * LSEQ + t] = e0 * inv;
    p_out[(size_t)row * LSEQ + t + 256] = e1 * inv;
  }

  bool a0 = true, a1 = true;
  for (int it = 0; it < KTOP; ++it) {
    float v0 = a0 ? x0 : -INFINITY;
    float v1 = a1 ? x1 : -INFINITY;
    float bv = v0; int bi = t;
    if (v1 > bv) { bv = v1; bi = t + 256; }
#pragma unroll
    for (int off = 32; off; off >>= 1) {
      float ov = __shfl_xor(bv, off);
      int oi = __shfl_xor(bi, off);
      if (ov > bv || (ov == bv && oi < bi)) { bv = ov; bi = oi; }
    }
    __syncthreads();
    if (lane == 0) { redf[wid] = bv; redi[wid] = bi; }
    __syncthreads();
    if (t == 0) {
      float wv = redf[0]; int wi = redi[0];
      for (int w = 1; w < 4; ++w)
        if (redf[w] > wv || (redf[w] == wv && redi[w] < wi)) { wv = redf[w]; wi = redi[w]; }
      top_out[row * KTOP + it] = wv - m - ls;
      if (idx_out) idx_out[row * KTOP + it] = wi;
      bc_i = wi;
    }
    __syncthreads();
    int wi = bc_i;
    if (wi == t) a0 = false;
    if (wi == t + 256) a1 = false;
  }
}

// ---------------- K3/K4: X2' = start_feature @ W2 + b_end_in ----------------
__global__ void k_x2p(const float* __restrict__ seq,
                      const int* __restrict__ idx,
                      const float* __restrict__ Wei,
                      float* __restrict__ x2part) {
  int bk = blockIdx.x, b = bk / KTOP, s = blockIdx.y, t = threadIdx.x;
  __shared__ float srow[128];
  int l = idx[bk];
  if (t < 128) srow[t] = seq[((size_t)(b * LSEQ + l)) * HD + s * 128 + t];
  __syncthreads();
  const float* W2 = Wei + (size_t)HD * HD + (size_t)s * 128 * HD;
  float4 acc = make_float4(0.f, 0.f, 0.f, 0.f);
#pragma unroll 8
  for (int h = 0; h < 128; ++h) {
    float4 wv = *(const float4*)(W2 + (size_t)h * HD + 4 * t);
    float sv = srow[h];
    acc.x = fmaf(sv, wv.x, acc.x);
    acc.y = fmaf(sv, wv.y, acc.y);
    acc.z = fmaf(sv, wv.z, acc.z);
    acc.w = fmaf(sv, wv.w, acc.w);
  }
  *(float4*)(x2part + ((size_t)bk * 8 + s) * HD + 4 * t) = acc;
}

__global__ void k_x2r(const float* __restrict__ x2part,
                      const float* __restrict__ bei,
                      float* __restrict__ x2p) {
  int bk = blockIdx.x, t = threadIdx.x;
  float4 a = *(const float4*)(bei + 4 * t);
#pragma unroll
  for (int s = 0; s < 8; ++s) {
    float4 p = *(const float4*)(x2part + ((size_t)bk * 8 + s) * HD + 4 * t);
    a.x += p.x; a.y += p.y; a.z += p.z; a.w += p.w;
  }
  *(float4*)(x2p + (size_t)bk * HD + 4 * t) = a;
}

// ---------------- K5: pure MFMA GEMM -> X1 bf16 ----------------
__launch_bounds__(256, 2)
__global__ void k_gemm(const unsigned short* __restrict__ Abf,
                       const unsigned short* __restrict__ Bt,
                       unsigned short* __restrict__ X1) {
  __shared__ unsigned short As[2][128 * 64];
  __shared__ unsigned short Bs[2][128 * 64];
  int t = threadIdx.x;
  int w = t >> 6, lane = t & 63, ln = lane & 15, hi = lane >> 4;
  int wr = w >> 1, wc = w & 1;
  int R0 = blockIdx.x * 128, C0 = blockIdx.y * 128;

  f32x4 acc[4][4] = {};

#define STAGE(buf, kc)                                                        \
  do {                                                                        \
    _Pragma("unroll")                                                         \
    for (int p_ = 0; p_ < 4; ++p_) {                                          \
      int rr_ = p_ * 32 + (t >> 3);                                           \
      int cc_ = (t & 7) ^ (rr_ & 7);                                          \
      GLDS(Abf + (size_t)(R0 + rr_) * HD + (kc) + cc_ * 8,                    \
           &As[buf][p_ * 2048 + w * 512]);                                    \
      GLDS(Bt + (size_t)(C0 + rr_) * HD + (kc) + cc_ * 8,                     \
           &Bs[buf][p_ * 2048 + w * 512]);                                    \
    }                                                                         \
  } while (0)

  STAGE(0, 0);
  for (int it = 0; it < 16; ++it) {
    int cur = it & 1;
    if (it < 15) {
      STAGE(cur ^ 1, (it + 1) * 64);
      asm volatile("s_waitcnt vmcnt(8)" ::: "memory");
    } else {
      asm volatile("s_waitcnt vmcnt(0)" ::: "memory");
    }
    __builtin_amdgcn_s_barrier();
    __builtin_amdgcn_sched_barrier(0);
#pragma unroll
    for (int ks = 0; ks < 2; ++ks) {
      bf16x8 av[4], bv[4];
#pragma unroll
      for (int m = 0; m < 4; ++m) {
        int r = wr * 64 + m * 16 + ln;
        av[m] = *(const bf16x8*)(const void*)&As[cur][r * 64 + (((ks * 4 + hi) ^ (r & 7)) * 8)];
      }
#pragma unroll
      for (int n = 0; n < 4; ++n) {
        int r = wc * 64 + n * 16 + ln;
        bv[n] = *(const bf16x8*)(const void*)&Bs[cur][r * 64 + (((ks * 4 + hi) ^ (r & 7)) * 8)];
      }
#pragma unroll
      for (int m = 0; m < 4; ++m)
#pragma unroll
        for (int n = 0; n < 4; ++n)
          acc[m][n] = __builtin_amdgcn_mfma_f32_16x16x32_bf16(av[m], bv[n], acc[m][n], 0, 0, 0);
    }
    __builtin_amdgcn_sched_barrier(0);
    __builtin_amdgcn_s_barrier();
  }
#undef STAGE

#pragma unroll
  for (int m = 0; m < 4; ++m)
#pragma unroll
    for (int j = 0; j < 4; ++j) {
      int row = R0 + wr * 64 + m * 16 + hi * 4 + j;
#pragma unroll
      for (int n = 0; n < 4; ++n) {
        int col = C0 + wc * 64 + n * 16 + ln;
        X1[(size_t)row * HD + col] = f2bf(acc[m][n][j]);
      }
    }
}

// ---------------- K6: per-row tanh + LN sums + end logit + mask ----------------
// 4 rows/block (one wave each), x2p staged+prescaled in LDS, rcp-based tanh.
__launch_bounds__(256)
__global__ void k_endrow(const unsigned short* __restrict__ X1,
                         const float* __restrict__ x2p,
                         const float* __restrict__ gw_ws,
                         const float* __restrict__ sgb_ws,
                         const float* __restrict__ mask,
                         float* __restrict__ mel) {
  __shared__ float x2s[KTOP * HD];  // 20KB, prescaled by A
  const float A = 2.885390081777927f;  // 2*log2(e)
  int t = threadIdx.x, wave = t >> 6, lane = t & 63;
  int row = blockIdx.x * 4 + wave;
  int b = row >> 9, l = row & 511;

  // stage x2p[b] * A
  {
    const float4* src = (const float4*)(x2p + (size_t)b * KTOP * HD);
    float4* dst = (float4*)x2s;
    for (int i = t; i < KTOP * HD / 4; i += 256) {
      float4 v = src[i];
      dst[i] = make_float4(v.x * A, v.y * A, v.z * A, v.w * A);
    }
  }

  // per-lane columns: q*256 + lane*4 + {0..3}
  float xs[16], gwr[16];
  const unsigned short* xrow = X1 + (size_t)row * HD + lane * 4;
#pragma unroll
  for (int q = 0; q < 4; ++q) {
    ushort4 u = *(const ushort4*)(xrow + q * 256);
    xs[4 * q + 0] = bf2f(u.x) * A;
    xs[4 * q + 1] = bf2f(u.y) * A;
    xs[4 * q + 2] = bf2f(u.z) * A;
    xs[4 * q + 3] = bf2f(u.w) * A;
    float4 g = *(const float4*)(gw_ws + q * 256 + lane * 4);
    gwr[4 * q + 0] = g.x; gwr[4 * q + 1] = g.y;
    gwr[4 * q + 2] = g.z; gwr[4 * q + 3] = g.w;
  }
  float mv = mask[row];
  float sG = sgb_ws[0], sBW = sgb_ws[1];
  __syncthreads();

#pragma unroll
  for (int k = 0; k < KTOP; ++k) {
    float sv = 0.f, s2 = 0.f, sg = 0.f;
#pragma unroll
    for (int q = 0; q < 4; ++q) {
      float4 xq = *(const float4*)&x2s[k * HD + q * 256 + lane * 4];
      float v0 = tanh_scaled(xs[4 * q + 0] + xq.x);
      float v1 = tanh_scaled(xs[4 * q + 1] + xq.y);
      float v2 = tanh_scaled(xs[4 * q + 2] + xq.z);
      float v3 = tanh_scaled(xs[4 * q + 3] + xq.w);
      sv += v0 + v1 + v2 + v3;
      s2 = fmaf(v0, v0, s2); s2 = fmaf(v1, v1, s2);
      s2 = fmaf(v2, v2, s2); s2 = fmaf(v3, v3, s2);
      sg = fmaf(v0, gwr[4 * q + 0], sg); sg = fmaf(v1, gwr[4 * q + 1], sg);
      sg = fmaf(v2, gwr[4 * q + 2], sg); sg = fmaf(v3, gwr[4 * q + 3], sg);
    }
#pragma unroll
    for (int off = 32; off; off >>= 1) {
      sv += __shfl_xor(sv, off);
      s2 += __shfl_xor(s2, off);
      sg += __shfl_xor(sg, off);
    }
    if (lane == 0) {
      float mu = sv * (1.f / (float)HD);
      float var = s2 * (1.f / (float)HD) - mu * mu;
      float rr = rsqrtf(var + 1e-12f);
      float logit = rr * (sg - mu * sG) + sBW;
      mel[((size_t)b * KTOP + k) * LSEQ + l] = logit * mv - NEGV * (1.f - mv);
    }
  }
}

// ---------------- K8/K9/K10: answer path ----------------
__global__ void k_ans_in(const float* __restrict__ seq,
                         const float* __restrict__ p_ws,
                         const int* __restrict__ cls,
                         float* __restrict__ pa,
                         float* __restrict__ cf) {
  int b = blockIdx.x, s = blockIdx.y, t = threadIdx.x;
  __shared__ float ps[16];
  if (t < 16) ps[t] = p_ws[b * LSEQ + s * 16 + t];
  __syncthreads();
  const float* sb = seq + (size_t)(b * LSEQ + s * 16) * HD;
  float4 acc = make_float4(0.f, 0.f, 0.f, 0.f);
#pragma unroll
  for (int r = 0; r < 16; ++r) {
    float4 v = *(const float4*)(sb + (size_t)r * HD + 4 * t);
    float p = ps[r];
    acc.x = fmaf(p, v.x, acc.x);
    acc.y = fmaf(p, v.y, acc.y);
    acc.z = fmaf(p, v.z, acc.z);
    acc.w = fmaf(p, v.w, acc.w);
  }
  *(float4*)(pa + ((size_t)b * 32 + s) * HD + 4 * t) = acc;
  if (s == 0) {
    int ci = cls[b];
    *(float4*)(cf + (size_t)b * HD + 4 * t) =
        *(const float4*)(seq + (size_t)(b * LSEQ + ci) * HD + 4 * t);
  }
}

__global__ void k_ans_mid(const float* __restrict__ pa,
                          const float* __restrict__ cf,
                          const float* __restrict__ Wai,
                          float* __restrict__ pans) {
  int b = blockIdx.x, c = blockIdx.y, t = threadIdx.x;
  __shared__ float a_s[128];
  if (t < 128) {
    int i = c * 128 + t;
    float av;
    if (i < HD) {
      av = 0.f;
#pragma unroll
      for (int s = 0; s < 32; ++s) av += pa[((size_t)b * 32 + s) * HD + i];
    } else {
      av = cf[(size_t)b * HD + (i - HD)];
    }
    a_s[t] = av;
  }
  __syncthreads();
  float4 acc = make_float4(0.f, 0.f, 0.f, 0.f);
#pragma unroll 8
  for (int r = 0; r < 128; ++r) {
    float4 wv = *(const float4*)(Wai + (size_t)(c * 128 + r) * HD + 4 * t);
    float a = a_s[r];
    acc.x = fmaf(a, wv.x, acc.x);
    acc.y = fmaf(a, wv.y, acc.y);
    acc.z = fmaf(a, wv.z, acc.z);
    acc.w = fmaf(a, wv.w, acc.w);
  }
  *(float4*)(pans + ((size_t)b * 16 + c) * HD + 4 * t) = acc;
}

__global__ void k_ans_final(const float* __restrict__ pans,
                            const float* __restrict__ bai,
                            const float* __restrict__ Wao,
                            float* __restrict__ out6) {
  int b = blockIdx.x, t = threadIdx.x, lane = t & 63, wid = t >> 6;
  __shared__ float red[4];
  float4 a = *(const float4*)(bai + 4 * t);
#pragma unroll
  for (int c = 0; c < 16; ++c) {
    float4 p = *(const float4*)(pans + ((size_t)b * 16 + c) * HD + 4 * t);
    a.x += p.x; a.y += p.y; a.z += p.z; a.w += p.w;
  }
  float4 wo = *(const float4*)(Wao + 4 * t);
  float part = fast_tanh(a.x) * wo.x + fast_tanh(a.y) * wo.y +
               fast_tanh(a.z) * wo.z + fast_tanh(a.w) * wo.w;
#pragma unroll
  for (int off = 32; off; off >>= 1) part += __shfl_xor(part, off);
  if (lane == 0) red[wid] = part;
  __syncthreads();
  if (t == 0) out6[b] = red[0] + red[1] + red[2] + red[3];
}

// ================= fallback tier: fused gemm (atomic) =================
__launch_bounds__(256, 2)
__global__ void k_gemm_end_at(const unsigned short* __restrict__ Abf,
                              const unsigned short* __restrict__ Bt,
                              const float* __restrict__ x2p,
                              const float* __restrict__ gamma,
                              const float* __restrict__ Wout,
                              float* __restrict__ outp) {
  __shared__ unsigned short As[2][128 * 64];
  __shared__ unsigned short Bs[2][128 * 64];
  int t = threadIdx.x;
  int w = t >> 6, lane = t & 63, ln = lane & 15, hi = lane >> 4;
  int wr = w >> 1, wc = w & 1;
  int R0 = blockIdx.x * 128, C0 = blockIdx.y * 128;
  int b = R0 >> 9;
  f32x4 acc[4][4] = {};
#define STAGE(buf, kc)                                                        \
  do {                                                                        \
    _Pragma("unroll")                                                         \
    for (int p_ = 0; p_ < 4; ++p_) {                                          \
      int rr_ = p_ * 32 + (t >> 3);                                           \
      int cc_ = (t & 7) ^ (rr_ & 7);                                          \
      GLDS(Abf + (size_t)(R0 + rr_) * HD + (kc) + cc_ * 8,                    \
           &As[buf][p_ * 2048 + w * 512]);                                    \
      GLDS(Bt + (size_t)(C0 + rr_) * HD + (kc) + cc_ * 8,                     \
           &Bs[buf][p_ * 2048 + w * 512]);                                    \
    }                                                                         \
  } while (0)
  STAGE(0, 0);
  for (int it = 0; it < 16; ++it) {
    int cur = it & 1;
    if (it < 15) {
      STAGE(cur ^ 1, (it + 1) * 64);
      asm volatile("s_waitcnt vmcnt(8)" ::: "memory");
    } else {
      asm volatile("s_waitcnt vmcnt(0)" ::: "memory");
    }
    __builtin_amdgcn_s_barrier();
    __builtin_amdgcn_sched_barrier(0);
#pragma unroll
    for (int ks = 0; ks < 2; ++ks) {
      bf16x8 av[4], bv[4];
#pragma unroll
      for (int m = 0; m < 4; ++m) {
        int r = wr * 64 + m * 16 + ln;
        av[m] = *(const bf16x8*)(const void*)&As[cur][r * 64 + (((ks * 4 + hi) ^ (r & 7)) * 8)];
      }
#pragma unroll
      for (int n = 0; n < 4; ++n) {
        int r = wc * 64 + n * 16 + ln;
        bv[n] = *(const bf16x8*)(const void*)&Bs[cur][r * 64 + (((ks * 4 + hi) ^ (r & 7)) * 8)];
      }
#pragma unroll
      for (int m = 0; m < 4; ++m)
#pragma unroll
        for (int n = 0; n < 4; ++n)
          acc[m][n] = __builtin_amdgcn_mfma_f32_16x16x32_bf16(av[m], bv[n], acc[m][n], 0, 0, 0);
    }
    __builtin_amdgcn_sched_barrier(0);
    __builtin_amdgcn_s_barrier();
  }
#undef STAGE
  float gsv[4];
  float x2v[4][KTOP];
#pragma unroll
  for (int n = 0; n < 4; ++n) {
    int c = C0 + wc * 64 + n * 16 + ln;
    gsv[n] = gamma[c] * Wout[c];
#pragma unroll
    for (int k = 0; k < KTOP; ++k) x2v[n][k] = x2p[((size_t)b * KTOP + k) * HD + c];
  }
#pragma unroll
  for (int m = 0; m < 4; ++m)
#pragma unroll
    for (int j = 0; j < 4; ++j) {
      int row = R0 + wr * 64 + m * 16 + hi * 4 + j;
#pragma unroll
      for (int k = 0; k < KTOP; ++k) {
        float sv = 0.f, s2 = 0.f, sg = 0.f;
#pragma unroll
        for (int n = 0; n < 4; ++n) {
          float v = fast_tanh(acc[m][n][j] + x2v[n][k]);
          sv += v; s2 += v * v; sg += v * gsv[n];
        }
#pragma unroll
        for (int off = 8; off; off >>= 1) {
          sv += __shfl_xor(sv, off);
          s2 += __shfl_xor(s2, off);
          sg += __shfl_xor(sg, off);
        }
        if (ln == 0) {
          float* p = outp + ((size_t)row * KTOP + k) * 3;
          atomicAdd(p, sv);
          atomicAdd(p + 1, s2);
          atomicAdd(p + 2, sg);
        }
      }
    }
}

__global__ void k_end_final(const float* __restrict__ sums,
                            const float* __restrict__ gamma,
                            const float* __restrict__ beta,
                            const float* __restrict__ Wout,
                            const float* __restrict__ beo,
                            const float* __restrict__ mask,
                            float* __restrict__ mel) {
  int bk = blockIdx.x, b = bk / KTOP, k = bk % KTOP;
  int t = threadIdx.x, lane = t & 63, wid = t >> 6;
  __shared__ float red[4][2];
  float pg = 0.f, pb = 0.f;
  for (int i = t; i < HD; i += 256) {
    float wv = Wout[i];
    pg += gamma[i] * wv;
    pb += beta[i] * wv;
  }
#pragma unroll
  for (int off = 32; off; off >>= 1) {
    pg += __shfl_xor(pg, off);
    pb += __shfl_xor(pb, off);
  }
  if (lane == 0) { red[wid][0] = pg; red[wid][1] = pb; }
  __syncthreads();
  float sG = red[0][0] + red[1][0] + red[2][0] + red[3][0];
  float sBW = red[0][1] + red[1][1] + red[2][1] + red[3][1] + beo[0];
  for (int l = t; l < LSEQ; l += 256) {
    int row = b * LSEQ + l;
    const float* s = sums + ((size_t)row * KTOP + k) * 3;
    float sv = s[0], s2 = s[1], sg = s[2];
    float mu = sv * (1.f / (float)HD);
    float var = s2 * (1.f / (float)HD) - mu * mu;
    float rr = rsqrtf(var + 1e-12f);
    float logit = rr * (sg - mu * sG) + sBW;
    float mv = mask[row];
    mel[((size_t)b * KTOP + k) * LSEQ + l] = logit * mv - NEGV * (1.f - mv);
  }
}

// ---------------- host ----------------
extern "C" void kernel_launch(void* const* d_in, const int* in_sizes, int n_in,
                              void* d_out, int out_size, void* d_ws, size_t ws_size,
                              hipStream_t stream) {
  (void)in_sizes; (void)n_in; (void)out_size;
  const float* seq = (const float*)d_in[0];
  const int*   cls = (const int*)d_in[1];
  const float* mask = (const float*)d_in[2];
  const float* Wst = (const float*)d_in[3];
  const float* bst = (const float*)d_in[4];
  const float* Wei = (const float*)d_in[5];
  const float* bei = (const float*)d_in[6];
  const float* gam = (const float*)d_in[7];
  const float* bet = (const float*)d_in[8];
  const float* Weo = (const float*)d_in[9];
  const float* beo = (const float*)d_in[10];
  const float* Wai = (const float*)d_in[11];
  const float* bai = (const float*)d_in[12];
  const float* Wao = (const float*)d_in[13];

  float* out = (float*)d_out;
  float* out0 = out;             // start_predictions  (16,512)
  float* out1 = out0 + 8192;     // end_predictions    (16,5,512)
  float* out2 = out1 + 40960;    // masked_start_logits(16,512)
  float* out3 = out2 + 8192;     // masked_end_logits  (16,5,512)
  float* out4 = out3 + 40960;    // start_top_predictions (16,5)
  float* out5 = out4 + 80;       // end_top_predictions (16,25)
  float* out6 = out5 + 400;      // class_logits (16)

  // ws layout
  char* p = (char*)d_ws;
  unsigned short* seqb = (unsigned short*)p;  p += (size_t)8192 * 1024 * 2;
  unsigned short* w1t  = (unsigned short*)p;  p += (size_t)1024 * 1024 * 2;
  float* p_ws   = (float*)p;                  p += 8192 * 4;
  int*   idx_ws = (int*)p;                    p += 128 * 4;
  float* x2p    = (float*)p;                  p += (size_t)80 * 1024 * 4;
  float* gw_ws  = (float*)p;                  p += 1024 * 4;
  float* sgb_ws = (float*)p;                  p += 4 * 4;
  float* pa     = (float*)p;                  p += (size_t)16 * 32 * 1024 * 4;
  float* cf     = (float*)p;                  p += (size_t)16 * 1024 * 4;
  float* pans   = (float*)p;                  p += (size_t)16 * 16 * 1024 * 4;
  // tail union: x2part (2.62MB) consumed before X1 (16MB) is written
  float* x2part = (float*)p;
  unsigned short* x1 = (unsigned short*)p;
  float* sums = (float*)(p + (size_t)640 * 1024 * 4);
  size_t base = (size_t)(p - (char*)d_ws);
  size_t need_big = base + (size_t)8192 * 1024 * 2;
  size_t need_small = base + (size_t)640 * 1024 * 4 + (size_t)8192 * KTOP * 3 * 4;

  k_prep<<<3073, 256, 0, stream>>>(seq, seqb, Wst, bst, mask, out2, Wei, w1t,
                                   gam, bet, Weo, beo, gw_ws, sgb_ws);
  k_softmax_topk<<<NB, 256, 0, stream>>>(out2, out0, out4, p_ws, idx_ws);
  k_x2p<<<dim3(NB * KTOP, 8), 256, 0, stream>>>(seq, idx_ws, Wei, x2part);
  k_x2r<<<NB * KTOP, 256, 0, stream>>>(x2part, bei, x2p);

  if (ws_size >= need_big) {
    k_gemm<<<dim3(64, 8), 256, 0, stream>>>(seqb, w1t, x1);
    k_endrow<<<2048, 256, 0, stream>>>(x1, x2p, gw_ws, sgb_ws, mask, out3);
  } else if (ws_size >= need_small) {
    hipMemsetAsync(sums, 0, (size_t)8192 * KTOP * 3 * sizeof(float), stream);
    k_gemm_end_at<<<dim3(64, 8), 256, 0, stream>>>(seqb, w1t, x2p, gam, Weo, sums);
    k_end_final<<<NB * KTOP, 256, 0, stream>>>(sums, gam, bet, Weo, beo, mask, out3);
  }

  k_softmax_topk<<<NB * KTOP, 256, 0, stream>>>(out3, out1, out5, nullptr, nullptr);
  k_ans_in<<<dim3(NB, 32), 256, 0, stream>>>(seq, p_ws, cls, pa, cf);
  k_ans_mid<<<dim3(NB, 16), 256, 0, stream>>>(pa, cf, Wai, pans);
  k_ans_final<<<NB, 256, 0, stream>>>(pans, bai, Wao, out6);
}

// Round 6
// 95.935 us; speedup vs baseline: 7.0675x; 1.0984x over previous
//
#include <hip/hip_runtime.h>
#include <math.h>

#define HD   1024
#define LSEQ 512
#define NB   16
#define KTOP 5
#define NEGV 1e30f

typedef __bf16 bf16x8 __attribute__((ext_vector_type(8)));
typedef float  f32x4  __attribute__((ext_vector_type(4)));

__device__ inline unsigned short f2bf(float f) {
  unsigned u = __float_as_uint(f);
  unsigned r = (u + 0x7FFFu + ((u >> 16) & 1u)) >> 16;
  return (unsigned short)r;
}
__device__ inline float bf2f(unsigned short u) {
  return __uint_as_float(((unsigned)u) << 16);
}

__device__ inline float fast_tanh(float x) {
  float e = __expf(-2.f * fabsf(x));
  float v = (1.f - e) / (1.f + e);
  return copysignf(v, x);
}

// tanh(arg) with pre-scaled xs = A*arg, A = 2*log2(e): tanh = 1 - 2*rcp(1+exp2(xs))
__device__ inline float tanh_scaled(float xs) {
  float e = __builtin_amdgcn_exp2f(xs);
  float r = __builtin_amdgcn_rcpf(1.f + e);
  return fmaf(-2.f, r, 1.f);
}

#define GLDS(g, l) __builtin_amdgcn_global_load_lds(                      \
    (const __attribute__((address_space(1))) unsigned int*)(g),          \
    (__attribute__((address_space(3))) unsigned int*)(l), 16, 0, 0)

// =============== device bodies ===============

// ---- row log_softmax + top5 over 512 (256 threads) ----
__device__ __forceinline__ void sm_body(int row, const float* __restrict__ xin,
                                        float* __restrict__ lsm_out,
                                        float* __restrict__ top_out,
                                        float* __restrict__ p_out,
                                        int* __restrict__ idx_out) {
  __shared__ float redf[4];
  __shared__ int redi[4];
  __shared__ float bc_m, bc_s;
  __shared__ int bc_i;
  int t = threadIdx.x, lane = t & 63, wid = t >> 6;
  const float* x = xin + (size_t)row * LSEQ;
  float x0 = x[t], x1 = x[t + 256];

  float m = fmaxf(x0, x1);
#pragma unroll
  for (int off = 32; off; off >>= 1) m = fmaxf(m, __shfl_xor(m, off));
  if (lane == 0) redf[wid] = m;
  __syncthreads();
  if (t == 0) bc_m = fmaxf(fmaxf(redf[0], redf[1]), fmaxf(redf[2], redf[3]));
  __syncthreads();
  m = bc_m;

  float e0 = expf(x0 - m), e1 = expf(x1 - m);
  float s = e0 + e1;
#pragma unroll
  for (int off = 32; off; off >>= 1) s += __shfl_xor(s, off);
  if (lane == 0) redf[wid] = s;
  __syncthreads();
  if (t == 0) bc_s = redf[0] + redf[1] + redf[2] + redf[3];
  __syncthreads();
  s = bc_s;
  float ls = logf(s);

  lsm_out[(size_t)row * LSEQ + t] = x0 - m - ls;
  lsm_out[(size_t)row * LSEQ + t + 256] = x1 - m - ls;
  if (p_out) {
    float inv = 1.f / s;
    p_out[(size_t)row * LSEQ + t] = e0 * inv;
    p_out[(size_t)row * LSEQ + t + 256] = e1 * inv;
  }

  bool a0 = true, a1 = true;
  for (int it = 0; it < KTOP; ++it) {
    float v0 = a0 ? x0 : -INFINITY;
    float v1 = a1 ? x1 : -INFINITY;
    float bv = v0; int bi = t;
    if (v1 > bv) { bv = v1; bi = t + 256; }
#pragma unroll
    for (int off = 32; off; off >>= 1) {
      float ov = __shfl_xor(bv, off);
      int oi = __shfl_xor(bi, off);
      if (ov > bv || (ov == bv && oi < bi)) { bv = ov; bi = oi; }
    }
    __syncthreads();
    if (lane == 0) { redf[wid] = bv; redi[wid] = bi; }
    __syncthreads();
    if (t == 0) {
      float wv = redf[0]; int wi = redi[0];
      for (int w = 1; w < 4; ++w)
        if (redf[w] > wv || (redf[w] == wv && redi[w] < wi)) { wv = redf[w]; wi = redi[w]; }
      top_out[row * KTOP + it] = wv - m - ls;
      if (idx_out) idx_out[row * KTOP + it] = wi;
      bc_i = wi;
    }
    __syncthreads();
    int wi = bc_i;
    if (wi == t) a0 = false;
    if (wi == t + 256) a1 = false;
  }
}

// ---- 128x128 MFMA GEMM tile (proven round-3 pipeline) -> X1 bf16 ----
__device__ __forceinline__ void gemm_body(int gid,
                                          const unsigned short* __restrict__ Abf,
                                          const unsigned short* __restrict__ Bt,
                                          unsigned short* __restrict__ X1) {
  __shared__ unsigned short SH[32768];  // As[2][8192] | Bs[2][8192]
  unsigned short* As = SH;
  unsigned short* Bs = SH + 16384;
  int t = threadIdx.x;
  int w = t >> 6, lane = t & 63, ln = lane & 15, hi = lane >> 4;
  int wr = w >> 1, wc = w & 1;
  int R0 = (gid >> 3) * 128, C0 = (gid & 7) * 128;

  f32x4 acc[4][4] = {};

#define STAGE(buf, kc)                                                        \
  do {                                                                        \
    _Pragma("unroll")                                                         \
    for (int p_ = 0; p_ < 4; ++p_) {                                          \
      int rr_ = p_ * 32 + (t >> 3);                                           \
      int cc_ = (t & 7) ^ (rr_ & 7);                                          \
      GLDS(Abf + (size_t)(R0 + rr_) * HD + (kc) + cc_ * 8,                    \
           As + (buf) * 8192 + p_ * 2048 + w * 512);                          \
      GLDS(Bt + (size_t)(C0 + rr_) * HD + (kc) + cc_ * 8,                     \
           Bs + (buf) * 8192 + p_ * 2048 + w * 512);                          \
    }                                                                         \
  } while (0)

  STAGE(0, 0);
  for (int it = 0; it < 16; ++it) {
    int cur = it & 1;
    if (it < 15) {
      STAGE(cur ^ 1, (it + 1) * 64);
      asm volatile("s_waitcnt vmcnt(8)" ::: "memory");
    } else {
      asm volatile("s_waitcnt vmcnt(0)" ::: "memory");
    }
    __builtin_amdgcn_s_barrier();
    __builtin_amdgcn_sched_barrier(0);
#pragma unroll
    for (int ks = 0; ks < 2; ++ks) {
      bf16x8 av[4], bv[4];
#pragma unroll
      for (int m = 0; m < 4; ++m) {
        int r = wr * 64 + m * 16 + ln;
        av[m] = *(const bf16x8*)(const void*)&As[cur * 8192 + r * 64 + (((ks * 4 + hi) ^ (r & 7)) * 8)];
      }
#pragma unroll
      for (int n = 0; n < 4; ++n) {
        int r = wc * 64 + n * 16 + ln;
        bv[n] = *(const bf16x8*)(const void*)&Bs[cur * 8192 + r * 64 + (((ks * 4 + hi) ^ (r & 7)) * 8)];
      }
#pragma unroll
      for (int m = 0; m < 4; ++m)
#pragma unroll
        for (int n = 0; n < 4; ++n)
          acc[m][n] = __builtin_amdgcn_mfma_f32_16x16x32_bf16(av[m], bv[n], acc[m][n], 0, 0, 0);
    }
    __builtin_amdgcn_sched_barrier(0);
    __builtin_amdgcn_s_barrier();
  }
#undef STAGE

#pragma unroll
  for (int m = 0; m < 4; ++m)
#pragma unroll
    for (int j = 0; j < 4; ++j) {
      int row = R0 + wr * 64 + m * 16 + hi * 4 + j;
#pragma unroll
      for (int n = 0; n < 4; ++n) {
        int col = C0 + wc * 64 + n * 16 + ln;
        X1[(size_t)row * HD + col] = f2bf(acc[m][n][j]);
      }
    }
}

// ---- X2 slice: x2p[bk] += srow_slice @ W2_slice (atomic; x2p pre-init = bei) ----
__device__ __forceinline__ void x2slice_body(int q, const float* __restrict__ seq,
                                             const int* __restrict__ idx,
                                             const float* __restrict__ Wei,
                                             float* __restrict__ x2p) {
  __shared__ float srow[128];
  int bk = q >> 3, s = q & 7, t = threadIdx.x;
  int b = bk / KTOP;
  int l = idx[bk];
  if (t < 128) srow[t] = seq[((size_t)(b * LSEQ + l)) * HD + s * 128 + t];
  __syncthreads();
  const float* W2 = Wei + (size_t)HD * HD + (size_t)s * 128 * HD;
  float4 acc = make_float4(0.f, 0.f, 0.f, 0.f);
#pragma unroll 8
  for (int h = 0; h < 128; ++h) {
    float4 wv = *(const float4*)(W2 + (size_t)h * HD + 4 * t);
    float sv = srow[h];
    acc.x = fmaf(sv, wv.x, acc.x);
    acc.y = fmaf(sv, wv.y, acc.y);
    acc.z = fmaf(sv, wv.z, acc.z);
    acc.w = fmaf(sv, wv.w, acc.w);
  }
  float* dst = x2p + (size_t)bk * HD + 4 * t;
  atomicAdd(dst + 0, acc.x);
  atomicAdd(dst + 1, acc.y);
  atomicAdd(dst + 2, acc.z);
  atomicAdd(dst + 3, acc.w);
}

// ---- answer-feature partial: pa[b][s] = sum_{l in slice} p*seq ----
__device__ __forceinline__ void ansin_body(int q, const float* __restrict__ seq,
                                           const float* __restrict__ p_ws,
                                           const int* __restrict__ cls,
                                           float* __restrict__ pa,
                                           float* __restrict__ cf) {
  __shared__ float ps[16];
  int b = q >> 5, s = q & 31, t = threadIdx.x;
  if (t < 16) ps[t] = p_ws[b * LSEQ + s * 16 + t];
  __syncthreads();
  const float* sb = seq + (size_t)(b * LSEQ + s * 16) * HD;
  float4 acc = make_float4(0.f, 0.f, 0.f, 0.f);
#pragma unroll
  for (int r = 0; r < 16; ++r) {
    float4 v = *(const float4*)(sb + (size_t)r * HD + 4 * t);
    float p = ps[r];
    acc.x = fmaf(p, v.x, acc.x);
    acc.y = fmaf(p, v.y, acc.y);
    acc.z = fmaf(p, v.z, acc.z);
    acc.w = fmaf(p, v.w, acc.w);
  }
  *(float4*)(pa + ((size_t)b * 32 + s) * HD + 4 * t) = acc;
  if (s == 0) {
    int ci = cls[b];
    *(float4*)(cf + (size_t)b * HD + 4 * t) =
        *(const float4*)(seq + (size_t)(b * LSEQ + ci) * HD + 4 * t);
  }
}

// ---- per-row tanh+LN+logit (proven round-5) ----
__device__ __forceinline__ void endrow_body(int bx, const unsigned short* __restrict__ X1,
                                            const float* __restrict__ x2p,
                                            const float* __restrict__ gw_ws,
                                            const float* __restrict__ sgb_ws,
                                            const float* __restrict__ mask,
                                            float* __restrict__ mel) {
  __shared__ float x2s[KTOP * HD];  // 20KB, prescaled by A
  const float A = 2.885390081777927f;  // 2*log2(e)
  int t = threadIdx.x, wave = t >> 6, lane = t & 63;
  int row = bx * 4 + wave;
  int b = row >> 9, l = row & 511;

  {
    const float4* src = (const float4*)(x2p + (size_t)b * KTOP * HD);
    float4* dst = (float4*)x2s;
    for (int i = t; i < KTOP * HD / 4; i += 256) {
      float4 v = src[i];
      dst[i] = make_float4(v.x * A, v.y * A, v.z * A, v.w * A);
    }
  }

  float xs[16], gwr[16];
  const unsigned short* xrow = X1 + (size_t)row * HD + lane * 4;
#pragma unroll
  for (int q = 0; q < 4; ++q) {
    ushort4 u = *(const ushort4*)(xrow + q * 256);
    xs[4 * q + 0] = bf2f(u.x) * A;
    xs[4 * q + 1] = bf2f(u.y) * A;
    xs[4 * q + 2] = bf2f(u.z) * A;
    xs[4 * q + 3] = bf2f(u.w) * A;
    float4 g = *(const float4*)(gw_ws + q * 256 + lane * 4);
    gwr[4 * q + 0] = g.x; gwr[4 * q + 1] = g.y;
    gwr[4 * q + 2] = g.z; gwr[4 * q + 3] = g.w;
  }
  float mv = mask[row];
  float sG = sgb_ws[0], sBW = sgb_ws[1];
  __syncthreads();

#pragma unroll
  for (int k = 0; k < KTOP; ++k) {
    float sv = 0.f, s2 = 0.f, sg = 0.f;
#pragma unroll
    for (int q = 0; q < 4; ++q) {
      float4 xq = *(const float4*)&x2s[k * HD + q * 256 + lane * 4];
      float v0 = tanh_scaled(xs[4 * q + 0] + xq.x);
      float v1 = tanh_scaled(xs[4 * q + 1] + xq.y);
      float v2 = tanh_scaled(xs[4 * q + 2] + xq.z);
      float v3 = tanh_scaled(xs[4 * q + 3] + xq.w);
      sv += v0 + v1 + v2 + v3;
      s2 = fmaf(v0, v0, s2); s2 = fmaf(v1, v1, s2);
      s2 = fmaf(v2, v2, s2); s2 = fmaf(v3, v3, s2);
      sg = fmaf(v0, gwr[4 * q + 0], sg); sg = fmaf(v1, gwr[4 * q + 1], sg);
      sg = fmaf(v2, gwr[4 * q + 2], sg); sg = fmaf(v3, gwr[4 * q + 3], sg);
    }
#pragma unroll
    for (int off = 32; off; off >>= 1) {
      sv += __shfl_xor(sv, off);
      s2 += __shfl_xor(s2, off);
      sg += __shfl_xor(sg, off);
    }
    if (lane == 0) {
      float mu = sv * (1.f / (float)HD);
      float var = s2 * (1.f / (float)HD) - mu * mu;
      float rr = rsqrtf(var + 1e-12f);
      float logit = rr * (sg - mu * sG) + sBW;
      mel[((size_t)b * KTOP + k) * LSEQ + l] = logit * mv - NEGV * (1.f - mv);
    }
  }
}

// ---- answer mid GEMM slice ----
__device__ __forceinline__ void ansmid_body(int q, const float* __restrict__ pa,
                                            const float* __restrict__ cf,
                                            const float* __restrict__ Wai,
                                            float* __restrict__ pans) {
  __shared__ float a_s[128];
  int b = q >> 4, c = q & 15, t = threadIdx.x;
  if (t < 128) {
    int i = c * 128 + t;
    float av;
    if (i < HD) {
      av = 0.f;
#pragma unroll
      for (int s = 0; s < 32; ++s) av += pa[((size_t)b * 32 + s) * HD + i];
    } else {
      av = cf[(size_t)b * HD + (i - HD)];
    }
    a_s[t] = av;
  }
  __syncthreads();
  float4 acc = make_float4(0.f, 0.f, 0.f, 0.f);
#pragma unroll 8
  for (int r = 0; r < 128; ++r) {
    float4 wv = *(const float4*)(Wai + (size_t)(c * 128 + r) * HD + 4 * t);
    float a = a_s[r];
    acc.x = fmaf(a, wv.x, acc.x);
    acc.y = fmaf(a, wv.y, acc.y);
    acc.z = fmaf(a, wv.z, acc.z);
    acc.w = fmaf(a, wv.w, acc.w);
  }
  *(float4*)(pans + ((size_t)b * 16 + c) * HD + 4 * t) = acc;
}

__device__ __forceinline__ void ansfinal_body(int b, const float* __restrict__ pans,
                                              const float* __restrict__ bai,
                                              const float* __restrict__ Wao,
                                              float* __restrict__ out6) {
  __shared__ float red[4];
  int t = threadIdx.x, lane = t & 63, wid = t >> 6;
  float4 a = *(const float4*)(bai + 4 * t);
#pragma unroll
  for (int c = 0; c < 16; ++c) {
    float4 p = *(const float4*)(pans + ((size_t)b * 16 + c) * HD + 4 * t);
    a.x += p.x; a.y += p.y; a.z += p.z; a.w += p.w;
  }
  float4 wo = *(const float4*)(Wao + 4 * t);
  float part = fast_tanh(a.x) * wo.x + fast_tanh(a.y) * wo.y +
               fast_tanh(a.z) * wo.z + fast_tanh(a.w) * wo.w;
#pragma unroll
  for (int off = 32; off; off >>= 1) part += __shfl_xor(part, off);
  if (lane == 0) red[wid] = part;
  __syncthreads();
  if (t == 0) out6[b] = red[0] + red[1] + red[2] + red[3];
}

// =============== kernels ===============

// K1: conv+start (2048) | W1 transpose (1024) | LN consts (1) | x2p init (80)
__global__ void k_prep(const float* __restrict__ seq,
                       unsigned short* __restrict__ seqb,
                       const float* __restrict__ Wst,
                       const float* __restrict__ bst,
                       const float* __restrict__ mask,
                       float* __restrict__ msl,
                       const float* __restrict__ Wei,
                       unsigned short* __restrict__ w1t,
                       const float* __restrict__ gam,
                       const float* __restrict__ bet,
                       const float* __restrict__ Weo,
                       const float* __restrict__ beo,
                       float* __restrict__ gw_ws,
                       float* __restrict__ sgb_ws,
                       const float* __restrict__ bei,
                       float* __restrict__ x2p) {
  __shared__ unsigned short tile[32][33];
  __shared__ float redp[4][2];
  int bx = blockIdx.x;
  if (bx < 2048) {
    int wave = threadIdx.x >> 6, lane = threadIdx.x & 63;
    int row = bx * 4 + wave;
    const float4* s4 = (const float4*)(seq + (size_t)row * HD);
    const float4* w4 = (const float4*)Wst;
    ushort4* o4 = (ushort4*)(seqb + (size_t)row * HD);
    float acc = 0.f;
#pragma unroll
    for (int m = 0; m < 4; ++m) {
      int i = lane + 64 * m;
      float4 a = s4[i], w = w4[i];
      acc += a.x * w.x + a.y * w.y + a.z * w.z + a.w * w.w;
      ushort4 o;
      o.x = f2bf(a.x); o.y = f2bf(a.y); o.z = f2bf(a.z); o.w = f2bf(a.w);
      o4[i] = o;
    }
#pragma unroll
    for (int off = 32; off; off >>= 1) acc += __shfl_xor(acc, off);
    if (lane == 0) {
      float logit = acc + bst[0];
      float mv = mask[row];
      msl[row] = logit * mv - NEGV * (1.f - mv);
    }
  } else if (bx < 3072) {
    int tb = bx - 2048;
    int h0 = (tb & 31) * 32, d0 = (tb >> 5) * 32;
    int tx = threadIdx.x & 31, ty = threadIdx.x >> 5;
#pragma unroll
    for (int i = 0; i < 4; ++i)
      tile[ty + 8 * i][tx] = f2bf(Wei[(size_t)(h0 + ty + 8 * i) * HD + d0 + tx]);
    __syncthreads();
#pragma unroll
    for (int i = 0; i < 4; ++i)
      w1t[(size_t)(d0 + ty + 8 * i) * HD + h0 + tx] = tile[tx][ty + 8 * i];
  } else if (bx == 3072) {
    int t = threadIdx.x, wave = t >> 6, lane = t & 63;
    float4 g = ((const float4*)gam)[t];
    float4 w = ((const float4*)Weo)[t];
    float4 bv = ((const float4*)bet)[t];
    float4 gwv = make_float4(g.x * w.x, g.y * w.y, g.z * w.z, g.w * w.w);
    ((float4*)gw_ws)[t] = gwv;
    float pg = gwv.x + gwv.y + gwv.z + gwv.w;
    float pb = bv.x * w.x + bv.y * w.y + bv.z * w.z + bv.w * w.w;
#pragma unroll
    for (int off = 32; off; off >>= 1) {
      pg += __shfl_xor(pg, off);
      pb += __shfl_xor(pb, off);
    }
    if (lane == 0) { redp[wave][0] = pg; redp[wave][1] = pb; }
    __syncthreads();
    if (t == 0) {
      sgb_ws[0] = redp[0][0] + redp[1][0] + redp[2][0] + redp[3][0];
      sgb_ws[1] = redp[0][1] + redp[1][1] + redp[2][1] + redp[3][1] + beo[0];
    }
  } else {
    int row = bx - 3073;  // 0..79
    ((float4*)(x2p + (size_t)row * HD))[threadIdx.x] = ((const float4*)bei)[threadIdx.x];
  }
}

__global__ void k_softmax_topk(const float* __restrict__ xin,
                               float* __restrict__ lsm_out,
                               float* __restrict__ top_out,
                               float* __restrict__ p_out,
                               int* __restrict__ idx_out) {
  sm_body(blockIdx.x, xin, lsm_out, top_out, p_out, idx_out);
}

// K3: gemm (512) + x2 slices (640) + ans_in (512), interleaved 4/5/4 per 13
__launch_bounds__(256, 2)
__global__ void k_big(const unsigned short* __restrict__ Abf,
                      const unsigned short* __restrict__ Bt,
                      unsigned short* __restrict__ X1,
                      const float* __restrict__ seq,
                      const int* __restrict__ idx,
                      const float* __restrict__ Wei,
                      float* __restrict__ x2p,
                      const float* __restrict__ p_ws,
                      const int* __restrict__ cls,
                      float* __restrict__ pa,
                      float* __restrict__ cf) {
  int id = blockIdx.x;
  int grp = id / 13, rem = id % 13;
  if (rem < 4) gemm_body(grp * 4 + rem, Abf, Bt, X1);
  else if (rem < 9) x2slice_body(grp * 5 + (rem - 4), seq, idx, Wei, x2p);
  else ansin_body(grp * 4 + (rem - 9), seq, p_ws, cls, pa, cf);
}

// K4: endrow (2048) + ans_mid (256)
__global__ void k_end2(const unsigned short* __restrict__ X1,
                       const float* __restrict__ x2p,
                       const float* __restrict__ gw_ws,
                       const float* __restrict__ sgb_ws,
                       const float* __restrict__ mask,
                       float* __restrict__ mel,
                       const float* __restrict__ pa,
                       const float* __restrict__ cf,
                       const float* __restrict__ Wai,
                       float* __restrict__ pans) {
  int bx = blockIdx.x;
  if (bx < 2048) endrow_body(bx, X1, x2p, gw_ws, sgb_ws, mask, mel);
  else ansmid_body(bx - 2048, pa, cf, Wai, pans);
}

// K5: softmax2 (80) + ans_final (16)
__global__ void k_fin(const float* __restrict__ mel,
                      float* __restrict__ lsm_out,
                      float* __restrict__ top_out,
                      const float* __restrict__ pans,
                      const float* __restrict__ bai,
                      const float* __restrict__ Wao,
                      float* __restrict__ out6) {
  int bx = blockIdx.x;
  if (bx < NB * KTOP) sm_body(bx, mel, lsm_out, top_out, nullptr, nullptr);
  else ansfinal_body(bx - NB * KTOP, pans, bai, Wao, out6);
}

// =============== fallback-tier kernels (small ws) ===============
__global__ void k_x2f(const float* __restrict__ seq, const int* __restrict__ idx,
                      const float* __restrict__ Wei, float* __restrict__ x2p) {
  x2slice_body(blockIdx.x, seq, idx, Wei, x2p);
}
__global__ void k_ansin_f(const float* __restrict__ seq, const float* __restrict__ p_ws,
                          const int* __restrict__ cls, float* __restrict__ pa,
                          float* __restrict__ cf) {
  ansin_body(blockIdx.x, seq, p_ws, cls, pa, cf);
}
__global__ void k_ansmid_f(const float* __restrict__ pa, const float* __restrict__ cf,
                           const float* __restrict__ Wai, float* __restrict__ pans) {
  ansmid_body(blockIdx.x, pa, cf, Wai, pans);
}

__launch_bounds__(256, 2)
__global__ void k_gemm_end_at(const unsigned short* __restrict__ Abf,
                              const unsigned short* __restrict__ Bt,
                              const float* __restrict__ x2p,
                              const float* __restrict__ gamma,
                              const float* __restrict__ Wout,
                              float* __restrict__ outp) {
  __shared__ unsigned short As[2][128 * 64];
  __shared__ unsigned short Bs[2][128 * 64];
  int t = threadIdx.x;
  int w = t >> 6, lane = t & 63, ln = lane & 15, hi = lane >> 4;
  int wr = w >> 1, wc = w & 1;
  int R0 = blockIdx.x * 128, C0 = blockIdx.y * 128;
  int b = R0 >> 9;
  f32x4 acc[4][4] = {};
#define STAGE(buf, kc)                                                        \
  do {                                                                        \
    _Pragma("unroll")                                                         \
    for (int p_ = 0; p_ < 4; ++p_) {                                          \
      int rr_ = p_ * 32 + (t >> 3);                                           \
      int cc_ = (t & 7) ^ (rr_ & 7);                                          \
      GLDS(Abf + (size_t)(R0 + rr_) * HD + (kc) + cc_ * 8,                    \
           &As[buf][p_ * 2048 + w * 512]);                                    \
      GLDS(Bt + (size_t)(C0 + rr_) * HD + (kc) + cc_ * 8,                     \
           &Bs[buf][p_ * 2048 + w * 512]);                                    \
    }                                                                         \
  } while (0)
  STAGE(0, 0);
  for (int it = 0; it < 16; ++it) {
    int cur = it & 1;
    if (it < 15) {
      STAGE(cur ^ 1, (it + 1) * 64);
      asm volatile("s_waitcnt vmcnt(8)" ::: "memory");
    } else {
      asm volatile("s_waitcnt vmcnt(0)" ::: "memory");
    }
    __builtin_amdgcn_s_barrier();
    __builtin_amdgcn_sched_barrier(0);
#pragma unroll
    for (int ks = 0; ks < 2; ++ks) {
      bf16x8 av[4], bv[4];
#pragma unroll
      for (int m = 0; m < 4; ++m) {
        int r = wr * 64 + m * 16 + ln;
        av[m] = *(const bf16x8*)(const void*)&As[cur][r * 64 + (((ks * 4 + hi) ^ (r & 7)) * 8)];
      }
#pragma unroll
      for (int n = 0; n < 4; ++n) {
        int r = wc * 64 + n * 16 + ln;
        bv[n] = *(const bf16x8*)(const void*)&Bs[cur][r * 64 + (((ks * 4 + hi) ^ (r & 7)) * 8)];
      }
#pragma unroll
      for (int m = 0; m < 4; ++m)
#pragma unroll
        for (int n = 0; n < 4; ++n)
          acc[m][n] = __builtin_amdgcn_mfma_f32_16x16x32_bf16(av[m], bv[n], acc[m][n], 0, 0, 0);
    }
    __builtin_amdgcn_sched_barrier(0);
    __builtin_amdgcn_s_barrier();
  }
#undef STAGE
  float gsv[4];
  float x2v[4][KTOP];
#pragma unroll
  for (int n = 0; n < 4; ++n) {
    int c = C0 + wc * 64 + n * 16 + ln;
    gsv[n] = gamma[c] * Wout[c];
#pragma unroll
    for (int k = 0; k < KTOP; ++k) x2v[n][k] = x2p[((size_t)b * KTOP + k) * HD + c];
  }
#pragma unroll
  for (int m = 0; m < 4; ++m)
#pragma unroll
    for (int j = 0; j < 4; ++j) {
      int row = R0 + wr * 64 + m * 16 + hi * 4 + j;
#pragma unroll
      for (int k = 0; k < KTOP; ++k) {
        float sv = 0.f, s2 = 0.f, sg = 0.f;
#pragma unroll
        for (int n = 0; n < 4; ++n) {
          float v = fast_tanh(acc[m][n][j] + x2v[n][k]);
          sv += v; s2 += v * v; sg += v * gsv[n];
        }
#pragma unroll
        for (int off = 8; off; off >>= 1) {
          sv += __shfl_xor(sv, off);
          s2 += __shfl_xor(s2, off);
          sg += __shfl_xor(sg, off);
        }
        if (ln == 0) {
          float* p = outp + ((size_t)row * KTOP + k) * 3;
          atomicAdd(p, sv);
          atomicAdd(p + 1, s2);
          atomicAdd(p + 2, sg);
        }
      }
    }
}

__global__ void k_end_final(const float* __restrict__ sums,
                            const float* __restrict__ gamma,
                            const float* __restrict__ beta,
                            const float* __restrict__ Wout,
                            const float* __restrict__ beo,
                            const float* __restrict__ mask,
                            float* __restrict__ mel) {
  int bk = blockIdx.x, b = bk / KTOP, k = bk % KTOP;
  int t = threadIdx.x, lane = t & 63, wid = t >> 6;
  __shared__ float red[4][2];
  float pg = 0.f, pb = 0.f;
  for (int i = t; i < HD; i += 256) {
    float wv = Wout[i];
    pg += gamma[i] * wv;
    pb += beta[i] * wv;
  }
#pragma unroll
  for (int off = 32; off; off >>= 1) {
    pg += __shfl_xor(pg, off);
    pb += __shfl_xor(pb, off);
  }
  if (lane == 0) { red[wid][0] = pg; red[wid][1] = pb; }
  __syncthreads();
  float sG = red[0][0] + red[1][0] + red[2][0] + red[3][0];
  float sBW = red[0][1] + red[1][1] + red[2][1] + red[3][1] + beo[0];
  for (int l = t; l < LSEQ; l += 256) {
    int row = b * LSEQ + l;
    const float* s = sums + ((size_t)row * KTOP + k) * 3;
    float sv = s[0], s2 = s[1], sg = s[2];
    float mu = sv * (1.f / (float)HD);
    float var = s2 * (1.f / (float)HD) - mu * mu;
    float rr = rsqrtf(var + 1e-12f);
    float logit = rr * (sg - mu * sG) + sBW;
    float mv = mask[row];
    mel[((size_t)b * KTOP + k) * LSEQ + l] = logit * mv - NEGV * (1.f - mv);
  }
}

// ---------------- host ----------------
extern "C" void kernel_launch(void* const* d_in, const int* in_sizes, int n_in,
                              void* d_out, int out_size, void* d_ws, size_t ws_size,
                              hipStream_t stream) {
  (void)in_sizes; (void)n_in; (void)out_size;
  const float* seq = (const float*)d_in[0];
  const int*   cls = (const int*)d_in[1];
  const float* mask = (const float*)d_in[2];
  const float* Wst = (const float*)d_in[3];
  const float* bst = (const float*)d_in[4];
  const float* Wei = (const float*)d_in[5];
  const float* bei = (const float*)d_in[6];
  const float* gam = (const float*)d_in[7];
  const float* bet = (const float*)d_in[8];
  const float* Weo = (const float*)d_in[9];
  const float* beo = (const float*)d_in[10];
  const float* Wai = (const float*)d_in[11];
  const float* bai = (const float*)d_in[12];
  const float* Wao = (const float*)d_in[13];

  float* out = (float*)d_out;
  float* out0 = out;             // start_predictions  (16,512)
  float* out1 = out0 + 8192;     // end_predictions    (16,5,512)
  float* out2 = out1 + 40960;    // masked_start_logits(16,512)
  float* out3 = out2 + 8192;     // masked_end_logits  (16,5,512)
  float* out4 = out3 + 40960;    // start_top_predictions (16,5)
  float* out5 = out4 + 80;       // end_top_predictions (16,25)
  float* out6 = out5 + 400;      // class_logits (16)

  // ws layout
  char* p = (char*)d_ws;
  unsigned short* seqb = (unsigned short*)p;  p += (size_t)8192 * 1024 * 2;
  unsigned short* w1t  = (unsigned short*)p;  p += (size_t)1024 * 1024 * 2;
  float* p_ws   = (float*)p;                  p += 8192 * 4;
  int*   idx_ws = (int*)p;                    p += 128 * 4;
  float* x2p    = (float*)p;                  p += (size_t)80 * 1024 * 4;
  float* gw_ws  = (float*)p;                  p += 1024 * 4;
  float* sgb_ws = (float*)p;                  p += 4 * 4;
  float* pa     = (float*)p;                  p += (size_t)16 * 32 * 1024 * 4;
  float* cf     = (float*)p;                  p += (size_t)16 * 1024 * 4;
  float* pans   = (float*)p;                  p += (size_t)16 * 16 * 1024 * 4;
  // tail: X1 (big tier, 16MB) or sums (small tier, 480KB)
  unsigned short* x1 = (unsigned short*)p;
  float* sums = (float*)p;
  size_t base = (size_t)(p - (char*)d_ws);
  size_t need_big = base + (size_t)8192 * 1024 * 2;
  size_t need_small = base + (size_t)8192 * KTOP * 3 * 4;

  k_prep<<<3153, 256, 0, stream>>>(seq, seqb, Wst, bst, mask, out2, Wei, w1t,
                                   gam, bet, Weo, beo, gw_ws, sgb_ws, bei, x2p);
  k_softmax_topk<<<NB, 256, 0, stream>>>(out2, out0, out4, p_ws, idx_ws);

  if (ws_size >= need_big) {
    k_big<<<1664, 256, 0, stream>>>(seqb, w1t, x1, seq, idx_ws, Wei, x2p,
                                    p_ws, cls, pa, cf);
    k_end2<<<2304, 256, 0, stream>>>(x1, x2p, gw_ws, sgb_ws, mask, out3,
                                     pa, cf, Wai, pans);
  } else if (ws_size >= need_small) {
    k_x2f<<<640, 256, 0, stream>>>(seq, idx_ws, Wei, x2p);
    hipMemsetAsync(sums, 0, (size_t)8192 * KTOP * 3 * sizeof(float), stream);
    k_gemm_end_at<<<dim3(64, 8), 256, 0, stream>>>(seqb, w1t, x2p, gam, Weo, sums);
    k_end_final<<<NB * KTOP, 256, 0, stream>>>(sums, gam, bet, Weo, beo, mask, out3);
    k_ansin_f<<<512, 256, 0, stream>>>(seq, p_ws, cls, pa, cf);
    k_ansmid_f<<<256, 256, 0, stream>>>(pa, cf, Wai, pans);
  }

  k_fin<<<96, 256, 0, stream>>>(out3, out1, out5, pans, bai, Wao, out6);
}

// Round 7
// 88.709 us; speedup vs baseline: 7.6432x; 1.0815x over previous
//
#include <hip/hip_runtime.h>
#include <math.h>

#define HD   1024
#define LSEQ 512
#define NB   16
#define KTOP 5
#define NEGV 1e30f

typedef __bf16 bf16x8 __attribute__((ext_vector_type(8)));
typedef float  f32x4  __attribute__((ext_vector_type(4)));

__device__ inline unsigned short f2bf(float f) {
  unsigned u = __float_as_uint(f);
  unsigned r = (u + 0x7FFFu + ((u >> 16) & 1u)) >> 16;
  return (unsigned short)r;
}
__device__ inline float bf2f(unsigned short u) {
  return __uint_as_float(((unsigned)u) << 16);
}

__device__ inline float fast_tanh(float x) {
  float e = __expf(-2.f * fabsf(x));
  float v = (1.f - e) / (1.f + e);
  return copysignf(v, x);
}

// tanh(arg) with pre-scaled xs = A*arg, A = 2*log2(e): tanh = 1 - 2*rcp(1+exp2(xs))
__device__ inline float tanh_scaled(float xs) {
  float e = __builtin_amdgcn_exp2f(xs);
  float r = __builtin_amdgcn_rcpf(1.f + e);
  return fmaf(-2.f, r, 1.f);
}

#define GLDS(g, l) __builtin_amdgcn_global_load_lds(                      \
    (const __attribute__((address_space(1))) unsigned int*)(g),          \
    (__attribute__((address_space(3))) unsigned int*)(l), 16, 0, 0)

// =============== device bodies ===============

// ---- row log_softmax + top5 over 512 (256 threads) ----
__device__ __forceinline__ void sm_body(int row, const float* __restrict__ xin,
                                        float* __restrict__ lsm_out,
                                        float* __restrict__ top_out,
                                        float* __restrict__ p_out,
                                        int* __restrict__ idx_out) {
  __shared__ float redf[4];
  __shared__ int redi[4];
  __shared__ float bc_m, bc_s;
  __shared__ int bc_i;
  int t = threadIdx.x, lane = t & 63, wid = t >> 6;
  const float* x = xin + (size_t)row * LSEQ;
  float x0 = x[t], x1 = x[t + 256];

  float m = fmaxf(x0, x1);
#pragma unroll
  for (int off = 32; off; off >>= 1) m = fmaxf(m, __shfl_xor(m, off));
  if (lane == 0) redf[wid] = m;
  __syncthreads();
  if (t == 0) bc_m = fmaxf(fmaxf(redf[0], redf[1]), fmaxf(redf[2], redf[3]));
  __syncthreads();
  m = bc_m;

  float e0 = expf(x0 - m), e1 = expf(x1 - m);
  float s = e0 + e1;
#pragma unroll
  for (int off = 32; off; off >>= 1) s += __shfl_xor(s, off);
  if (lane == 0) redf[wid] = s;
  __syncthreads();
  if (t == 0) bc_s = redf[0] + redf[1] + redf[2] + redf[3];
  __syncthreads();
  s = bc_s;
  float ls = logf(s);

  lsm_out[(size_t)row * LSEQ + t] = x0 - m - ls;
  lsm_out[(size_t)row * LSEQ + t + 256] = x1 - m - ls;
  if (p_out) {
    float inv = 1.f / s;
    p_out[(size_t)row * LSEQ + t] = e0 * inv;
    p_out[(size_t)row * LSEQ + t + 256] = e1 * inv;
  }

  bool a0 = true, a1 = true;
  for (int it = 0; it < KTOP; ++it) {
    float v0 = a0 ? x0 : -INFINITY;
    float v1 = a1 ? x1 : -INFINITY;
    float bv = v0; int bi = t;
    if (v1 > bv) { bv = v1; bi = t + 256; }
#pragma unroll
    for (int off = 32; off; off >>= 1) {
      float ov = __shfl_xor(bv, off);
      int oi = __shfl_xor(bi, off);
      if (ov > bv || (ov == bv && oi < bi)) { bv = ov; bi = oi; }
    }
    __syncthreads();
    if (lane == 0) { redf[wid] = bv; redi[wid] = bi; }
    __syncthreads();
    if (t == 0) {
      float wv = redf[0]; int wi = redi[0];
      for (int w = 1; w < 4; ++w)
        if (redf[w] > wv || (redf[w] == wv && redi[w] < wi)) { wv = redf[w]; wi = redi[w]; }
      top_out[row * KTOP + it] = wv - m - ls;
      if (idx_out) idx_out[row * KTOP + it] = wi;
      bc_i = wi;
    }
    __syncthreads();
    int wi = bc_i;
    if (wi == t) a0 = false;
    if (wi == t + 256) a1 = false;
  }
}

// ---- 128x128 MFMA GEMM tile (proven 2-phase pipeline) -> X1 bf16 ----
__device__ __forceinline__ void gemm_body(int R0, int C0,
                                          const unsigned short* __restrict__ Abf,
                                          const unsigned short* __restrict__ Bt,
                                          unsigned short* __restrict__ X1) {
  __shared__ unsigned short SH[32768];  // As[2][8192] | Bs[2][8192]
  unsigned short* As = SH;
  unsigned short* Bs = SH + 16384;
  int t = threadIdx.x;
  int w = t >> 6, lane = t & 63, ln = lane & 15, hi = lane >> 4;
  int wr = w >> 1, wc = w & 1;

  f32x4 acc[4][4] = {};

#define STAGE(buf, kc)                                                        \
  do {                                                                        \
    _Pragma("unroll")                                                         \
    for (int p_ = 0; p_ < 4; ++p_) {                                          \
      int rr_ = p_ * 32 + (t >> 3);                                           \
      int cc_ = (t & 7) ^ (rr_ & 7);                                          \
      GLDS(Abf + (size_t)(R0 + rr_) * HD + (kc) + cc_ * 8,                    \
           As + (buf) * 8192 + p_ * 2048 + w * 512);                          \
      GLDS(Bt + (size_t)(C0 + rr_) * HD + (kc) + cc_ * 8,                     \
           Bs + (buf) * 8192 + p_ * 2048 + w * 512);                          \
    }                                                                         \
  } while (0)

  STAGE(0, 0);
  for (int it = 0; it < 16; ++it) {
    int cur = it & 1;
    if (it < 15) {
      STAGE(cur ^ 1, (it + 1) * 64);
      asm volatile("s_waitcnt vmcnt(8)" ::: "memory");
    } else {
      asm volatile("s_waitcnt vmcnt(0)" ::: "memory");
    }
    __builtin_amdgcn_s_barrier();
    __builtin_amdgcn_sched_barrier(0);
#pragma unroll
    for (int ks = 0; ks < 2; ++ks) {
      bf16x8 av[4], bv[4];
#pragma unroll
      for (int m = 0; m < 4; ++m) {
        int r = wr * 64 + m * 16 + ln;
        av[m] = *(const bf16x8*)(const void*)&As[cur * 8192 + r * 64 + (((ks * 4 + hi) ^ (r & 7)) * 8)];
      }
#pragma unroll
      for (int n = 0; n < 4; ++n) {
        int r = wc * 64 + n * 16 + ln;
        bv[n] = *(const bf16x8*)(const void*)&Bs[cur * 8192 + r * 64 + (((ks * 4 + hi) ^ (r & 7)) * 8)];
      }
#pragma unroll
      for (int m = 0; m < 4; ++m)
#pragma unroll
        for (int n = 0; n < 4; ++n)
          acc[m][n] = __builtin_amdgcn_mfma_f32_16x16x32_bf16(av[m], bv[n], acc[m][n], 0, 0, 0);
    }
    __builtin_amdgcn_sched_barrier(0);
    __builtin_amdgcn_s_barrier();
  }
#undef STAGE

#pragma unroll
  for (int m = 0; m < 4; ++m)
#pragma unroll
    for (int j = 0; j < 4; ++j) {
      int row = R0 + wr * 64 + m * 16 + hi * 4 + j;
#pragma unroll
      for (int n = 0; n < 4; ++n) {
        int col = C0 + wc * 64 + n * 16 + ln;
        X1[(size_t)row * HD + col] = f2bf(acc[m][n][j]);
      }
    }
}

// ---- X2 MFMA gather-GEMM: x2p[0:80][C0:C0+128] = SF @ W2 + bei ----
// A rows gathered from seqb via idx (per-lane global src, linear LDS dest).
__device__ __forceinline__ void x2gemm_body(int cid,
                                            const unsigned short* __restrict__ seqb,
                                            const unsigned short* __restrict__ w2t,
                                            const int* __restrict__ idx,
                                            const float* __restrict__ bei,
                                            float* __restrict__ x2p) {
  __shared__ unsigned short SH2[32768];
  unsigned short* As = SH2;
  unsigned short* Bs = SH2 + 16384;
  int t = threadIdx.x;
  int w = t >> 6, lane = t & 63, ln = lane & 15, hi = lane >> 4;
  int wr = w >> 1, wc = w & 1;
  int C0 = cid * 128;

  // per-thread gather row bases (fixed across K loop)
  size_t abase[4];
#pragma unroll
  for (int p_ = 0; p_ < 4; ++p_) {
    int rr = p_ * 32 + (t >> 3);
    int bk = rr < 80 ? rr : 0;
    int l = idx[bk];
    abase[p_] = ((size_t)((bk / KTOP) * LSEQ + l)) * HD;
  }

  f32x4 acc[4][4] = {};

#define STAGE2(buf, kc)                                                       \
  do {                                                                        \
    _Pragma("unroll")                                                         \
    for (int p_ = 0; p_ < 4; ++p_) {                                          \
      int rr_ = p_ * 32 + (t >> 3);                                           \
      int cc_ = (t & 7) ^ (rr_ & 7);                                          \
      GLDS(seqb + abase[p_] + (kc) + cc_ * 8,                                 \
           As + (buf) * 8192 + p_ * 2048 + w * 512);                          \
      GLDS(w2t + (size_t)(C0 + rr_) * HD + (kc) + cc_ * 8,                    \
           Bs + (buf) * 8192 + p_ * 2048 + w * 512);                          \
    }                                                                         \
  } while (0)

  STAGE2(0, 0);
  for (int it = 0; it < 16; ++it) {
    int cur = it & 1;
    if (it < 15) {
      STAGE2(cur ^ 1, (it + 1) * 64);
      asm volatile("s_waitcnt vmcnt(8)" ::: "memory");
    } else {
      asm volatile("s_waitcnt vmcnt(0)" ::: "memory");
    }
    __builtin_amdgcn_s_barrier();
    __builtin_amdgcn_sched_barrier(0);
#pragma unroll
    for (int ks = 0; ks < 2; ++ks) {
      bf16x8 av[4], bv[4];
#pragma unroll
      for (int m = 0; m < 4; ++m) {
        int r = wr * 64 + m * 16 + ln;
        av[m] = *(const bf16x8*)(const void*)&As[cur * 8192 + r * 64 + (((ks * 4 + hi) ^ (r & 7)) * 8)];
      }
#pragma unroll
      for (int n = 0; n < 4; ++n) {
        int r = wc * 64 + n * 16 + ln;
        bv[n] = *(const bf16x8*)(const void*)&Bs[cur * 8192 + r * 64 + (((ks * 4 + hi) ^ (r & 7)) * 8)];
      }
#pragma unroll
      for (int m = 0; m < 4; ++m)
#pragma unroll
        for (int n = 0; n < 4; ++n)
          acc[m][n] = __builtin_amdgcn_mfma_f32_16x16x32_bf16(av[m], bv[n], acc[m][n], 0, 0, 0);
    }
    __builtin_amdgcn_sched_barrier(0);
    __builtin_amdgcn_s_barrier();
  }
#undef STAGE2

#pragma unroll
  for (int m = 0; m < 4; ++m)
#pragma unroll
    for (int j = 0; j < 4; ++j) {
      int row = wr * 64 + m * 16 + hi * 4 + j;
      if (row < 80) {
#pragma unroll
        for (int n = 0; n < 4; ++n) {
          int col = C0 + wc * 64 + n * 16 + ln;
          x2p[(size_t)row * HD + col] = acc[m][n][j] + bei[col];
        }
      }
    }
}

// ---- answer-feature partial: pa[b][s] = sum_{l in slice} p*seq ----
__device__ __forceinline__ void ansin_body(int q, const float* __restrict__ seq,
                                           const float* __restrict__ p_ws,
                                           const int* __restrict__ cls,
                                           float* __restrict__ pa,
                                           float* __restrict__ cf) {
  __shared__ float ps[16];
  int b = q >> 5, s = q & 31, t = threadIdx.x;
  if (t < 16) ps[t] = p_ws[b * LSEQ + s * 16 + t];
  __syncthreads();
  const float* sb = seq + (size_t)(b * LSEQ + s * 16) * HD;
  float4 acc = make_float4(0.f, 0.f, 0.f, 0.f);
#pragma unroll
  for (int r = 0; r < 16; ++r) {
    float4 v = *(const float4*)(sb + (size_t)r * HD + 4 * t);
    float p = ps[r];
    acc.x = fmaf(p, v.x, acc.x);
    acc.y = fmaf(p, v.y, acc.y);
    acc.z = fmaf(p, v.z, acc.z);
    acc.w = fmaf(p, v.w, acc.w);
  }
  *(float4*)(pa + ((size_t)b * 32 + s) * HD + 4 * t) = acc;
  if (s == 0) {
    int ci = cls[b];
    *(float4*)(cf + (size_t)b * HD + 4 * t) =
        *(const float4*)(seq + (size_t)(b * LSEQ + ci) * HD + 4 * t);
  }
}

// ---- per-row tanh+LN+logit (proven round-5) ----
__device__ __forceinline__ void endrow_body(int bx, const unsigned short* __restrict__ X1,
                                            const float* __restrict__ x2p,
                                            const float* __restrict__ gw_ws,
                                            const float* __restrict__ sgb_ws,
                                            const float* __restrict__ mask,
                                            float* __restrict__ mel) {
  __shared__ float x2s[KTOP * HD];  // 20KB, prescaled by A
  const float A = 2.885390081777927f;  // 2*log2(e)
  int t = threadIdx.x, wave = t >> 6, lane = t & 63;
  int row = bx * 4 + wave;
  int b = row >> 9, l = row & 511;

  {
    const float4* src = (const float4*)(x2p + (size_t)b * KTOP * HD);
    float4* dst = (float4*)x2s;
    for (int i = t; i < KTOP * HD / 4; i += 256) {
      float4 v = src[i];
      dst[i] = make_float4(v.x * A, v.y * A, v.z * A, v.w * A);
    }
  }

  float xs[16], gwr[16];
  const unsigned short* xrow = X1 + (size_t)row * HD + lane * 4;
#pragma unroll
  for (int q = 0; q < 4; ++q) {
    ushort4 u = *(const ushort4*)(xrow + q * 256);
    xs[4 * q + 0] = bf2f(u.x) * A;
    xs[4 * q + 1] = bf2f(u.y) * A;
    xs[4 * q + 2] = bf2f(u.z) * A;
    xs[4 * q + 3] = bf2f(u.w) * A;
    float4 g = *(const float4*)(gw_ws + q * 256 + lane * 4);
    gwr[4 * q + 0] = g.x; gwr[4 * q + 1] = g.y;
    gwr[4 * q + 2] = g.z; gwr[4 * q + 3] = g.w;
  }
  float mv = mask[row];
  float sG = sgb_ws[0], sBW = sgb_ws[1];
  __syncthreads();

#pragma unroll
  for (int k = 0; k < KTOP; ++k) {
    float sv = 0.f, s2 = 0.f, sg = 0.f;
#pragma unroll
    for (int q = 0; q < 4; ++q) {
      float4 xq = *(const float4*)&x2s[k * HD + q * 256 + lane * 4];
      float v0 = tanh_scaled(xs[4 * q + 0] + xq.x);
      float v1 = tanh_scaled(xs[4 * q + 1] + xq.y);
      float v2 = tanh_scaled(xs[4 * q + 2] + xq.z);
      float v3 = tanh_scaled(xs[4 * q + 3] + xq.w);
      sv += v0 + v1 + v2 + v3;
      s2 = fmaf(v0, v0, s2); s2 = fmaf(v1, v1, s2);
      s2 = fmaf(v2, v2, s2); s2 = fmaf(v3, v3, s2);
      sg = fmaf(v0, gwr[4 * q + 0], sg); sg = fmaf(v1, gwr[4 * q + 1], sg);
      sg = fmaf(v2, gwr[4 * q + 2], sg); sg = fmaf(v3, gwr[4 * q + 3], sg);
    }
#pragma unroll
    for (int off = 32; off; off >>= 1) {
      sv += __shfl_xor(sv, off);
      s2 += __shfl_xor(s2, off);
      sg += __shfl_xor(sg, off);
    }
    if (lane == 0) {
      float mu = sv * (1.f / (float)HD);
      float var = s2 * (1.f / (float)HD) - mu * mu;
      float rr = rsqrtf(var + 1e-12f);
      float logit = rr * (sg - mu * sG) + sBW;
      mel[((size_t)b * KTOP + k) * LSEQ + l] = logit * mv - NEGV * (1.f - mv);
    }
  }
}

// ---- answer mid GEMM slice ----
__device__ __forceinline__ void ansmid_body(int q, const float* __restrict__ pa,
                                            const float* __restrict__ cf,
                                            const float* __restrict__ Wai,
                                            float* __restrict__ pans) {
  __shared__ float a_s[128];
  int b = q >> 4, c = q & 15, t = threadIdx.x;
  if (t < 128) {
    int i = c * 128 + t;
    float av;
    if (i < HD) {
      av = 0.f;
#pragma unroll
      for (int s = 0; s < 32; ++s) av += pa[((size_t)b * 32 + s) * HD + i];
    } else {
      av = cf[(size_t)b * HD + (i - HD)];
    }
    a_s[t] = av;
  }
  __syncthreads();
  float4 acc = make_float4(0.f, 0.f, 0.f, 0.f);
#pragma unroll 8
  for (int r = 0; r < 128; ++r) {
    float4 wv = *(const float4*)(Wai + (size_t)(c * 128 + r) * HD + 4 * t);
    float a = a_s[r];
    acc.x = fmaf(a, wv.x, acc.x);
    acc.y = fmaf(a, wv.y, acc.y);
    acc.z = fmaf(a, wv.z, acc.z);
    acc.w = fmaf(a, wv.w, acc.w);
  }
  *(float4*)(pans + ((size_t)b * 16 + c) * HD + 4 * t) = acc;
}

__device__ __forceinline__ void ansfinal_body(int b, const float* __restrict__ pans,
                                              const float* __restrict__ bai,
                                              const float* __restrict__ Wao,
                                              float* __restrict__ out6) {
  __shared__ float red[4];
  int t = threadIdx.x, lane = t & 63, wid = t >> 6;
  float4 a = *(const float4*)(bai + 4 * t);
#pragma unroll
  for (int c = 0; c < 16; ++c) {
    float4 p = *(const float4*)(pans + ((size_t)b * 16 + c) * HD + 4 * t);
    a.x += p.x; a.y += p.y; a.z += p.z; a.w += p.w;
  }
  float4 wo = *(const float4*)(Wao + 4 * t);
  float part = fast_tanh(a.x) * wo.x + fast_tanh(a.y) * wo.y +
               fast_tanh(a.z) * wo.z + fast_tanh(a.w) * wo.w;
#pragma unroll
  for (int off = 32; off; off >>= 1) part += __shfl_xor(part, off);
  if (lane == 0) red[wid] = part;
  __syncthreads();
  if (t == 0) out6[b] = red[0] + red[1] + red[2] + red[3];
}

// =============== kernels ===============

// K1: conv+start (2048) | W1/W2 transpose (2048) | LN consts (1)
__global__ void k_prep(const float* __restrict__ seq,
                       unsigned short* __restrict__ seqb,
                       const float* __restrict__ Wst,
                       const float* __restrict__ bst,
                       const float* __restrict__ mask,
                       float* __restrict__ msl,
                       const float* __restrict__ Wei,
                       unsigned short* __restrict__ w1t,
                       unsigned short* __restrict__ w2t,
                       const float* __restrict__ gam,
                       const float* __restrict__ bet,
                       const float* __restrict__ Weo,
                       const float* __restrict__ beo,
                       float* __restrict__ gw_ws,
                       float* __restrict__ sgb_ws) {
  __shared__ unsigned short tile[32][33];
  __shared__ float redp[4][2];
  int bx = blockIdx.x;
  if (bx < 2048) {
    int wave = threadIdx.x >> 6, lane = threadIdx.x & 63;
    int row = bx * 4 + wave;
    const float4* s4 = (const float4*)(seq + (size_t)row * HD);
    const float4* w4 = (const float4*)Wst;
    ushort4* o4 = (ushort4*)(seqb + (size_t)row * HD);
    float acc = 0.f;
#pragma unroll
    for (int m = 0; m < 4; ++m) {
      int i = lane + 64 * m;
      float4 a = s4[i], w = w4[i];
      acc += a.x * w.x + a.y * w.y + a.z * w.z + a.w * w.w;
      ushort4 o;
      o.x = f2bf(a.x); o.y = f2bf(a.y); o.z = f2bf(a.z); o.w = f2bf(a.w);
      o4[i] = o;
    }
#pragma unroll
    for (int off = 32; off; off >>= 1) acc += __shfl_xor(acc, off);
    if (lane == 0) {
      float logit = acc + bst[0];
      float mv = mask[row];
      msl[row] = logit * mv - NEGV * (1.f - mv);
    }
  } else if (bx < 4096) {
    int tb = bx - 2048;  // 0..2047: 0..1023 -> W1, 1024..2047 -> W2
    const float* Wsrc = Wei + (tb >= 1024 ? (size_t)HD * HD : 0);
    unsigned short* Wdst = (tb >= 1024) ? w2t : w1t;
    int tb2 = tb & 1023;
    int h0 = (tb2 & 31) * 32, d0 = (tb2 >> 5) * 32;
    int tx = threadIdx.x & 31, ty = threadIdx.x >> 5;
#pragma unroll
    for (int i = 0; i < 4; ++i)
      tile[ty + 8 * i][tx] = f2bf(Wsrc[(size_t)(h0 + ty + 8 * i) * HD + d0 + tx]);
    __syncthreads();
#pragma unroll
    for (int i = 0; i < 4; ++i)
      Wdst[(size_t)(d0 + ty + 8 * i) * HD + h0 + tx] = tile[tx][ty + 8 * i];
  } else {
    int t = threadIdx.x, wave = t >> 6, lane = t & 63;
    float4 g = ((const float4*)gam)[t];
    float4 w = ((const float4*)Weo)[t];
    float4 bv = ((const float4*)bet)[t];
    float4 gwv = make_float4(g.x * w.x, g.y * w.y, g.z * w.z, g.w * w.w);
    ((float4*)gw_ws)[t] = gwv;
    float pg = gwv.x + gwv.y + gwv.z + gwv.w;
    float pb = bv.x * w.x + bv.y * w.y + bv.z * w.z + bv.w * w.w;
#pragma unroll
    for (int off = 32; off; off >>= 1) {
      pg += __shfl_xor(pg, off);
      pb += __shfl_xor(pb, off);
    }
    if (lane == 0) { redp[wave][0] = pg; redp[wave][1] = pb; }
    __syncthreads();
    if (t == 0) {
      sgb_ws[0] = redp[0][0] + redp[1][0] + redp[2][0] + redp[3][0];
      sgb_ws[1] = redp[0][1] + redp[1][1] + redp[2][1] + redp[3][1] + beo[0];
    }
  }
}

__global__ void k_softmax_topk(const float* __restrict__ xin,
                               float* __restrict__ lsm_out,
                               float* __restrict__ top_out,
                               float* __restrict__ p_out,
                               int* __restrict__ idx_out) {
  sm_body(blockIdx.x, xin, lsm_out, top_out, p_out, idx_out);
}

// K2: sm1 (ids 0..15) + XCD-affine gemm (ids 16..527; r=gid%64 -> id%8 const per row panel)
__launch_bounds__(256, 2)
__global__ void k_gsm(const unsigned short* __restrict__ Abf,
                      const unsigned short* __restrict__ Bt,
                      unsigned short* __restrict__ X1,
                      const float* __restrict__ msl,
                      float* __restrict__ lsm_out,
                      float* __restrict__ top_out,
                      float* __restrict__ p_out,
                      int* __restrict__ idx_out) {
  int id = blockIdx.x;
  if (id < 16) {
    sm_body(id, msl, lsm_out, top_out, p_out, idx_out);
  } else {
    int gid = id - 16;
    gemm_body((gid & 63) * 128, (gid >> 6) * 128, Abf, Bt, X1);
  }
}

// K3: x2 MFMA gather-gemm (ids 0..7) + ans_in (ids 8..519)
__launch_bounds__(256, 2)
__global__ void k_x2a(const unsigned short* __restrict__ seqb,
                      const unsigned short* __restrict__ w2t,
                      const int* __restrict__ idx,
                      const float* __restrict__ bei,
                      float* __restrict__ x2p,
                      const float* __restrict__ seq,
                      const float* __restrict__ p_ws,
                      const int* __restrict__ cls,
                      float* __restrict__ pa,
                      float* __restrict__ cf) {
  int id = blockIdx.x;
  if (id < 8) x2gemm_body(id, seqb, w2t, idx, bei, x2p);
  else ansin_body(id - 8, seq, p_ws, cls, pa, cf);
}

// K4: endrow (2048) + ans_mid (256)
__global__ void k_end2(const unsigned short* __restrict__ X1,
                       const float* __restrict__ x2p,
                       const float* __restrict__ gw_ws,
                       const float* __restrict__ sgb_ws,
                       const float* __restrict__ mask,
                       float* __restrict__ mel,
                       const float* __restrict__ pa,
                       const float* __restrict__ cf,
                       const float* __restrict__ Wai,
                       float* __restrict__ pans) {
  int bx = blockIdx.x;
  if (bx < 2048) endrow_body(bx, X1, x2p, gw_ws, sgb_ws, mask, mel);
  else ansmid_body(bx - 2048, pa, cf, Wai, pans);
}

// K5: softmax2 (80) + ans_final (16)
__global__ void k_fin(const float* __restrict__ mel,
                      float* __restrict__ lsm_out,
                      float* __restrict__ top_out,
                      const float* __restrict__ pans,
                      const float* __restrict__ bai,
                      const float* __restrict__ Wao,
                      float* __restrict__ out6) {
  int bx = blockIdx.x;
  if (bx < NB * KTOP) sm_body(bx, mel, lsm_out, top_out, nullptr, nullptr);
  else ansfinal_body(bx - NB * KTOP, pans, bai, Wao, out6);
}

// =============== fallback-tier kernels (small ws) ===============
__global__ void k_x2init(const float* __restrict__ bei, float* __restrict__ x2p) {
  ((float4*)(x2p + (size_t)blockIdx.x * HD))[threadIdx.x] = ((const float4*)bei)[threadIdx.x];
}

__global__ void k_x2f(const float* __restrict__ seq, const int* __restrict__ idx,
                      const float* __restrict__ Wei, float* __restrict__ x2p) {
  __shared__ float srow[128];
  int q = blockIdx.x;
  int bk = q >> 3, s = q & 7, t = threadIdx.x;
  int b = bk / KTOP;
  int l = idx[bk];
  if (t < 128) srow[t] = seq[((size_t)(b * LSEQ + l)) * HD + s * 128 + t];
  __syncthreads();
  const float* W2 = Wei + (size_t)HD * HD + (size_t)s * 128 * HD;
  float4 acc = make_float4(0.f, 0.f, 0.f, 0.f);
#pragma unroll 8
  for (int h = 0; h < 128; ++h) {
    float4 wv = *(const float4*)(W2 + (size_t)h * HD + 4 * t);
    float sv = srow[h];
    acc.x = fmaf(sv, wv.x, acc.x);
    acc.y = fmaf(sv, wv.y, acc.y);
    acc.z = fmaf(sv, wv.z, acc.z);
    acc.w = fmaf(sv, wv.w, acc.w);
  }
  float* dst = x2p + (size_t)bk * HD + 4 * t;
  atomicAdd(dst + 0, acc.x);
  atomicAdd(dst + 1, acc.y);
  atomicAdd(dst + 2, acc.z);
  atomicAdd(dst + 3, acc.w);
}

__global__ void k_ansin_f(const float* __restrict__ seq, const float* __restrict__ p_ws,
                          const int* __restrict__ cls, float* __restrict__ pa,
                          float* __restrict__ cf) {
  ansin_body(blockIdx.x, seq, p_ws, cls, pa, cf);
}
__global__ void k_ansmid_f(const float* __restrict__ pa, const float* __restrict__ cf,
                           const float* __restrict__ Wai, float* __restrict__ pans) {
  ansmid_body(blockIdx.x, pa, cf, Wai, pans);
}

__launch_bounds__(256, 2)
__global__ void k_gemm_end_at(const unsigned short* __restrict__ Abf,
                              const unsigned short* __restrict__ Bt,
                              const float* __restrict__ x2p,
                              const float* __restrict__ gamma,
                              const float* __restrict__ Wout,
                              float* __restrict__ outp) {
  __shared__ unsigned short As[2][128 * 64];
  __shared__ unsigned short Bs[2][128 * 64];
  int t = threadIdx.x;
  int w = t >> 6, lane = t & 63, ln = lane & 15, hi = lane >> 4;
  int wr = w >> 1, wc = w & 1;
  int R0 = blockIdx.x * 128, C0 = blockIdx.y * 128;
  int b = R0 >> 9;
  f32x4 acc[4][4] = {};
#define STAGE(buf, kc)                                                        \
  do {                                                                        \
    _Pragma("unroll")                                                         \
    for (int p_ = 0; p_ < 4; ++p_) {                                          \
      int rr_ = p_ * 32 + (t >> 3);                                           \
      int cc_ = (t & 7) ^ (rr_ & 7);                                          \
      GLDS(Abf + (size_t)(R0 + rr_) * HD + (kc) + cc_ * 8,                    \
           &As[buf][p_ * 2048 + w * 512]);                                    \
      GLDS(Bt + (size_t)(C0 + rr_) * HD + (kc) + cc_ * 8,                     \
           &Bs[buf][p_ * 2048 + w * 512]);                                    \
    }                                                                         \
  } while (0)
  STAGE(0, 0);
  for (int it = 0; it < 16; ++it) {
    int cur = it & 1;
    if (it < 15) {
      STAGE(cur ^ 1, (it + 1) * 64);
      asm volatile("s_waitcnt vmcnt(8)" ::: "memory");
    } else {
      asm volatile("s_waitcnt vmcnt(0)" ::: "memory");
    }
    __builtin_amdgcn_s_barrier();
    __builtin_amdgcn_sched_barrier(0);
#pragma unroll
    for (int ks = 0; ks < 2; ++ks) {
      bf16x8 av[4], bv[4];
#pragma unroll
      for (int m = 0; m < 4; ++m) {
        int r = wr * 64 + m * 16 + ln;
        av[m] = *(const bf16x8*)(const void*)&As[cur][r * 64 + (((ks * 4 + hi) ^ (r & 7)) * 8)];
      }
#pragma unroll
      for (int n = 0; n < 4; ++n) {
        int r = wc * 64 + n * 16 + ln;
        bv[n] = *(const bf16x8*)(const void*)&Bs[cur][r * 64 + (((ks * 4 + hi) ^ (r & 7)) * 8)];
      }
#pragma unroll
      for (int m = 0; m < 4; ++m)
#pragma unroll
        for (int n = 0; n < 4; ++n)
          acc[m][n] = __builtin_amdgcn_mfma_f32_16x16x32_bf16(av[m], bv[n], acc[m][n], 0, 0, 0);
    }
    __builtin_amdgcn_sched_barrier(0);
    __builtin_amdgcn_s_barrier();
  }
#undef STAGE
  float gsv[4];
  float x2v[4][KTOP];
#pragma unroll
  for (int n = 0; n < 4; ++n) {
    int c = C0 + wc * 64 + n * 16 + ln;
    gsv[n] = gamma[c] * Wout[c];
#pragma unroll
    for (int k = 0; k < KTOP; ++k) x2v[n][k] = x2p[((size_t)b * KTOP + k) * HD + c];
  }
#pragma unroll
  for (int m = 0; m < 4; ++m)
#pragma unroll
    for (int j = 0; j < 4; ++j) {
      int row = R0 + wr * 64 + m * 16 + hi * 4 + j;
#pragma unroll
      for (int k = 0; k < KTOP; ++k) {
        float sv = 0.f, s2 = 0.f, sg = 0.f;
#pragma unroll
        for (int n = 0; n < 4; ++n) {
          float v = fast_tanh(acc[m][n][j] + x2v[n][k]);
          sv += v; s2 += v * v; sg += v * gsv[n];
        }
#pragma unroll
        for (int off = 8; off; off >>= 1) {
          sv += __shfl_xor(sv, off);
          s2 += __shfl_xor(s2, off);
          sg += __shfl_xor(sg, off);
        }
        if (ln == 0) {
          float* p = outp + ((size_t)row * KTOP + k) * 3;
          atomicAdd(p, sv);
          atomicAdd(p + 1, s2);
          atomicAdd(p + 2, sg);
        }
      }
    }
}

__global__ void k_end_final(const float* __restrict__ sums,
                            const float* __restrict__ gamma,
                            const float* __restrict__ beta,
                            const float* __restrict__ Wout,
                            const float* __restrict__ beo,
                            const float* __restrict__ mask,
                            float* __restrict__ mel) {
  int bk = blockIdx.x, b = bk / KTOP, k = bk % KTOP;
  int t = threadIdx.x, lane = t & 63, wid = t >> 6;
  __shared__ float red[4][2];
  float pg = 0.f, pb = 0.f;
  for (int i = t; i < HD; i += 256) {
    float wv = Wout[i];
    pg += gamma[i] * wv;
    pb += beta[i] * wv;
  }
#pragma unroll
  for (int off = 32; off; off >>= 1) {
    pg += __shfl_xor(pg, off);
    pb += __shfl_xor(pb, off);
  }
  if (lane == 0) { red[wid][0] = pg; red[wid][1] = pb; }
  __syncthreads();
  float sG = red[0][0] + red[1][0] + red[2][0] + red[3][0];
  float sBW = red[0][1] + red[1][1] + red[2][1] + red[3][1] + beo[0];
  for (int l = t; l < LSEQ; l += 256) {
    int row = b * LSEQ + l;
    const float* s = sums + ((size_t)row * KTOP + k) * 3;
    float sv = s[0], s2 = s[1], sg = s[2];
    float mu = sv * (1.f / (float)HD);
    float var = s2 * (1.f / (float)HD) - mu * mu;
    float rr = rsqrtf(var + 1e-12f);
    float logit = rr * (sg - mu * sG) + sBW;
    float mv = mask[row];
    mel[((size_t)b * KTOP + k) * LSEQ + l] = logit * mv - NEGV * (1.f - mv);
  }
}

// ---------------- host ----------------
extern "C" void kernel_launch(void* const* d_in, const int* in_sizes, int n_in,
                              void* d_out, int out_size, void* d_ws, size_t ws_size,
                              hipStream_t stream) {
  (void)in_sizes; (void)n_in; (void)out_size;
  const float* seq = (const float*)d_in[0];
  const int*   cls = (const int*)d_in[1];
  const float* mask = (const float*)d_in[2];
  const float* Wst = (const float*)d_in[3];
  const float* bst = (const float*)d_in[4];
  const float* Wei = (const float*)d_in[5];
  const float* bei = (const float*)d_in[6];
  const float* gam = (const float*)d_in[7];
  const float* bet = (const float*)d_in[8];
  const float* Weo = (const float*)d_in[9];
  const float* beo = (const float*)d_in[10];
  const float* Wai = (const float*)d_in[11];
  const float* bai = (const float*)d_in[12];
  const float* Wao = (const float*)d_in[13];

  float* out = (float*)d_out;
  float* out0 = out;             // start_predictions  (16,512)
  float* out1 = out0 + 8192;     // end_predictions    (16,5,512)
  float* out2 = out1 + 40960;    // masked_start_logits(16,512)
  float* out3 = out2 + 8192;     // masked_end_logits  (16,5,512)
  float* out4 = out3 + 40960;    // start_top_predictions (16,5)
  float* out5 = out4 + 80;       // end_top_predictions (16,25)
  float* out6 = out5 + 400;      // class_logits (16)

  // ws layout
  char* p = (char*)d_ws;
  unsigned short* seqb = (unsigned short*)p;  p += (size_t)8192 * 1024 * 2;
  unsigned short* w1t  = (unsigned short*)p;  p += (size_t)1024 * 1024 * 2;
  unsigned short* w2t  = (unsigned short*)p;  p += (size_t)1024 * 1024 * 2;
  float* p_ws   = (float*)p;                  p += 8192 * 4;
  int*   idx_ws = (int*)p;                    p += 128 * 4;
  float* x2p    = (float*)p;                  p += (size_t)80 * 1024 * 4;
  float* gw_ws  = (float*)p;                  p += 1024 * 4;
  float* sgb_ws = (float*)p;                  p += 4 * 4;
  float* pa     = (float*)p;                  p += (size_t)16 * 32 * 1024 * 4;
  float* cf     = (float*)p;                  p += (size_t)16 * 1024 * 4;
  float* pans   = (float*)p;                  p += (size_t)16 * 16 * 1024 * 4;
  // tail: X1 (big tier, 16MB) or sums (small tier, 480KB)
  unsigned short* x1 = (unsigned short*)p;
  float* sums = (float*)p;
  size_t base = (size_t)(p - (char*)d_ws);
  size_t need_big = base + (size_t)8192 * 1024 * 2;
  size_t need_small = base + (size_t)8192 * KTOP * 3 * 4;

  k_prep<<<4097, 256, 0, stream>>>(seq, seqb, Wst, bst, mask, out2, Wei, w1t, w2t,
                                   gam, bet, Weo, beo, gw_ws, sgb_ws);

  if (ws_size >= need_big) {
    k_gsm<<<528, 256, 0, stream>>>(seqb, w1t, x1, out2, out0, out4, p_ws, idx_ws);
    k_x2a<<<520, 256, 0, stream>>>(seqb, w2t, idx_ws, bei, x2p,
                                   seq, p_ws, cls, pa, cf);
    k_end2<<<2304, 256, 0, stream>>>(x1, x2p, gw_ws, sgb_ws, mask, out3,
                                     pa, cf, Wai, pans);
  } else if (ws_size >= need_small) {
    k_softmax_topk<<<NB, 256, 0, stream>>>(out2, out0, out4, p_ws, idx_ws);
    k_x2init<<<80, 256, 0, stream>>>(bei, x2p);
    k_x2f<<<640, 256, 0, stream>>>(seq, idx_ws, Wei, x2p);
    hipMemsetAsync(sums, 0, (size_t)8192 * KTOP * 3 * sizeof(float), stream);
    k_gemm_end_at<<<dim3(64, 8), 256, 0, stream>>>(seqb, w1t, x2p, gam, Weo, sums);
    k_end_final<<<NB * KTOP, 256, 0, stream>>>(sums, gam, bet, Weo, beo, mask, out3);
    k_ansin_f<<<512, 256, 0, stream>>>(seq, p_ws, cls, pa, cf);
    k_ansmid_f<<<256, 256, 0, stream>>>(pa, cf, Wai, pans);
  }

  k_fin<<<96, 256, 0, stream>>>(out3, out1, out5, pans, bai, Wao, out6);
}